// Round 1
// baseline (10481.146 us; speedup 1.0000x reference)
//
#include <hip/hip_runtime.h>

#define H 128
#define HEADS 4
#define OUTD 10

// ---------- ordered-float encoding for atomic max ----------
__device__ __forceinline__ unsigned fenc(float x) {
  unsigned u = __float_as_uint(x);
  return (u & 0x80000000u) ? ~u : (u | 0x80000000u);
}
__device__ __forceinline__ float fdec(unsigned u) {
  u = (u & 0x80000000u) ? (u & 0x7fffffffu) : ~u;
  return __uint_as_float(u);
}

// ---------- generic [n,128] @ [128,128] GEMM, staged rows in LDS, scalar W ----------
template <int RELU, int BIAS>
__global__ __launch_bounds__(256) void dense128(const float* __restrict__ X,
                                                const float* __restrict__ W,
                                                const float* __restrict__ bias,
                                                float* __restrict__ Y, int n) {
  __shared__ float tl[128][65];
  const int tid = threadIdx.x, lane = tid & 63, wave = tid >> 6;
  for (int base = blockIdx.x * 64; base < n; base += gridDim.x * 64) {
    const int nr = min(64, n - base);
    __syncthreads();
#pragma unroll
    for (int p = 0; p < 32; ++p) {
      int flat = p * 256 + tid;
      int r = flat >> 7, k = flat & 127;
      if (r < nr) tl[k][r] = X[(size_t)(base + r) * H + k];
    }
    __syncthreads();
    const int jb = wave * 32;
    float acc[32];
#pragma unroll
    for (int j = 0; j < 32; ++j) acc[j] = 0.f;
    for (int k = 0; k < 128; ++k) {
      float tk = tl[k][lane];
#pragma unroll
      for (int j = 0; j < 32; ++j) acc[j] = fmaf(tk, W[k * H + jb + j], acc[j]);
    }
    if (lane < nr) {
      size_t o = (size_t)(base + lane) * H + jb;
#pragma unroll
      for (int j = 0; j < 32; ++j) {
        float y = acc[j];
        if (BIAS) y += bias[jb + j];
        if (RELU) y = fmaxf(y, 0.f);
        Y[o + j] = y;
      }
    }
  }
}

// ---------- small elementwise / init kernels ----------
__global__ void fill_u32(unsigned* p, unsigned v, size_t n) {
  size_t i = (size_t)blockIdx.x * 256 + threadIdx.x;
  if (i < n) p[i] = v;
}
__global__ void deg_init(float* deg, int n) {
  int i = blockIdx.x * 256 + threadIdx.x;
  if (i < n) deg[i] = 1.f;
}
__global__ void deg_scatter(const int* __restrict__ ei, float* __restrict__ deg, int E) {
  int e = blockIdx.x * 256 + threadIdx.x;
  if (e < E) unsafeAtomicAdd(&deg[ei[(size_t)E + e]], 1.f);
}
__global__ void deg_rsqrt(float* deg, int n) {
  int i = blockIdx.x * 256 + threadIdx.x;
  if (i < n) deg[i] = rsqrtf(deg[i]);  // deg >= 1 always (self loop)
}
__global__ void gcn_self(const float* __restrict__ hx, const float* __restrict__ dinv,
                         float* __restrict__ out, size_t nh) {
  size_t i = (size_t)blockIdx.x * 256 + threadIdx.x;
  if (i < nh) {
    float dv = dinv[i >> 7];
    out[i] = hx[i] * dv * dv;
  }
}
__global__ void scatter_norm(const float* __restrict__ hx, const int* __restrict__ ei,
                             const float* __restrict__ dinv, float* __restrict__ out, int E) {
  int t = blockIdx.x * 256 + threadIdx.x;
  if (t >= E * 32) return;
  int e = t >> 5, q = t & 31;
  int s = ei[e], d = ei[E + e];
  float nm = dinv[s] * dinv[d];
  float4 v = *((const float4*)(hx + (size_t)s * H) + q);
  float* o = out + (size_t)d * H + q * 4;
  unsafeAtomicAdd(o + 0, v.x * nm);
  unsafeAtomicAdd(o + 1, v.y * nm);
  unsafeAtomicAdd(o + 2, v.z * nm);
  unsafeAtomicAdd(o + 3, v.w * nm);
}
__global__ void bias_relu(float* __restrict__ h, const float* __restrict__ b, size_t nh) {
  size_t i = (size_t)blockIdx.x * 256 + threadIdx.x;
  if (i < nh) h[i] = fmaxf(h[i] + b[i & 127], 0.f);
}
__global__ void bias_elu(float* __restrict__ h, const float* __restrict__ b, size_t nh) {
  size_t i = (size_t)blockIdx.x * 256 + threadIdx.x;
  if (i < nh) {
    float x = h[i] + b[i & 127];
    h[i] = x > 0.f ? x : expm1f(x);
  }
}

// ---------- GAT ----------
__global__ void att_pre(const float* __restrict__ g, const float* __restrict__ attS,
                        const float* __restrict__ attD, float* __restrict__ asrc,
                        float* __restrict__ adst, int n) {
  int t = blockIdx.x * 256 + threadIdx.x;
  if (t >= n * HEADS) return;
  int i = t >> 2, hd = t & 3;
  const float* gr = g + (size_t)i * H + hd * 32;
  float s1 = 0.f, s2 = 0.f;
#pragma unroll
  for (int c = 0; c < 32; ++c) {
    float gv = gr[c];
    s1 = fmaf(gv, attS[hd * 32 + c], s1);
    s2 = fmaf(gv, attD[hd * 32 + c], s2);
  }
  asrc[t] = s1;
  adst[t] = s2;
}
__global__ void gat_max(const float* __restrict__ asrc, const float* __restrict__ adst,
                        const int* __restrict__ ei, unsigned* __restrict__ emax, int E, int n) {
  int t = blockIdx.x * 256 + threadIdx.x;
  if (t >= (E + n) * HEADS) return;
  int el = t >> 2, hd = t & 3;
  int s, d;
  if (el < E) { s = ei[el]; d = ei[E + el]; } else { s = d = el - E; }
  float e = asrc[s * 4 + hd] + adst[d * 4 + hd];
  e = e > 0.f ? e : 0.2f * e;
  atomicMax(&emax[d * 4 + hd], fenc(e));
}
__global__ void gat_exp(const float* __restrict__ asrc, const float* __restrict__ adst,
                        const int* __restrict__ ei, const unsigned* __restrict__ emax,
                        float* __restrict__ esum, float* __restrict__ ex, int E, int n) {
  int t = blockIdx.x * 256 + threadIdx.x;
  if (t >= (E + n) * HEADS) return;
  int el = t >> 2, hd = t & 3;
  int s, d;
  if (el < E) { s = ei[el]; d = ei[E + el]; } else { s = d = el - E; }
  float e = asrc[s * 4 + hd] + adst[d * 4 + hd];
  e = e > 0.f ? e : 0.2f * e;
  float v = expf(e - fdec(emax[d * 4 + hd]));
  ex[t] = v;
  unsafeAtomicAdd(&esum[d * 4 + hd], v);
}
__global__ void gat_agg(const float* __restrict__ g, const int* __restrict__ ei,
                        const float* __restrict__ ex, const float* __restrict__ esum,
                        float* __restrict__ out, int E, int n) {
  int t = blockIdx.x * 256 + threadIdx.x;
  if (t >= (E + n) * 32) return;
  int el = t >> 5, q = t & 31;
  int s, d;
  if (el < E) { s = ei[el]; d = ei[E + el]; } else { s = d = el - E; }
  int hd = q >> 3;
  float alpha = ex[el * 4 + hd] / (esum[d * 4 + hd] + 1e-16f);
  float4 v = *((const float4*)(g + (size_t)s * H) + q);
  float* o = out + (size_t)d * H + q * 4;
  unsafeAtomicAdd(o + 0, v.x * alpha);
  unsafeAtomicAdd(o + 1, v.y * alpha);
  unsafeAtomicAdd(o + 2, v.z * alpha);
  unsafeAtomicAdd(o + 3, v.w * alpha);
}

// ---------- EdgeConv ----------
__global__ void ec_prep(const float* __restrict__ W1, float* __restrict__ Wa,
                        float* __restrict__ Wb) {
  int i = blockIdx.x * 256 + threadIdx.x;
  if (i < H * H) {
    float top = W1[i], bot = W1[H * H + i];
    Wa[i] = top - bot;
    Wb[i] = bot;
  }
}
__global__ __launch_bounds__(256) void edgeconv(const float* __restrict__ A,
                                                const float* __restrict__ Bm,
                                                const int* __restrict__ ei,
                                                const float* __restrict__ b1,
                                                const float* __restrict__ W2,
                                                const float* __restrict__ b2,
                                                unsigned* __restrict__ hec, int E) {
  __shared__ float tl[128][65];
  const int tid = threadIdx.x, lane = tid & 63, wave = tid >> 6;
  for (int base = blockIdx.x * 64; base < E; base += gridDim.x * 64) {
    const int ne = min(64, E - base);
    __syncthreads();
#pragma unroll
    for (int p = 0; p < 32; ++p) {
      int flat = p * 256 + tid;
      int r = flat >> 7, k = flat & 127;
      if (r < ne) {
        int s = ei[base + r], d = ei[E + base + r];
        float v = A[(size_t)d * H + k] + Bm[(size_t)s * H + k] + b1[k];
        tl[k][r] = fmaxf(v, 0.f);
      }
    }
    __syncthreads();
    const int jb = wave * 32;
    float acc[32];
#pragma unroll
    for (int j = 0; j < 32; ++j) acc[j] = 0.f;
    for (int k = 0; k < 128; ++k) {
      float tk = tl[k][lane];
#pragma unroll
      for (int j = 0; j < 32; ++j) acc[j] = fmaf(tk, W2[k * H + jb + j], acc[j]);
    }
    if (lane < ne) {
      int d = ei[E + base + lane];
      unsigned* o = hec + (size_t)d * H + jb;
#pragma unroll
      for (int j = 0; j < 32; ++j) atomicMax(o + j, fenc(acc[j] + b2[jb + j]));
    }
  }
}
__global__ void ec_decode(unsigned* __restrict__ hec, float* __restrict__ sgin, size_t nh) {
  size_t i = (size_t)blockIdx.x * 256 + threadIdx.x;
  if (i < nh) {
    float v = fdec(hec[i]);
    ((float*)hec)[i] = v;
    sgin[i] = v;
  }
}
__global__ void scatter_add(const float* __restrict__ h, const int* __restrict__ ei,
                            float* __restrict__ out, int E) {
  int t = blockIdx.x * 256 + threadIdx.x;
  if (t >= E * 32) return;
  int e = t >> 5, q = t & 31;
  int s = ei[e], d = ei[E + e];
  float4 v = *((const float4*)(h + (size_t)s * H) + q);
  float* o = out + (size_t)d * H + q * 4;
  unsafeAtomicAdd(o + 0, v.x);
  unsafeAtomicAdd(o + 1, v.y);
  unsafeAtomicAdd(o + 2, v.z);
  unsafeAtomicAdd(o + 3, v.w);
}

// ---------- gating + pooling + fc ----------
__global__ __launch_bounds__(256) void gate_dot(const float* __restrict__ X,
                                                const float* __restrict__ w2,
                                                const float* __restrict__ b2,
                                                float* __restrict__ gate, int n) {
  int wid = (blockIdx.x * 256 + threadIdx.x) >> 6;
  int lane = threadIdx.x & 63;
  if (wid >= n) return;
  const float* r = X + (size_t)wid * H;
  float a = fmaf(r[lane], w2[lane], r[lane + 64] * w2[lane + 64]);
#pragma unroll
  for (int off = 32; off; off >>= 1) a += __shfl_xor(a, off);
  if (lane == 0) gate[wid] = a + b2[0];
}
__global__ void pool_max(const float* __restrict__ gate, const int* __restrict__ batch,
                         unsigned* __restrict__ gmax, int n) {
  int i = blockIdx.x * 256 + threadIdx.x;
  if (i < n) atomicMax(&gmax[batch[i]], fenc(gate[i]));
}
__global__ void pool_exp(const float* __restrict__ gate, const int* __restrict__ batch,
                         const unsigned* __restrict__ gmax, float* __restrict__ gsum,
                         float* __restrict__ wb, int n) {
  int i = blockIdx.x * 256 + threadIdx.x;
  if (i < n) {
    int b = batch[i];
    float v = expf(gate[i] - fdec(gmax[b]));
    wb[i] = v;
    unsafeAtomicAdd(&gsum[b], v);
  }
}
__global__ void starts_kernel(const int* __restrict__ batch, int* __restrict__ starts, int n,
                              int G) {
  int i = blockIdx.x * 256 + threadIdx.x;
  if (i >= n) return;
  int b = batch[i];
  int bp = (i == 0) ? -1 : batch[i - 1];
  for (int g = bp + 1; g <= b; ++g) starts[g] = i;
  if (i == n - 1)
    for (int g = b + 1; g <= G; ++g) starts[g] = n;
}
__global__ __launch_bounds__(128) void pool_agg(const float* __restrict__ h,
                                                const float* __restrict__ wb,
                                                const int* __restrict__ starts,
                                                float* __restrict__ pooled) {
  int g = blockIdx.x >> 2, c = blockIdx.x & 3;
  int s0 = starts[g], s1 = starts[g + 1];
  int len = s1 - s0;
  int a = s0 + (int)((long long)len * c / 4);
  int b = s0 + (int)((long long)len * (c + 1) / 4);
  int d = threadIdx.x;
  float acc = 0.f;
  for (int i = a; i < b; ++i) acc = fmaf(wb[i], h[(size_t)i * H + d], acc);
  unsafeAtomicAdd(&pooled[g * H + d], acc);
}
__global__ __launch_bounds__(64) void fc_kernel(const float* __restrict__ pooled,
                                                const float* __restrict__ gsum,
                                                const float* __restrict__ fcW,
                                                const float* __restrict__ fcB,
                                                float* __restrict__ out) {
  int g = blockIdx.x, lane = threadIdx.x;
  float rg = 1.f / (gsum[g] + 1e-16f);
  float acc[OUTD];
#pragma unroll
  for (int j = 0; j < OUTD; ++j) acc[j] = 0.f;
#pragma unroll
  for (int t = 0; t < 2; ++t) {
    int k = lane + t * 64;
    float p = pooled[g * H + k] * rg;
#pragma unroll
    for (int j = 0; j < OUTD; ++j) acc[j] = fmaf(p, fcW[k * OUTD + j], acc[j]);
  }
#pragma unroll
  for (int j = 0; j < OUTD; ++j) {
#pragma unroll
    for (int off = 32; off; off >>= 1) acc[j] += __shfl_xor(acc[j], off);
  }
  if (lane == 0) {
    float o[OUTD], m = -1e30f;
#pragma unroll
    for (int j = 0; j < OUTD; ++j) {
      o[j] = acc[j] + fcB[j];
      m = fmaxf(m, o[j]);
    }
    float s = 0.f;
#pragma unroll
    for (int j = 0; j < OUTD; ++j) s += expf(o[j] - m);
    float lse = logf(s);
#pragma unroll
    for (int j = 0; j < OUTD; ++j) out[g * OUTD + j] = o[j] - m - lse;
  }
}

extern "C" void kernel_launch(void* const* d_in, const int* in_sizes, int n_in, void* d_out,
                              int out_size, void* d_ws, size_t ws_size, hipStream_t stream) {
  const float* x = (const float*)d_in[0];
  const int* ei = (const int*)d_in[1];
  const int* batch = (const int*)d_in[2];
  const float* gcnW = (const float*)d_in[3];
  const float* gcnB = (const float*)d_in[4];
  const float* gatW = (const float*)d_in[5];
  const float* attS = (const float*)d_in[6];
  const float* attD = (const float*)d_in[7];
  const float* gatB = (const float*)d_in[8];
  const float* ecW1 = (const float*)d_in[9];
  const float* ecB1 = (const float*)d_in[10];
  const float* ecW2 = (const float*)d_in[11];
  const float* ecB2 = (const float*)d_in[12];
  const float* ginW1 = (const float*)d_in[13];
  const float* ginB1 = (const float*)d_in[14];
  const float* ginW2 = (const float*)d_in[15];
  const float* ginB2 = (const float*)d_in[16];
  const float* gtW1 = (const float*)d_in[17];
  const float* gtB1 = (const float*)d_in[18];
  const float* gtW2 = (const float*)d_in[19];
  const float* gtB2 = (const float*)d_in[20];
  const float* fcW = (const float*)d_in[21];
  const float* fcB = (const float*)d_in[22];

  const int N = in_sizes[0] / H;
  const int E = in_sizes[1] / 2;
  const int G = out_size / OUTD;
  const size_t NH = (size_t)N * H;

  float* ws = (float*)d_ws;
  float* S0 = ws;
  float* S1 = S0 + NH;
  float* S2 = S1 + NH;
  float* S3 = S2 + NH;
  float* dinv = S3 + NH;                       // N
  float* asrc = dinv + N;                      // 4N
  float* adst = asrc + 4 * (size_t)N;          // 4N
  float* esum = adst + 4 * (size_t)N;          // 4N
  unsigned* emax = (unsigned*)(esum + 4 * (size_t)N);  // 4N
  float* ex = (float*)(emax + 4 * (size_t)N);  // 4*(E+N)
  float* Wa = ex + 4 * (size_t)(E + N);        // 16384
  float* Wb = Wa + H * H;                      // 16384
  float* gate = Wb + H * H;                    // N
  float* wb = gate + N;                        // N
  float* gsum = wb + N;                        // G
  unsigned* gmax = (unsigned*)(gsum + G);      // G
  float* pooled = (float*)(gmax + G);          // G*H
  int* starts = (int*)(pooled + (size_t)G * H);  // G+1

  const int gN = (N + 255) / 256;
  const int gNH = (int)((NH + 255) / 256);
  const int gE = (E + 255) / 256;
  const int gE32 = (E * 32 + 255) / 256;
  const int gEL4 = ((E + N) * 4 + 255) / 256;
  const int gEL32 = ((E + N) * 32 + 255) / 256;
  const int gDense = (N + 63) / 64;

  // ---- GCN ----
  dense128<0, 0><<<gDense, 256, 0, stream>>>(x, gcnW, nullptr, S0, N);
  deg_init<<<gN, 256, 0, stream>>>(dinv, N);
  deg_scatter<<<gE, 256, 0, stream>>>(ei, dinv, E);
  deg_rsqrt<<<gN, 256, 0, stream>>>(dinv, N);
  gcn_self<<<gNH, 256, 0, stream>>>(S0, dinv, S1, NH);
  scatter_norm<<<gE32, 256, 0, stream>>>(S0, ei, dinv, S1, E);
  bias_relu<<<gNH, 256, 0, stream>>>(S1, gcnB, NH);

  // ---- GAT ----
  dense128<0, 0><<<gDense, 256, 0, stream>>>(S1, gatW, nullptr, S2, N);
  att_pre<<<(N * 4 + 255) / 256, 256, 0, stream>>>(S2, attS, attD, asrc, adst, N);
  hipMemsetAsync(emax, 0, (size_t)4 * N * 4, stream);
  hipMemsetAsync(esum, 0, (size_t)4 * N * 4, stream);
  gat_max<<<gEL4, 256, 0, stream>>>(asrc, adst, ei, emax, E, N);
  gat_exp<<<gEL4, 256, 0, stream>>>(asrc, adst, ei, emax, esum, ex, E, N);
  hipMemsetAsync(S0, 0, NH * 4, stream);
  gat_agg<<<gEL32, 256, 0, stream>>>(S2, ei, ex, esum, S0, E, N);
  bias_elu<<<gNH, 256, 0, stream>>>(S0, gatB, NH);

  // ---- EdgeConv ----
  ec_prep<<<(H * H + 255) / 256, 256, 0, stream>>>(ecW1, Wa, Wb);
  dense128<0, 0><<<gDense, 256, 0, stream>>>(S0, Wa, nullptr, S1, N);
  dense128<0, 0><<<gDense, 256, 0, stream>>>(S0, Wb, nullptr, S2, N);
  fill_u32<<<gNH, 256, 0, stream>>>((unsigned*)S3, 0x80000000u, NH);
  edgeconv<<<2048, 256, 0, stream>>>(S1, S2, ei, ecB1, ecW2, ecB2, (unsigned*)S3, E);
  ec_decode<<<gNH, 256, 0, stream>>>((unsigned*)S3, S0, NH);

  // ---- GIN ----
  scatter_add<<<gE32, 256, 0, stream>>>(S3, ei, S0, E);
  dense128<1, 1><<<gDense, 256, 0, stream>>>(S0, ginW1, ginB1, S1, N);
  dense128<1, 1><<<gDense, 256, 0, stream>>>(S1, ginW2, ginB2, S2, N);  // h4 = S2

  // ---- gating + pooling ----
  dense128<1, 1><<<gDense, 256, 0, stream>>>(S2, gtW1, gtB1, S0, N);
  gate_dot<<<(N * 64 + 255) / 256, 256, 0, stream>>>(S0, gtW2, gtB2, gate, N);
  hipMemsetAsync(gmax, 0, (size_t)G * 4, stream);
  hipMemsetAsync(gsum, 0, (size_t)G * 4, stream);
  pool_max<<<gN, 256, 0, stream>>>(gate, batch, gmax, N);
  pool_exp<<<gN, 256, 0, stream>>>(gate, batch, gmax, gsum, wb, N);
  starts_kernel<<<gN, 256, 0, stream>>>(batch, starts, N, G);
  hipMemsetAsync(pooled, 0, (size_t)G * H * 4, stream);
  pool_agg<<<G * 4, 128, 0, stream>>>(S2, wb, starts, pooled);
  fc_kernel<<<G, 64, 0, stream>>>(pooled, gsum, fcW, fcB, (float*)d_out);
}

// Round 2
// 3925.615 us; speedup vs baseline: 2.6699x; 2.6699x over previous
//
#include <hip/hip_runtime.h>

#define H 128
#define OUTD 10

// ---------- ordered-float encoding for atomic max ----------
__device__ __forceinline__ unsigned fenc(float x) {
  unsigned u = __float_as_uint(x);
  return (u & 0x80000000u) ? ~u : (u | 0x80000000u);
}
__device__ __forceinline__ float fdec(unsigned u) {
  u = (u & 0x80000000u) ? (u & 0x7fffffffu) : ~u;
  return __uint_as_float(u);
}

// ---------- generic [n,128] @ [128,128] GEMM, staged rows in LDS, scalar W ----------
template <int RELU, int BIAS>
__global__ __launch_bounds__(256) void dense128(const float* __restrict__ X,
                                                const float* __restrict__ W,
                                                const float* __restrict__ bias,
                                                float* __restrict__ Y, int n) {
  __shared__ float tl[128][65];
  const int tid = threadIdx.x, lane = tid & 63, wave = tid >> 6;
  for (int base = blockIdx.x * 64; base < n; base += gridDim.x * 64) {
    const int nr = min(64, n - base);
    __syncthreads();
#pragma unroll
    for (int p = 0; p < 32; ++p) {
      int flat = p * 256 + tid;
      int r = flat >> 7, k = flat & 127;
      if (r < nr) tl[k][r] = X[(size_t)(base + r) * H + k];
    }
    __syncthreads();
    const int jb = wave * 32;
    float acc[32];
#pragma unroll
    for (int j = 0; j < 32; ++j) acc[j] = 0.f;
    for (int k = 0; k < 128; ++k) {
      float tk = tl[k][lane];
#pragma unroll
      for (int j = 0; j < 32; ++j) acc[j] = fmaf(tk, W[k * H + jb + j], acc[j]);
    }
    if (lane < nr) {
      size_t o = (size_t)(base + lane) * H + jb;
#pragma unroll
      for (int j = 0; j < 32; ++j) {
        float y = acc[j];
        if (BIAS) y += bias[jb + j];
        if (RELU) y = fmaxf(y, 0.f);
        Y[o + j] = y;
      }
    }
  }
}

// ---------- CSR build ----------
__global__ void zero_int(int* p, int n) {
  int i = blockIdx.x * 256 + threadIdx.x;
  if (i < n) p[i] = 0;
}
__global__ void csr_count(const int* __restrict__ ei, int* __restrict__ cnt, int E) {
  int e = blockIdx.x * 256 + threadIdx.x;
  if (e < E) atomicAdd(&cnt[ei[(size_t)E + e]], 1);
}
__global__ __launch_bounds__(1024) void scan50k(const int* __restrict__ cnt,
                                                int* __restrict__ row_ptr, int n) {
  __shared__ int ls[1024];
  int t = threadIdx.x;
  int chunk = (n + 1023) >> 10;
  int a = t * chunk;
  if (a > n) a = n;
  int b = a + chunk;
  if (b > n) b = n;
  int s = 0;
  for (int i = a; i < b; ++i) s += cnt[i];
  ls[t] = s;
  __syncthreads();
  for (int off = 1; off < 1024; off <<= 1) {
    int v = (t >= off) ? ls[t - off] : 0;
    __syncthreads();
    ls[t] += v;
    __syncthreads();
  }
  int run = (t > 0) ? ls[t - 1] : 0;
  for (int i = a; i < b; ++i) {
    row_ptr[i] = run;
    run += cnt[i];
  }
  if (t == 1023) row_ptr[n] = ls[1023];
}
__global__ void copy_int(const int* __restrict__ a, int* __restrict__ b, int n) {
  int i = blockIdx.x * 256 + threadIdx.x;
  if (i < n) b[i] = a[i];
}
__global__ void csr_fill(const int* __restrict__ ei, int* __restrict__ cursor,
                         int* __restrict__ csr_src, int* __restrict__ csr_dst, int E) {
  int e = blockIdx.x * 256 + threadIdx.x;
  if (e >= E) return;
  int s = ei[e], d = ei[(size_t)E + e];
  int p = atomicAdd(&cursor[d], 1);
  csr_src[p] = s;
  csr_dst[p] = d;
}
__global__ void dinv_kernel(const int* __restrict__ row_ptr, float* __restrict__ dinv, int n) {
  int i = blockIdx.x * 256 + threadIdx.x;
  if (i < n) dinv[i] = rsqrtf((float)(1 + row_ptr[i + 1] - row_ptr[i]));
}

// ---------- per-node gathers (no atomics) ----------
__global__ __launch_bounds__(128) void gcn_gather(const float* __restrict__ h,
                                                  const float* __restrict__ dinv,
                                                  const int* __restrict__ row_ptr,
                                                  const int* __restrict__ csr_src,
                                                  const float* __restrict__ bias,
                                                  float* __restrict__ out, int n) {
  int i = blockIdx.x, c = threadIdx.x;
  float di = dinv[i];
  float t = h[(size_t)i * H + c] * di;
  int a = row_ptr[i], b = row_ptr[i + 1];
  for (int e = a; e < b; ++e) {
    int s = csr_src[e];
    t = fmaf(h[(size_t)s * H + c], dinv[s], t);
  }
  out[(size_t)i * H + c] = fmaxf(fmaf(t, di, bias[c]), 0.f);
}

__global__ __launch_bounds__(128) void gat_gather(const float* __restrict__ g,
                                                  const float* __restrict__ asrc,
                                                  const float* __restrict__ adst,
                                                  const int* __restrict__ row_ptr,
                                                  const int* __restrict__ csr_src,
                                                  const float* __restrict__ bias,
                                                  float* __restrict__ out, int n) {
  __shared__ float red[128];
  int i = blockIdx.x, t = threadIdx.x;
  int a = row_ptr[i], b = row_ptr[i + 1];
  // phase A: per-head max over self + in-edges
  int hd = t & 3;
  float ad = adst[i * 4 + hd];
  float lm = -1e30f;
  if (t < 4) {
    float v = asrc[i * 4 + hd] + ad;
    lm = v > 0.f ? v : 0.2f * v;
  }
  for (int e = a + (t >> 2); e < b; e += 32) {
    int s = csr_src[e];
    float v = asrc[s * 4 + hd] + ad;
    v = v > 0.f ? v : 0.2f * v;
    lm = fmaxf(lm, v);
  }
  red[t] = lm;
  __syncthreads();
  for (int off = 64; off >= 4; off >>= 1) {
    if (t < off) red[t] = fmaxf(red[t], red[t + off]);
    __syncthreads();
  }
  // phase B: channel-parallel exp-weighted aggregate
  int c = t;
  int chd = c >> 5;
  float mh = red[chd];
  float adc = adst[i * 4 + chd];
  float es = asrc[i * 4 + chd] + adc;
  es = es > 0.f ? es : 0.2f * es;
  float w = __expf(es - mh);
  float acc = w * g[(size_t)i * H + c];
  float wsum = w;
  for (int e = a; e < b; ++e) {
    int s = csr_src[e];
    float ev = asrc[s * 4 + chd] + adc;
    ev = ev > 0.f ? ev : 0.2f * ev;
    w = __expf(ev - mh);
    acc = fmaf(w, g[(size_t)s * H + c], acc);
    wsum += w;
  }
  float r = acc / (wsum + 1e-16f) + bias[c];
  out[(size_t)i * H + c] = r > 0.f ? r : expm1f(r);
}

__global__ __launch_bounds__(128) void gin_gather(const float* __restrict__ h,
                                                  const int* __restrict__ row_ptr,
                                                  const int* __restrict__ csr_src,
                                                  float* __restrict__ out, int n) {
  int i = blockIdx.x, c = threadIdx.x;
  float acc = h[(size_t)i * H + c];
  int a = row_ptr[i], b = row_ptr[i + 1];
  for (int e = a; e < b; ++e) acc += h[(size_t)csr_src[e] * H + c];
  out[(size_t)i * H + c] = acc;
}

// ---------- misc ----------
__global__ void fill_u32(unsigned* p, unsigned v, size_t n) {
  size_t i = (size_t)blockIdx.x * 256 + threadIdx.x;
  if (i < n) p[i] = v;
}
__global__ void att_pre(const float* __restrict__ g, const float* __restrict__ attS,
                        const float* __restrict__ attD, float* __restrict__ asrc,
                        float* __restrict__ adst, int n) {
  int t = blockIdx.x * 256 + threadIdx.x;
  if (t >= n * 4) return;
  int i = t >> 2, hd = t & 3;
  const float* gr = g + (size_t)i * H + hd * 32;
  float s1 = 0.f, s2 = 0.f;
#pragma unroll
  for (int c = 0; c < 32; ++c) {
    float gv = gr[c];
    s1 = fmaf(gv, attS[hd * 32 + c], s1);
    s2 = fmaf(gv, attD[hd * 32 + c], s2);
  }
  asrc[t] = s1;
  adst[t] = s2;
}
__global__ void ec_prep(const float* __restrict__ W1, float* __restrict__ Wa,
                        float* __restrict__ Wb) {
  int i = blockIdx.x * 256 + threadIdx.x;
  if (i < H * H) {
    float top = W1[i], bot = W1[H * H + i];
    Wa[i] = top - bot;
    Wb[i] = bot;
  }
}

// ---------- EdgeConv over CSR-ordered edges, segmented max in-block ----------
__global__ __launch_bounds__(256) void edgeconv_csr(const float* __restrict__ A,
                                                    const float* __restrict__ Bm,
                                                    const int* __restrict__ csr_src,
                                                    const int* __restrict__ csr_dst,
                                                    const float* __restrict__ W2,
                                                    const float* __restrict__ b2,
                                                    unsigned* __restrict__ hec, int E) {
  __shared__ float tl[128][65];
  __shared__ int dsts[64];
  const int tid = threadIdx.x, lane = tid & 63, wave = tid >> 6;
  const float b2c = (tid < 128) ? b2[tid] : 0.f;
  for (int base = blockIdx.x * 64; base < E; base += gridDim.x * 64) {
    const int ne = min(64, E - base);
    __syncthreads();
#pragma unroll
    for (int p = 0; p < 32; ++p) {
      int flat = p * 256 + tid;
      int r = flat >> 7, k = flat & 127;
      if (r < ne) {
        int s = csr_src[base + r], d = csr_dst[base + r];
        tl[k][r] = fmaxf(A[(size_t)d * H + k] + Bm[(size_t)s * H + k], 0.f);
      }
    }
    if (tid < ne) dsts[tid] = csr_dst[base + tid];
    __syncthreads();
    const int jb = wave * 32;
    float acc[32];
#pragma unroll
    for (int j = 0; j < 32; ++j) acc[j] = 0.f;
    for (int k = 0; k < 128; ++k) {
      float tk = tl[k][lane];
#pragma unroll
      for (int j = 0; j < 32; ++j) acc[j] = fmaf(tk, W2[k * H + jb + j], acc[j]);
    }
    __syncthreads();
    float* lds2 = &tl[0][0];  // reuse as [64][129]
#pragma unroll
    for (int j = 0; j < 32; ++j) lds2[lane * 129 + jb + j] = acc[j];
    __syncthreads();
    if (tid < 128) {
      const int c = tid;
      int cur = dsts[0];
      float m = lds2[c];
      for (int r = 1; r < ne; ++r) {
        int d = dsts[r];
        float v = lds2[r * 129 + c];
        if (d != cur) {
          atomicMax(&hec[(size_t)cur * H + c], fenc(m + b2c));
          cur = d;
          m = v;
        } else {
          m = fmaxf(m, v);
        }
      }
      atomicMax(&hec[(size_t)cur * H + c], fenc(m + b2c));
    }
  }
}
__global__ void ec_decode(unsigned* __restrict__ hec, size_t nh) {
  size_t i = (size_t)blockIdx.x * 256 + threadIdx.x;
  if (i < nh) ((float*)hec)[i] = fdec(hec[i]);
}

// ---------- gating + pooling + fc ----------
__global__ __launch_bounds__(256) void gate_dot(const float* __restrict__ X,
                                                const float* __restrict__ w2,
                                                const float* __restrict__ b2,
                                                float* __restrict__ gate, int n) {
  int wid = (blockIdx.x * 256 + threadIdx.x) >> 6;
  int lane = threadIdx.x & 63;
  if (wid >= n) return;
  const float* r = X + (size_t)wid * H;
  float a = fmaf(r[lane], w2[lane], r[lane + 64] * w2[lane + 64]);
#pragma unroll
  for (int off = 32; off; off >>= 1) a += __shfl_xor(a, off);
  if (lane == 0) gate[wid] = a + b2[0];
}
__global__ void pool_max(const float* __restrict__ gate, const int* __restrict__ batch,
                         unsigned* __restrict__ gmax, int n) {
  int i = blockIdx.x * 256 + threadIdx.x;
  if (i < n) atomicMax(&gmax[batch[i]], fenc(gate[i]));
}
__global__ void pool_exp(const float* __restrict__ gate, const int* __restrict__ batch,
                         const unsigned* __restrict__ gmax, float* __restrict__ gsum,
                         float* __restrict__ wb, int n) {
  int i = blockIdx.x * 256 + threadIdx.x;
  if (i < n) {
    int b = batch[i];
    float v = expf(gate[i] - fdec(gmax[b]));
    wb[i] = v;
    unsafeAtomicAdd(&gsum[b], v);
  }
}
__global__ void starts_kernel(const int* __restrict__ batch, int* __restrict__ starts, int n,
                              int G) {
  int i = blockIdx.x * 256 + threadIdx.x;
  if (i >= n) return;
  int b = batch[i];
  int bp = (i == 0) ? -1 : batch[i - 1];
  for (int g = bp + 1; g <= b; ++g) starts[g] = i;
  if (i == n - 1)
    for (int g = b + 1; g <= G; ++g) starts[g] = n;
}
__global__ __launch_bounds__(128) void pool_agg(const float* __restrict__ h,
                                                const float* __restrict__ wb,
                                                const int* __restrict__ starts,
                                                float* __restrict__ pooled) {
  int g = blockIdx.x >> 2, c = blockIdx.x & 3;
  int s0 = starts[g], s1 = starts[g + 1];
  int len = s1 - s0;
  int a = s0 + (int)((long long)len * c / 4);
  int b = s0 + (int)((long long)len * (c + 1) / 4);
  int d = threadIdx.x;
  float acc = 0.f;
  for (int i = a; i < b; ++i) acc = fmaf(wb[i], h[(size_t)i * H + d], acc);
  unsafeAtomicAdd(&pooled[g * H + d], acc);
}
__global__ __launch_bounds__(64) void fc_kernel(const float* __restrict__ pooled,
                                                const float* __restrict__ gsum,
                                                const float* __restrict__ fcW,
                                                const float* __restrict__ fcB,
                                                float* __restrict__ out) {
  int g = blockIdx.x, lane = threadIdx.x;
  float rg = 1.f / (gsum[g] + 1e-16f);
  float acc[OUTD];
#pragma unroll
  for (int j = 0; j < OUTD; ++j) acc[j] = 0.f;
#pragma unroll
  for (int t = 0; t < 2; ++t) {
    int k = lane + t * 64;
    float p = pooled[g * H + k] * rg;
#pragma unroll
    for (int j = 0; j < OUTD; ++j) acc[j] = fmaf(p, fcW[k * OUTD + j], acc[j]);
  }
#pragma unroll
  for (int j = 0; j < OUTD; ++j) {
#pragma unroll
    for (int off = 32; off; off >>= 1) acc[j] += __shfl_xor(acc[j], off);
  }
  if (lane == 0) {
    float o[OUTD], m = -1e30f;
#pragma unroll
    for (int j = 0; j < OUTD; ++j) {
      o[j] = acc[j] + fcB[j];
      m = fmaxf(m, o[j]);
    }
    float s = 0.f;
#pragma unroll
    for (int j = 0; j < OUTD; ++j) s += expf(o[j] - m);
    float lse = logf(s);
#pragma unroll
    for (int j = 0; j < OUTD; ++j) out[g * OUTD + j] = o[j] - m - lse;
  }
}

extern "C" void kernel_launch(void* const* d_in, const int* in_sizes, int n_in, void* d_out,
                              int out_size, void* d_ws, size_t ws_size, hipStream_t stream) {
  const float* x = (const float*)d_in[0];
  const int* ei = (const int*)d_in[1];
  const int* batch = (const int*)d_in[2];
  const float* gcnW = (const float*)d_in[3];
  const float* gcnB = (const float*)d_in[4];
  const float* gatW = (const float*)d_in[5];
  const float* attS = (const float*)d_in[6];
  const float* attD = (const float*)d_in[7];
  const float* gatB = (const float*)d_in[8];
  const float* ecW1 = (const float*)d_in[9];
  const float* ecB1 = (const float*)d_in[10];
  const float* ecW2 = (const float*)d_in[11];
  const float* ecB2 = (const float*)d_in[12];
  const float* ginW1 = (const float*)d_in[13];
  const float* ginB1 = (const float*)d_in[14];
  const float* ginW2 = (const float*)d_in[15];
  const float* ginB2 = (const float*)d_in[16];
  const float* gtW1 = (const float*)d_in[17];
  const float* gtB1 = (const float*)d_in[18];
  const float* gtW2 = (const float*)d_in[19];
  const float* gtB2 = (const float*)d_in[20];
  const float* fcW = (const float*)d_in[21];
  const float* fcB = (const float*)d_in[22];

  const int N = in_sizes[0] / H;
  const int E = in_sizes[1] / 2;
  const int G = out_size / OUTD;
  const size_t NH = (size_t)N * H;

  float* ws = (float*)d_ws;
  float* S0 = ws;
  float* S1 = S0 + NH;
  float* S2 = S1 + NH;
  float* S3 = S2 + NH;
  float* dinv = S3 + NH;                 // N
  float* asrc = dinv + N;                // 4N
  float* adst = asrc + 4 * (size_t)N;    // 4N
  float* Wa = adst + 4 * (size_t)N;      // 16384
  float* Wb = Wa + H * H;                // 16384
  float* gate = Wb + H * H;              // N
  float* wb = gate + N;                  // N
  float* gsum = wb + N;                  // G
  unsigned* gmax = (unsigned*)(gsum + G);  // G
  float* pooled = (float*)(gmax + G);      // G*H
  int* starts = (int*)(pooled + (size_t)G * H);  // G+1
  int* cnt = starts + (G + 1);           // N
  int* row_ptr = cnt + N;                // N+1
  int* cursor = row_ptr + N + 1;         // N
  int* csr_src = cursor + N;             // E
  int* csr_dst = csr_src + E;            // E

  const int gN = (N + 255) / 256;
  const int gNH = (int)((NH + 255) / 256);
  const int gE = (E + 255) / 256;
  const int gDense = (N + 63) / 64;

  // ---- CSR build (sorted by dst) ----
  zero_int<<<gN, 256, 0, stream>>>(cnt, N);
  csr_count<<<gE, 256, 0, stream>>>(ei, cnt, E);
  scan50k<<<1, 1024, 0, stream>>>(cnt, row_ptr, N);
  copy_int<<<gN, 256, 0, stream>>>(row_ptr, cursor, N);
  csr_fill<<<gE, 256, 0, stream>>>(ei, cursor, csr_src, csr_dst, E);
  dinv_kernel<<<gN, 256, 0, stream>>>(row_ptr, dinv, N);

  // ---- GCN ----
  dense128<0, 0><<<gDense, 256, 0, stream>>>(x, gcnW, nullptr, S0, N);
  gcn_gather<<<N, 128, 0, stream>>>(S0, dinv, row_ptr, csr_src, gcnB, S1, N);

  // ---- GAT ----
  dense128<0, 0><<<gDense, 256, 0, stream>>>(S1, gatW, nullptr, S2, N);
  att_pre<<<(N * 4 + 255) / 256, 256, 0, stream>>>(S2, attS, attD, asrc, adst, N);
  gat_gather<<<N, 128, 0, stream>>>(S2, asrc, adst, row_ptr, csr_src, gatB, S0, N);

  // ---- EdgeConv ----
  ec_prep<<<(H * H + 255) / 256, 256, 0, stream>>>(ecW1, Wa, Wb);
  dense128<0, 0><<<gDense, 256, 0, stream>>>(S0, Wa, nullptr, S1, N);
  dense128<0, 1><<<gDense, 256, 0, stream>>>(S0, Wb, ecB1, S2, N);
  fill_u32<<<gNH, 256, 0, stream>>>((unsigned*)S3, 0x80000000u, NH);
  edgeconv_csr<<<2048, 256, 0, stream>>>(S1, S2, csr_src, csr_dst, ecW2, ecB2, (unsigned*)S3, E);
  ec_decode<<<gNH, 256, 0, stream>>>((unsigned*)S3, NH);

  // ---- GIN ----
  gin_gather<<<N, 128, 0, stream>>>(S3, row_ptr, csr_src, S0, N);
  dense128<1, 1><<<gDense, 256, 0, stream>>>(S0, ginW1, ginB1, S1, N);
  dense128<1, 1><<<gDense, 256, 0, stream>>>(S1, ginW2, ginB2, S2, N);  // h4 = S2

  // ---- gating + pooling ----
  dense128<1, 1><<<gDense, 256, 0, stream>>>(S2, gtW1, gtB1, S0, N);
  gate_dot<<<(N * 64 + 255) / 256, 256, 0, stream>>>(S0, gtW2, gtB2, gate, N);
  hipMemsetAsync(gmax, 0, (size_t)G * 4, stream);
  hipMemsetAsync(gsum, 0, (size_t)G * 4, stream);
  pool_max<<<gN, 256, 0, stream>>>(gate, batch, gmax, N);
  pool_exp<<<gN, 256, 0, stream>>>(gate, batch, gmax, gsum, wb, N);
  starts_kernel<<<gN, 256, 0, stream>>>(batch, starts, N, G);
  hipMemsetAsync(pooled, 0, (size_t)G * H * 4, stream);
  pool_agg<<<G * 4, 128, 0, stream>>>(S2, wb, starts, pooled);
  fc_kernel<<<G, 64, 0, stream>>>(pooled, gsum, fcW, fcB, (float*)d_out);
}

// Round 3
// 1451.801 us; speedup vs baseline: 7.2194x; 2.7040x over previous
//
#include <hip/hip_runtime.h>

#define H 128
#define OUTD 10

typedef short bf16x8 __attribute__((ext_vector_type(8)));
typedef float f32x4 __attribute__((ext_vector_type(4)));

// ---------- bf16 helpers ----------
__device__ __forceinline__ unsigned short f2bf(float x) {
  unsigned u = __float_as_uint(x);
  u += 0x7fffu + ((u >> 16) & 1u);  // RNE
  return (unsigned short)(u >> 16);
}
__device__ __forceinline__ unsigned pack2bf(float a, float b) {
  return (unsigned)f2bf(a) | ((unsigned)f2bf(b) << 16);
}
__device__ __forceinline__ float bf2f(unsigned short u) {
  return __uint_as_float(((unsigned)u) << 16);
}

// ---------- ordered-float encoding for atomic max ----------
__device__ __forceinline__ unsigned fenc(float x) {
  unsigned u = __float_as_uint(x);
  return (u & 0x80000000u) ? ~u : (u | 0x80000000u);
}
__device__ __forceinline__ float fdec(unsigned u) {
  u = (u & 0x80000000u) ? (u & 0x7fffffffu) : ~u;
  return __uint_as_float(u);
}

// ---------- MFMA [n,128] @ [128,128] GEMM, bf16 inputs / f32 accum ----------
template <int RELU, int BIAS>
__global__ __launch_bounds__(256) void dense128_mfma(const float* __restrict__ X,
                                                     const float* __restrict__ W,
                                                     const float* __restrict__ bias,
                                                     float* __restrict__ Y, int n) {
  __shared__ unsigned short wt[128][136];   // W^T bf16, pad 8 -> 2-way conflicts (free)
  __shared__ unsigned short tile[64][136];  // X tile bf16
  const int tid = threadIdx.x, lane = tid & 63, wave = tid >> 6;
  const int jl = lane & 15, kg = lane >> 4;
  for (int f = tid; f < H * H; f += 256) {  // f = k*128 + j
    int k = f >> 7, j = f & 127;
    wt[j][k] = f2bf(W[f]);
  }
  __syncthreads();
  for (int base = blockIdx.x * 64; base < n; base += gridDim.x * 64) {
    const int nr = min(64, n - base);
    __syncthreads();
    for (int f = tid; f < 4096; f += 256) {  // 64 rows x 64 float2
      int r = f >> 6, kp = f & 63;
      if (r < nr) {
        float2 v = *(const float2*)&X[(size_t)(base + r) * H + 2 * kp];
        *(unsigned*)&tile[r][2 * kp] = pack2bf(v.x, v.y);
      }
    }
    __syncthreads();
    bf16x8 afrag[4];
#pragma unroll
    for (int kk = 0; kk < 4; ++kk)
      afrag[kk] = *(const bf16x8*)&tile[wave * 16 + jl][kk * 32 + kg * 8];
#pragma unroll
    for (int jt = 0; jt < 8; ++jt) {
      f32x4 c = {0.f, 0.f, 0.f, 0.f};
#pragma unroll
      for (int kk = 0; kk < 4; ++kk) {
        bf16x8 bf = *(const bf16x8*)&wt[jt * 16 + jl][kk * 32 + kg * 8];
        c = __builtin_amdgcn_mfma_f32_16x16x32_bf16(afrag[kk], bf, c, 0, 0, 0);
      }
      const int col = jt * 16 + jl;
      const float bb = BIAS ? bias[col] : 0.f;
#pragma unroll
      for (int r = 0; r < 4; ++r) {
        int row = wave * 16 + kg * 4 + r;
        if (row < nr) {
          float y = c[r] + bb;
          if (RELU) y = fmaxf(y, 0.f);
          Y[(size_t)(base + row) * H + col] = y;
        }
      }
    }
  }
}

// ---------- CSR build ----------
__global__ void zero_int(int* p, int n) {
  int i = blockIdx.x * 256 + threadIdx.x;
  if (i < n) p[i] = 0;
}
__global__ void csr_count(const int* __restrict__ ei, int* __restrict__ cnt, int E) {
  int e = blockIdx.x * 256 + threadIdx.x;
  if (e < E) atomicAdd(&cnt[ei[(size_t)E + e]], 1);
}
__global__ __launch_bounds__(1024) void scan50k(const int* __restrict__ cnt,
                                                int* __restrict__ row_ptr, int n) {
  __shared__ int ls[1024];
  int t = threadIdx.x;
  int chunk = (n + 1023) >> 10;
  int a = t * chunk;
  if (a > n) a = n;
  int b = a + chunk;
  if (b > n) b = n;
  int s = 0;
  for (int i = a; i < b; ++i) s += cnt[i];
  ls[t] = s;
  __syncthreads();
  for (int off = 1; off < 1024; off <<= 1) {
    int v = (t >= off) ? ls[t - off] : 0;
    __syncthreads();
    ls[t] += v;
    __syncthreads();
  }
  int run = (t > 0) ? ls[t - 1] : 0;
  for (int i = a; i < b; ++i) {
    row_ptr[i] = run;
    run += cnt[i];
  }
  if (t == 1023) row_ptr[n] = ls[1023];
}
__global__ void copy_int(const int* __restrict__ a, int* __restrict__ b, int n) {
  int i = blockIdx.x * 256 + threadIdx.x;
  if (i < n) b[i] = a[i];
}
__global__ void csr_fill(const int* __restrict__ ei, int* __restrict__ cursor,
                         int* __restrict__ csr_src, int* __restrict__ csr_dst, int E) {
  int e = blockIdx.x * 256 + threadIdx.x;
  if (e >= E) return;
  int s = ei[e], d = ei[(size_t)E + e];
  int p = atomicAdd(&cursor[d], 1);
  csr_src[p] = s;
  csr_dst[p] = d;
}
__global__ void dinv_kernel(const int* __restrict__ row_ptr, float* __restrict__ dinv, int n) {
  int i = blockIdx.x * 256 + threadIdx.x;
  if (i < n) dinv[i] = rsqrtf((float)(1 + row_ptr[i + 1] - row_ptr[i]));
}

// ---------- per-node gathers (no atomics) ----------
__global__ __launch_bounds__(128) void gcn_gather(const float* __restrict__ h,
                                                  const float* __restrict__ dinv,
                                                  const int* __restrict__ row_ptr,
                                                  const int* __restrict__ csr_src,
                                                  const float* __restrict__ bias,
                                                  float* __restrict__ out, int n) {
  int i = blockIdx.x, c = threadIdx.x;
  float di = dinv[i];
  float t = h[(size_t)i * H + c] * di;
  int a = row_ptr[i], b = row_ptr[i + 1];
  for (int e = a; e < b; ++e) {
    int s = csr_src[e];
    t = fmaf(h[(size_t)s * H + c], dinv[s], t);
  }
  out[(size_t)i * H + c] = fmaxf(fmaf(t, di, bias[c]), 0.f);
}

__global__ __launch_bounds__(128) void gat_gather(const float* __restrict__ g,
                                                  const float* __restrict__ asrc,
                                                  const float* __restrict__ adst,
                                                  const int* __restrict__ row_ptr,
                                                  const int* __restrict__ csr_src,
                                                  const float* __restrict__ bias,
                                                  float* __restrict__ out, int n) {
  __shared__ float red[128];
  int i = blockIdx.x, t = threadIdx.x;
  int a = row_ptr[i], b = row_ptr[i + 1];
  int hd = t & 3;
  float ad = adst[i * 4 + hd];
  float lm = -1e30f;
  if (t < 4) {
    float v = asrc[i * 4 + hd] + ad;
    lm = v > 0.f ? v : 0.2f * v;
  }
  for (int e = a + (t >> 2); e < b; e += 32) {
    int s = csr_src[e];
    float v = asrc[s * 4 + hd] + ad;
    v = v > 0.f ? v : 0.2f * v;
    lm = fmaxf(lm, v);
  }
  red[t] = lm;
  __syncthreads();
  for (int off = 64; off >= 4; off >>= 1) {
    if (t < off) red[t] = fmaxf(red[t], red[t + off]);
    __syncthreads();
  }
  int c = t;
  int chd = c >> 5;
  float mh = red[chd];
  float adc = adst[i * 4 + chd];
  float es = asrc[i * 4 + chd] + adc;
  es = es > 0.f ? es : 0.2f * es;
  float w = __expf(es - mh);
  float acc = w * g[(size_t)i * H + c];
  float wsum = w;
  for (int e = a; e < b; ++e) {
    int s = csr_src[e];
    float ev = asrc[s * 4 + chd] + adc;
    ev = ev > 0.f ? ev : 0.2f * ev;
    w = __expf(ev - mh);
    acc = fmaf(w, g[(size_t)s * H + c], acc);
    wsum += w;
  }
  float r = acc / (wsum + 1e-16f) + bias[c];
  out[(size_t)i * H + c] = r > 0.f ? r : expm1f(r);
}

__global__ __launch_bounds__(128) void gin_gather(const float* __restrict__ h,
                                                  const int* __restrict__ row_ptr,
                                                  const int* __restrict__ csr_src,
                                                  float* __restrict__ out, int n) {
  int i = blockIdx.x, c = threadIdx.x;
  float acc = h[(size_t)i * H + c];
  int a = row_ptr[i], b = row_ptr[i + 1];
  for (int e = a; e < b; ++e) acc += h[(size_t)csr_src[e] * H + c];
  out[(size_t)i * H + c] = acc;
}

// ---------- misc ----------
__global__ void fill_u32(unsigned* p, unsigned v, size_t n) {
  size_t i = (size_t)blockIdx.x * 256 + threadIdx.x;
  if (i < n) p[i] = v;
}
__global__ void att_pre(const float* __restrict__ g, const float* __restrict__ attS,
                        const float* __restrict__ attD, float* __restrict__ asrc,
                        float* __restrict__ adst, int n) {
  int t = blockIdx.x * 256 + threadIdx.x;
  if (t >= n * 4) return;
  int i = t >> 2, hd = t & 3;
  const float* gr = g + (size_t)i * H + hd * 32;
  float s1 = 0.f, s2 = 0.f;
#pragma unroll
  for (int c = 0; c < 32; ++c) {
    float gv = gr[c];
    s1 = fmaf(gv, attS[hd * 32 + c], s1);
    s2 = fmaf(gv, attD[hd * 32 + c], s2);
  }
  asrc[t] = s1;
  adst[t] = s2;
}
__global__ void ec_prep(const float* __restrict__ W1, float* __restrict__ Wa,
                        float* __restrict__ Wb) {
  int i = blockIdx.x * 256 + threadIdx.x;
  if (i < H * H) {
    float top = W1[i], bot = W1[H * H + i];
    Wa[i] = top - bot;
    Wb[i] = bot;
  }
}

// ---------- EdgeConv: bf16 MFMA GEMM + in-block segmented max ----------
__global__ __launch_bounds__(256) void edgeconv_mfma(const float* __restrict__ A,
                                                     const float* __restrict__ Bm,
                                                     const int* __restrict__ csr_src,
                                                     const int* __restrict__ csr_dst,
                                                     const float* __restrict__ W2,
                                                     const float* __restrict__ b2,
                                                     unsigned* __restrict__ hec, int E) {
  __shared__ unsigned short w2t[128][136];  // W2^T bf16
  __shared__ unsigned short tile[64][136];  // msg tile bf16 (then output tile bf16)
  __shared__ int dsts[64];
  const int tid = threadIdx.x, lane = tid & 63, wave = tid >> 6;
  const int jl = lane & 15, kg = lane >> 4;
  for (int f = tid; f < H * H; f += 256) {
    int k = f >> 7, j = f & 127;
    w2t[j][k] = f2bf(W2[f]);
  }
  const float b2c = (tid < 128) ? b2[tid] : 0.f;
  __syncthreads();
  for (int base = blockIdx.x * 64; base < E; base += gridDim.x * 64) {
    const int ne = min(64, E - base);
    __syncthreads();
    for (int f = tid; f < 4096; f += 256) {  // 64 rows x 64 float2
      int r = f >> 6, kp = f & 63;
      if (r < ne) {
        int s = csr_src[base + r], d = csr_dst[base + r];
        float2 va = *(const float2*)&A[(size_t)d * H + 2 * kp];
        float2 vb = *(const float2*)&Bm[(size_t)s * H + 2 * kp];
        *(unsigned*)&tile[r][2 * kp] =
            pack2bf(fmaxf(va.x + vb.x, 0.f), fmaxf(va.y + vb.y, 0.f));
      }
    }
    if (tid < 64) dsts[tid] = (tid < ne) ? csr_dst[base + tid] : -1;
    __syncthreads();
    bf16x8 afrag[4];
#pragma unroll
    for (int kk = 0; kk < 4; ++kk)
      afrag[kk] = *(const bf16x8*)&tile[wave * 16 + jl][kk * 32 + kg * 8];
    f32x4 acc[8];
#pragma unroll
    for (int jt = 0; jt < 8; ++jt) {
      f32x4 c = {0.f, 0.f, 0.f, 0.f};
#pragma unroll
      for (int kk = 0; kk < 4; ++kk) {
        bf16x8 bf = *(const bf16x8*)&w2t[jt * 16 + jl][kk * 32 + kg * 8];
        c = __builtin_amdgcn_mfma_f32_16x16x32_bf16(afrag[kk], bf, c, 0, 0, 0);
      }
      acc[jt] = c;
    }
    // write outputs (bf16) back into tile: row=wave*16+kg*4+r, col=jt*16+jl
#pragma unroll
    for (int jt = 0; jt < 8; ++jt)
#pragma unroll
      for (int r = 0; r < 4; ++r)
        tile[wave * 16 + kg * 4 + r][jt * 16 + jl] = f2bf(acc[jt][r]);
    __syncthreads();
    if (tid < 128) {
      const int c = tid;
      int cur = dsts[0];
      float m = bf2f(tile[0][c]);
      for (int r = 1; r < ne; ++r) {
        int d = dsts[r];
        float v = bf2f(tile[r][c]);
        if (d != cur) {
          atomicMax(&hec[(size_t)cur * H + c], fenc(m + b2c));
          cur = d;
          m = v;
        } else {
          m = fmaxf(m, v);
        }
      }
      atomicMax(&hec[(size_t)cur * H + c], fenc(m + b2c));
    }
  }
}
__global__ void ec_decode(unsigned* __restrict__ hec, size_t nh) {
  size_t i = (size_t)blockIdx.x * 256 + threadIdx.x;
  if (i < nh) ((float*)hec)[i] = fdec(hec[i]);
}

// ---------- gating + pooling + fc ----------
__global__ __launch_bounds__(256) void gate_dot(const float* __restrict__ X,
                                                const float* __restrict__ w2,
                                                const float* __restrict__ b2,
                                                float* __restrict__ gate, int n) {
  int wid = (blockIdx.x * 256 + threadIdx.x) >> 6;
  int lane = threadIdx.x & 63;
  if (wid >= n) return;
  const float* r = X + (size_t)wid * H;
  float a = fmaf(r[lane], w2[lane], r[lane + 64] * w2[lane + 64]);
#pragma unroll
  for (int off = 32; off; off >>= 1) a += __shfl_xor(a, off);
  if (lane == 0) gate[wid] = a + b2[0];
}
__global__ void pool_max(const float* __restrict__ gate, const int* __restrict__ batch,
                         unsigned* __restrict__ gmax, int n) {
  int i = blockIdx.x * 256 + threadIdx.x;
  if (i < n) atomicMax(&gmax[batch[i]], fenc(gate[i]));
}
__global__ void pool_exp(const float* __restrict__ gate, const int* __restrict__ batch,
                         const unsigned* __restrict__ gmax, float* __restrict__ gsum,
                         float* __restrict__ wb, int n) {
  int i = blockIdx.x * 256 + threadIdx.x;
  if (i < n) {
    int b = batch[i];
    float v = expf(gate[i] - fdec(gmax[b]));
    wb[i] = v;
    unsafeAtomicAdd(&gsum[b], v);
  }
}
__global__ void starts_kernel(const int* __restrict__ batch, int* __restrict__ starts, int n,
                              int G) {
  int i = blockIdx.x * 256 + threadIdx.x;
  if (i >= n) return;
  int b = batch[i];
  int bp = (i == 0) ? -1 : batch[i - 1];
  for (int g = bp + 1; g <= b; ++g) starts[g] = i;
  if (i == n - 1)
    for (int g = b + 1; g <= G; ++g) starts[g] = n;
}
__global__ __launch_bounds__(128) void pool_agg(const float* __restrict__ h,
                                                const float* __restrict__ wb,
                                                const int* __restrict__ starts,
                                                float* __restrict__ pooled) {
  int g = blockIdx.x >> 2, c = blockIdx.x & 3;
  int s0 = starts[g], s1 = starts[g + 1];
  int len = s1 - s0;
  int a = s0 + (int)((long long)len * c / 4);
  int b = s0 + (int)((long long)len * (c + 1) / 4);
  int d = threadIdx.x;
  float acc = 0.f;
  for (int i = a; i < b; ++i) acc = fmaf(wb[i], h[(size_t)i * H + d], acc);
  unsafeAtomicAdd(&pooled[g * H + d], acc);
}
__global__ __launch_bounds__(64) void fc_kernel(const float* __restrict__ pooled,
                                                const float* __restrict__ gsum,
                                                const float* __restrict__ fcW,
                                                const float* __restrict__ fcB,
                                                float* __restrict__ out) {
  int g = blockIdx.x, lane = threadIdx.x;
  float rg = 1.f / (gsum[g] + 1e-16f);
  float acc[OUTD];
#pragma unroll
  for (int j = 0; j < OUTD; ++j) acc[j] = 0.f;
#pragma unroll
  for (int t = 0; t < 2; ++t) {
    int k = lane + t * 64;
    float p = pooled[g * H + k] * rg;
#pragma unroll
    for (int j = 0; j < OUTD; ++j) acc[j] = fmaf(p, fcW[k * OUTD + j], acc[j]);
  }
#pragma unroll
  for (int j = 0; j < OUTD; ++j) {
#pragma unroll
    for (int off = 32; off; off >>= 1) acc[j] += __shfl_xor(acc[j], off);
  }
  if (lane == 0) {
    float o[OUTD], m = -1e30f;
#pragma unroll
    for (int j = 0; j < OUTD; ++j) {
      o[j] = acc[j] + fcB[j];
      m = fmaxf(m, o[j]);
    }
    float s = 0.f;
#pragma unroll
    for (int j = 0; j < OUTD; ++j) s += expf(o[j] - m);
    float lse = logf(s);
#pragma unroll
    for (int j = 0; j < OUTD; ++j) out[g * OUTD + j] = o[j] - m - lse;
  }
}

extern "C" void kernel_launch(void* const* d_in, const int* in_sizes, int n_in, void* d_out,
                              int out_size, void* d_ws, size_t ws_size, hipStream_t stream) {
  const float* x = (const float*)d_in[0];
  const int* ei = (const int*)d_in[1];
  const int* batch = (const int*)d_in[2];
  const float* gcnW = (const float*)d_in[3];
  const float* gcnB = (const float*)d_in[4];
  const float* gatW = (const float*)d_in[5];
  const float* attS = (const float*)d_in[6];
  const float* attD = (const float*)d_in[7];
  const float* gatB = (const float*)d_in[8];
  const float* ecW1 = (const float*)d_in[9];
  const float* ecB1 = (const float*)d_in[10];
  const float* ecW2 = (const float*)d_in[11];
  const float* ecB2 = (const float*)d_in[12];
  const float* ginW1 = (const float*)d_in[13];
  const float* ginB1 = (const float*)d_in[14];
  const float* ginW2 = (const float*)d_in[15];
  const float* ginB2 = (const float*)d_in[16];
  const float* gtW1 = (const float*)d_in[17];
  const float* gtB1 = (const float*)d_in[18];
  const float* gtW2 = (const float*)d_in[19];
  const float* gtB2 = (const float*)d_in[20];
  const float* fcW = (const float*)d_in[21];
  const float* fcB = (const float*)d_in[22];

  const int N = in_sizes[0] / H;
  const int E = in_sizes[1] / 2;
  const int G = out_size / OUTD;
  const size_t NH = (size_t)N * H;

  float* ws = (float*)d_ws;
  float* S0 = ws;
  float* S1 = S0 + NH;
  float* S2 = S1 + NH;
  float* S3 = S2 + NH;
  float* dinv = S3 + NH;                 // N
  float* asrc = dinv + N;                // 4N
  float* adst = asrc + 4 * (size_t)N;    // 4N
  float* Wa = adst + 4 * (size_t)N;      // 16384
  float* Wb = Wa + H * H;                // 16384
  float* gate = Wb + H * H;              // N
  float* wb = gate + N;                  // N
  float* gsum = wb + N;                  // G
  unsigned* gmax = (unsigned*)(gsum + G);        // G
  float* pooled = (float*)(gmax + G);            // G*H
  int* starts = (int*)(pooled + (size_t)G * H);  // G+1
  int* cnt = starts + (G + 1);           // N
  int* row_ptr = cnt + N;                // N+1
  int* cursor = row_ptr + N + 1;         // N
  int* csr_src = cursor + N;             // E
  int* csr_dst = csr_src + E;            // E

  const int gN = (N + 255) / 256;
  const int gNH = (int)((NH + 255) / 256);
  const int gE = (E + 255) / 256;
  const int gDense = (N + 63) / 64;

  // ---- CSR build (sorted by dst) ----
  zero_int<<<gN, 256, 0, stream>>>(cnt, N);
  csr_count<<<gE, 256, 0, stream>>>(ei, cnt, E);
  scan50k<<<1, 1024, 0, stream>>>(cnt, row_ptr, N);
  copy_int<<<gN, 256, 0, stream>>>(row_ptr, cursor, N);
  csr_fill<<<gE, 256, 0, stream>>>(ei, cursor, csr_src, csr_dst, E);
  dinv_kernel<<<gN, 256, 0, stream>>>(row_ptr, dinv, N);

  // ---- GCN ----
  dense128_mfma<0, 0><<<gDense, 256, 0, stream>>>(x, gcnW, nullptr, S0, N);
  gcn_gather<<<N, 128, 0, stream>>>(S0, dinv, row_ptr, csr_src, gcnB, S1, N);

  // ---- GAT ----
  dense128_mfma<0, 0><<<gDense, 256, 0, stream>>>(S1, gatW, nullptr, S2, N);
  att_pre<<<(N * 4 + 255) / 256, 256, 0, stream>>>(S2, attS, attD, asrc, adst, N);
  gat_gather<<<N, 128, 0, stream>>>(S2, asrc, adst, row_ptr, csr_src, gatB, S0, N);

  // ---- EdgeConv ----
  ec_prep<<<(H * H + 255) / 256, 256, 0, stream>>>(ecW1, Wa, Wb);
  dense128_mfma<0, 0><<<gDense, 256, 0, stream>>>(S0, Wa, nullptr, S1, N);
  dense128_mfma<0, 1><<<gDense, 256, 0, stream>>>(S0, Wb, ecB1, S2, N);
  fill_u32<<<gNH, 256, 0, stream>>>((unsigned*)S3, 0x80000000u, NH);
  edgeconv_mfma<<<768, 256, 0, stream>>>(S1, S2, csr_src, csr_dst, ecW2, ecB2, (unsigned*)S3, E);
  ec_decode<<<gNH, 256, 0, stream>>>((unsigned*)S3, NH);

  // ---- GIN ----
  gin_gather<<<N, 128, 0, stream>>>(S3, row_ptr, csr_src, S0, N);
  dense128_mfma<1, 1><<<gDense, 256, 0, stream>>>(S0, ginW1, ginB1, S1, N);
  dense128_mfma<1, 1><<<gDense, 256, 0, stream>>>(S1, ginW2, ginB2, S2, N);  // h4 = S2

  // ---- gating + pooling ----
  dense128_mfma<1, 1><<<gDense, 256, 0, stream>>>(S2, gtW1, gtB1, S0, N);
  gate_dot<<<(N * 64 + 255) / 256, 256, 0, stream>>>(S0, gtW2, gtB2, gate, N);
  hipMemsetAsync(gmax, 0, (size_t)G * 4, stream);
  hipMemsetAsync(gsum, 0, (size_t)G * 4, stream);
  pool_max<<<gN, 256, 0, stream>>>(gate, batch, gmax, N);
  pool_exp<<<gN, 256, 0, stream>>>(gate, batch, gmax, gsum, wb, N);
  starts_kernel<<<gN, 256, 0, stream>>>(batch, starts, N, G);
  hipMemsetAsync(pooled, 0, (size_t)G * H * 4, stream);
  pool_agg<<<G * 4, 128, 0, stream>>>(S2, wb, starts, pooled);
  fc_kernel<<<G, 64, 0, stream>>>(pooled, gsum, fcW, fcB, (float*)d_out);
}

// Round 4
// 982.043 us; speedup vs baseline: 10.6728x; 1.4783x over previous
//
#include <hip/hip_runtime.h>

#define H 128
#define OUTD 10

typedef short bf16x8 __attribute__((ext_vector_type(8)));
typedef float f32x4 __attribute__((ext_vector_type(4)));

// ---------- bf16 helpers ----------
__device__ __forceinline__ unsigned short f2bf(float x) {
  unsigned u = __float_as_uint(x);
  u += 0x7fffu + ((u >> 16) & 1u);  // RNE
  return (unsigned short)(u >> 16);
}
__device__ __forceinline__ unsigned pack2bf(float a, float b) {
  return (unsigned)f2bf(a) | ((unsigned)f2bf(b) << 16);
}
__device__ __forceinline__ float bf2f(unsigned short u) {
  return __uint_as_float(((unsigned)u) << 16);
}
__device__ __forceinline__ float bflo(unsigned u) { return __uint_as_float(u << 16); }
__device__ __forceinline__ float bfhi(unsigned u) { return __uint_as_float(u & 0xffff0000u); }

// ---------- ordered-float encoding for atomic max ----------
__device__ __forceinline__ unsigned fenc(float x) {
  unsigned u = __float_as_uint(x);
  return (u & 0x80000000u) ? ~u : (u | 0x80000000u);
}
__device__ __forceinline__ float fdec(unsigned u) {
  u = (u & 0x80000000u) ? (u & 0x7fffffffu) : ~u;
  return __uint_as_float(u);
}

// ---------- weight prep: 8 matrices -> bf16 transposed [j][k] ----------
__global__ void prep_w(const float* __restrict__ gcnW, const float* __restrict__ gatW,
                       const float* __restrict__ ecW1, const float* __restrict__ ecW2,
                       const float* __restrict__ ginW1, const float* __restrict__ ginW2,
                       const float* __restrict__ gtW1, unsigned short* __restrict__ WT) {
  int f = blockIdx.x * 256 + threadIdx.x;
  if (f >= 8 * 16384) return;
  int m = f >> 14, idx = f & 16383;
  int j = idx >> 7, k = idx & 127;
  int src = k * 128 + j;
  float v;
  switch (m) {
    case 0: v = gcnW[src]; break;
    case 1: v = gatW[src]; break;
    case 2: v = ecW1[src] - ecW1[16384 + src]; break;  // Wa = top - bot
    case 3: v = ecW1[16384 + src]; break;              // Wb
    case 4: v = ecW2[src]; break;
    case 5: v = ginW1[src]; break;
    case 6: v = ginW2[src]; break;
    default: v = gtW1[src]; break;
  }
  WT[f] = f2bf(v);
}

// ---------- MFMA dense [n,128]@[128,128], W^T bf16 in global (L1), bf16 out ----------
template <int IN_BF, int RELU, int BIAS>
__global__ __launch_bounds__(256) void dense_mfma(const void* __restrict__ Xv,
                                                  const unsigned short* __restrict__ WT,
                                                  const float* __restrict__ bias,
                                                  unsigned short* __restrict__ Y, int n) {
  __shared__ unsigned short tile[64][136];
  const int tid = threadIdx.x, lane = tid & 63, wave = tid >> 6;
  const int jl = lane & 15, kg = lane >> 4;
  const int base = blockIdx.x * 64;
  if (base >= n) return;
  const int nr = min(64, n - base);
  if (IN_BF) {
    const uint4* X4 = (const uint4*)Xv;
#pragma unroll
    for (int it = 0; it < 4; ++it) {
      int f = it * 256 + tid, r = f >> 4, q = f & 15;
      if (r < nr) *(uint4*)&tile[r][q * 8] = X4[(size_t)(base + r) * 16 + q];
    }
  } else {
    const float* X = (const float*)Xv;
#pragma unroll
    for (int it = 0; it < 16; ++it) {
      int f = it * 256 + tid, r = f >> 6, kp = f & 63;
      if (r < nr) {
        float2 v = *(const float2*)&X[(size_t)(base + r) * H + 2 * kp];
        *(unsigned*)&tile[r][2 * kp] = pack2bf(v.x, v.y);
      }
    }
  }
  __syncthreads();
  bf16x8 afrag[4];
#pragma unroll
  for (int kk = 0; kk < 4; ++kk)
    afrag[kk] = *(const bf16x8*)&tile[wave * 16 + jl][kk * 32 + kg * 8];
  f32x4 acc[8];
#pragma unroll
  for (int jt = 0; jt < 8; ++jt) {
    f32x4 c = {0.f, 0.f, 0.f, 0.f};
#pragma unroll
    for (int kk = 0; kk < 4; ++kk) {
      bf16x8 bf = *(const bf16x8*)&WT[(size_t)(jt * 16 + jl) * H + kk * 32 + kg * 8];
      c = __builtin_amdgcn_mfma_f32_16x16x32_bf16(afrag[kk], bf, c, 0, 0, 0);
    }
    if (BIAS) {
      float bb = bias[jt * 16 + jl];
#pragma unroll
      for (int r = 0; r < 4; ++r) c[r] += bb;
    }
    if (RELU) {
#pragma unroll
      for (int r = 0; r < 4; ++r) c[r] = fmaxf(c[r], 0.f);
    }
    acc[jt] = c;
  }
  __syncthreads();
#pragma unroll
  for (int jt = 0; jt < 8; ++jt)
#pragma unroll
    for (int r = 0; r < 4; ++r) tile[wave * 16 + kg * 4 + r][jt * 16 + jl] = f2bf(acc[jt][r]);
  __syncthreads();
#pragma unroll
  for (int it = 0; it < 4; ++it) {
    int f = it * 256 + tid, r = f >> 4, q = f & 15;
    if (r < nr) *(uint4*)&Y[(size_t)(base + r) * H + q * 8] = *(const uint4*)&tile[r][q * 8];
  }
}

// ---------- dual dense: Y1 = X@W1, Y2 = X@W2 + b2 (shared X staging) ----------
__global__ __launch_bounds__(256) void dense_dual(const unsigned short* __restrict__ X,
                                                  const unsigned short* __restrict__ WT1,
                                                  const unsigned short* __restrict__ WT2,
                                                  const float* __restrict__ bias2,
                                                  unsigned short* __restrict__ Y1,
                                                  unsigned short* __restrict__ Y2, int n) {
  __shared__ unsigned short tile[64][136];
  const int tid = threadIdx.x, lane = tid & 63, wave = tid >> 6;
  const int jl = lane & 15, kg = lane >> 4;
  const int base = blockIdx.x * 64;
  if (base >= n) return;
  const int nr = min(64, n - base);
  const uint4* X4 = (const uint4*)X;
#pragma unroll
  for (int it = 0; it < 4; ++it) {
    int f = it * 256 + tid, r = f >> 4, q = f & 15;
    if (r < nr) *(uint4*)&tile[r][q * 8] = X4[(size_t)(base + r) * 16 + q];
  }
  __syncthreads();
  bf16x8 afrag[4];
#pragma unroll
  for (int kk = 0; kk < 4; ++kk)
    afrag[kk] = *(const bf16x8*)&tile[wave * 16 + jl][kk * 32 + kg * 8];
  f32x4 acc[8];
#pragma unroll
  for (int jt = 0; jt < 8; ++jt) {
    f32x4 c = {0.f, 0.f, 0.f, 0.f};
#pragma unroll
    for (int kk = 0; kk < 4; ++kk) {
      bf16x8 bf = *(const bf16x8*)&WT1[(size_t)(jt * 16 + jl) * H + kk * 32 + kg * 8];
      c = __builtin_amdgcn_mfma_f32_16x16x32_bf16(afrag[kk], bf, c, 0, 0, 0);
    }
    acc[jt] = c;
  }
  __syncthreads();
#pragma unroll
  for (int jt = 0; jt < 8; ++jt)
#pragma unroll
    for (int r = 0; r < 4; ++r) tile[wave * 16 + kg * 4 + r][jt * 16 + jl] = f2bf(acc[jt][r]);
  __syncthreads();
#pragma unroll
  for (int it = 0; it < 4; ++it) {
    int f = it * 256 + tid, r = f >> 4, q = f & 15;
    if (r < nr) *(uint4*)&Y1[(size_t)(base + r) * H + q * 8] = *(const uint4*)&tile[r][q * 8];
  }
  __syncthreads();
#pragma unroll
  for (int jt = 0; jt < 8; ++jt) {
    f32x4 c = {0.f, 0.f, 0.f, 0.f};
#pragma unroll
    for (int kk = 0; kk < 4; ++kk) {
      bf16x8 bf = *(const bf16x8*)&WT2[(size_t)(jt * 16 + jl) * H + kk * 32 + kg * 8];
      c = __builtin_amdgcn_mfma_f32_16x16x32_bf16(afrag[kk], bf, c, 0, 0, 0);
    }
    float bb = bias2[jt * 16 + jl];
#pragma unroll
    for (int r = 0; r < 4; ++r) c[r] += bb;
    acc[jt] = c;
  }
  __syncthreads();
#pragma unroll
  for (int jt = 0; jt < 8; ++jt)
#pragma unroll
    for (int r = 0; r < 4; ++r) tile[wave * 16 + kg * 4 + r][jt * 16 + jl] = f2bf(acc[jt][r]);
  __syncthreads();
#pragma unroll
  for (int it = 0; it < 4; ++it) {
    int f = it * 256 + tid, r = f >> 4, q = f & 15;
    if (r < nr) *(uint4*)&Y2[(size_t)(base + r) * H + q * 8] = *(const uint4*)&tile[r][q * 8];
  }
}

// ---------- CSR build ----------
__global__ void zero_int(int* p, int n) {
  int i = blockIdx.x * 256 + threadIdx.x;
  if (i < n) p[i] = 0;
}
__global__ void csr_count(const int* __restrict__ ei, int* __restrict__ cnt, int E) {
  int e = blockIdx.x * 256 + threadIdx.x;
  if (e < E) atomicAdd(&cnt[ei[(size_t)E + e]], 1);
}
__global__ __launch_bounds__(1024) void scan50k(const int* __restrict__ cnt,
                                                int* __restrict__ row_ptr, int n) {
  __shared__ int ls[1024];
  int t = threadIdx.x;
  int chunk = (n + 1023) >> 10;
  int a = t * chunk;
  if (a > n) a = n;
  int b = a + chunk;
  if (b > n) b = n;
  int s = 0;
  for (int i = a; i < b; ++i) s += cnt[i];
  ls[t] = s;
  __syncthreads();
  for (int off = 1; off < 1024; off <<= 1) {
    int v = (t >= off) ? ls[t - off] : 0;
    __syncthreads();
    ls[t] += v;
    __syncthreads();
  }
  int run = (t > 0) ? ls[t - 1] : 0;
  for (int i = a; i < b; ++i) {
    row_ptr[i] = run;
    run += cnt[i];
  }
  if (t == 1023) row_ptr[n] = ls[1023];
}
__global__ void copy_int(const int* __restrict__ a, int* __restrict__ b, int n) {
  int i = blockIdx.x * 256 + threadIdx.x;
  if (i < n) b[i] = a[i];
}
__global__ void csr_fill(const int* __restrict__ ei, int* __restrict__ cursor,
                         int* __restrict__ csr_src, int* __restrict__ csr_dst, int E) {
  int e = blockIdx.x * 256 + threadIdx.x;
  if (e >= E) return;
  int s = ei[e], d = ei[(size_t)E + e];
  int p = atomicAdd(&cursor[d], 1);
  csr_src[p] = s;
  csr_dst[p] = d;
}
__global__ void dinv_kernel(const int* __restrict__ row_ptr, float* __restrict__ dinv, int n) {
  int i = blockIdx.x * 256 + threadIdx.x;
  if (i < n) dinv[i] = rsqrtf((float)(1 + row_ptr[i + 1] - row_ptr[i]));
}
__global__ void fill_u32(unsigned* p, unsigned v, size_t n) {
  size_t i = (size_t)blockIdx.x * 256 + threadIdx.x;
  if (i < n) p[i] = v;
}

// ---------- gathers (wave per node, 2 bf16 channels per lane) ----------
__global__ __launch_bounds__(256) void gcn_gather(const unsigned short* __restrict__ h,
                                                  const float* __restrict__ dinv,
                                                  const int* __restrict__ row_ptr,
                                                  const int* __restrict__ csr_src,
                                                  const float* __restrict__ bias,
                                                  unsigned short* __restrict__ out, int n) {
  int node = blockIdx.x * 4 + (threadIdx.x >> 6);
  int lane = threadIdx.x & 63;
  if (node >= n) return;
  const unsigned* hu = (const unsigned*)h;
  float di = dinv[node];
  unsigned v = hu[(size_t)node * 64 + lane];
  float t0 = bflo(v) * di, t1 = bfhi(v) * di;
  int a = row_ptr[node], b = row_ptr[node + 1];
  for (int e = a; e < b; ++e) {
    int s = csr_src[e];
    float ds = dinv[s];
    unsigned w = hu[(size_t)s * 64 + lane];
    t0 = fmaf(bflo(w), ds, t0);
    t1 = fmaf(bfhi(w), ds, t1);
  }
  float y0 = fmaxf(fmaf(t0, di, bias[lane * 2]), 0.f);
  float y1 = fmaxf(fmaf(t1, di, bias[lane * 2 + 1]), 0.f);
  ((unsigned*)out)[(size_t)node * 64 + lane] = pack2bf(y0, y1);
}

__global__ void att_pre(const unsigned short* __restrict__ g, const float* __restrict__ attS,
                        const float* __restrict__ attD, float* __restrict__ asrc,
                        float* __restrict__ adst, int n) {
  int t = blockIdx.x * 256 + threadIdx.x;
  if (t >= n * 4) return;
  int i = t >> 2, hd = t & 3;
  const unsigned* gr = (const unsigned*)(g + (size_t)i * H + hd * 32);
  float s1 = 0.f, s2 = 0.f;
#pragma unroll
  for (int p = 0; p < 16; ++p) {
    unsigned u = gr[p];
    float a = bflo(u), b = bfhi(u);
    s1 = fmaf(a, attS[hd * 32 + 2 * p], fmaf(b, attS[hd * 32 + 2 * p + 1], s1));
    s2 = fmaf(a, attD[hd * 32 + 2 * p], fmaf(b, attD[hd * 32 + 2 * p + 1], s2));
  }
  asrc[t] = s1;
  adst[t] = s2;
}

// GAT: single pass (no segment max; exp args are O(1)), per-edge w computed once per head
__global__ __launch_bounds__(128) void gat_gather(const unsigned short* __restrict__ g,
                                                  const float* __restrict__ asrc,
                                                  const float* __restrict__ adst,
                                                  const int* __restrict__ row_ptr,
                                                  const int* __restrict__ csr_src,
                                                  const float* __restrict__ bias,
                                                  unsigned short* __restrict__ out, int n) {
  __shared__ float wl[32][4];
  __shared__ int sl[32];
  int i = blockIdx.x, t = threadIdx.x;
  int a = row_ptr[i], b = row_ptr[i + 1];
  int c = t, chd = c >> 5;
  float adc = adst[i * 4 + chd];
  float e0 = asrc[i * 4 + chd] + adc;
  e0 = e0 > 0.f ? e0 : 0.2f * e0;
  float w = __expf(e0);
  float acc = w * bf2f(g[(size_t)i * H + c]);
  float wsum = w;
  for (int cb = a; cb < b; cb += 32) {
    int m = min(32, b - cb);
    __syncthreads();
    if (t < 4 * m) {
      int el = t >> 2, hd = t & 3;
      int s = csr_src[cb + el];
      float ev = asrc[s * 4 + hd] + adst[i * 4 + hd];
      ev = ev > 0.f ? ev : 0.2f * ev;
      wl[el][hd] = __expf(ev);
      if (hd == 0) sl[el] = s;
    }
    __syncthreads();
    for (int el = 0; el < m; ++el) {
      int s = sl[el];
      float we = wl[el][chd];
      acc = fmaf(we, bf2f(g[(size_t)s * H + c]), acc);
      wsum += we;
    }
  }
  float r = acc / (wsum + 1e-16f) + bias[c];
  out[(size_t)i * H + c] = f2bf(r > 0.f ? r : expm1f(r));
}

// ---------- EdgeConv: bf16 MFMA + split segmented max ----------
__global__ __launch_bounds__(256) void edgeconv_mfma(const unsigned short* __restrict__ A,
                                                     const unsigned short* __restrict__ Bm,
                                                     const int* __restrict__ csr_src,
                                                     const int* __restrict__ csr_dst,
                                                     const unsigned short* __restrict__ W2T,
                                                     const float* __restrict__ b2,
                                                     unsigned* __restrict__ hec, int E) {
  __shared__ unsigned short tile[64][136];
  __shared__ int dsts[64];
  const int tid = threadIdx.x, lane = tid & 63, wave = tid >> 6;
  const int jl = lane & 15, kg = lane >> 4;
  const float b2c = b2[tid & 127];
  for (int base = blockIdx.x * 64; base < E; base += gridDim.x * 64) {
    const int ne = min(64, E - base);
    __syncthreads();
#pragma unroll
    for (int it = 0; it < 8; ++it) {
      int f = it * 256 + tid, r = f >> 5, q = f & 31;
      if (r < ne) {
        int s = csr_src[base + r], d = csr_dst[base + r];
        uint2 va = *(const uint2*)&A[(size_t)d * H + q * 4];
        uint2 vb = *(const uint2*)&Bm[(size_t)s * H + q * 4];
        float x0 = fmaxf(bflo(va.x) + bflo(vb.x), 0.f);
        float x1 = fmaxf(bfhi(va.x) + bfhi(vb.x), 0.f);
        float x2 = fmaxf(bflo(va.y) + bflo(vb.y), 0.f);
        float x3 = fmaxf(bfhi(va.y) + bfhi(vb.y), 0.f);
        uint2 o;
        o.x = pack2bf(x0, x1);
        o.y = pack2bf(x2, x3);
        *(uint2*)&tile[r][q * 4] = o;
      }
    }
    if (tid < 64) dsts[tid] = (tid < ne) ? csr_dst[base + tid] : -1;
    __syncthreads();
    bf16x8 afrag[4];
#pragma unroll
    for (int kk = 0; kk < 4; ++kk)
      afrag[kk] = *(const bf16x8*)&tile[wave * 16 + jl][kk * 32 + kg * 8];
    f32x4 acc[8];
#pragma unroll
    for (int jt = 0; jt < 8; ++jt) {
      f32x4 c = {0.f, 0.f, 0.f, 0.f};
#pragma unroll
      for (int kk = 0; kk < 4; ++kk) {
        bf16x8 bf = *(const bf16x8*)&W2T[(size_t)(jt * 16 + jl) * H + kk * 32 + kg * 8];
        c = __builtin_amdgcn_mfma_f32_16x16x32_bf16(afrag[kk], bf, c, 0, 0, 0);
      }
      acc[jt] = c;
    }
    __syncthreads();
#pragma unroll
    for (int jt = 0; jt < 8; ++jt)
#pragma unroll
      for (int r = 0; r < 4; ++r) tile[wave * 16 + kg * 4 + r][jt * 16 + jl] = f2bf(acc[jt][r]);
    __syncthreads();
    {
      const int col = tid & 127, half = tid >> 7;
      int r0 = half * 32, r1 = min(ne, r0 + 32);
      if (r0 < r1) {
        int cur = dsts[r0];
        float m = bf2f(tile[r0][col]);
        for (int r = r0 + 1; r < r1; ++r) {
          int d = dsts[r];
          float v = bf2f(tile[r][col]);
          if (d != cur) {
            atomicMax(&hec[(size_t)cur * H + col], fenc(m + b2c));
            cur = d;
            m = v;
          } else {
            m = fmaxf(m, v);
          }
        }
        atomicMax(&hec[(size_t)cur * H + col], fenc(m + b2c));
      }
    }
  }
}

// GIN gather: decode hec on the fly, s = h_i + sum h_src, bf16 out
__global__ __launch_bounds__(256) void gin_gather(const unsigned* __restrict__ hec,
                                                  const int* __restrict__ row_ptr,
                                                  const int* __restrict__ csr_src,
                                                  unsigned short* __restrict__ out, int n) {
  int node = blockIdx.x * 4 + (threadIdx.x >> 6);
  int lane = threadIdx.x & 63;
  if (node >= n) return;
  uint2 v = *(const uint2*)&hec[(size_t)node * H + lane * 2];
  float t0 = fdec(v.x), t1 = fdec(v.y);
  int a = row_ptr[node], b = row_ptr[node + 1];
  for (int e = a; e < b; ++e) {
    int s = csr_src[e];
    uint2 w = *(const uint2*)&hec[(size_t)s * H + lane * 2];
    t0 += fdec(w.x);
    t1 += fdec(w.y);
  }
  ((unsigned*)out)[(size_t)node * 64 + lane] = pack2bf(t0, t1);
}

// ---------- gating + fused pooling ----------
__global__ __launch_bounds__(256) void gate_dot(const unsigned short* __restrict__ X,
                                                const float* __restrict__ w2,
                                                const float* __restrict__ b2,
                                                float* __restrict__ gate, int n) {
  int wid = (blockIdx.x * 256 + threadIdx.x) >> 6;
  int lane = threadIdx.x & 63;
  if (wid >= n) return;
  unsigned u = ((const unsigned*)X)[(size_t)wid * 64 + lane];
  float a = fmaf(bflo(u), w2[lane * 2], bfhi(u) * w2[lane * 2 + 1]);
#pragma unroll
  for (int off = 32; off; off >>= 1) a += __shfl_xor(a, off);
  if (lane == 0) gate[wid] = a + b2[0];
}
__global__ void starts_kernel(const int* __restrict__ batch, int* __restrict__ starts, int n,
                              int G) {
  int i = blockIdx.x * 256 + threadIdx.x;
  if (i >= n) return;
  int b = batch[i];
  int bp = (i == 0) ? -1 : batch[i - 1];
  for (int g = bp + 1; g <= b; ++g) starts[g] = i;
  if (i == n - 1)
    for (int g = b + 1; g <= G; ++g) starts[g] = n;
}
__global__ __launch_bounds__(256) void pool_fused(float* __restrict__ gate,
                                                  const unsigned short* __restrict__ h4,
                                                  const int* __restrict__ starts,
                                                  const float* __restrict__ fcW,
                                                  const float* __restrict__ fcB,
                                                  float* __restrict__ out) {
  __shared__ float red[256];
  __shared__ float pl[128];
  int g = blockIdx.x, t = threadIdx.x;
  int s0 = starts[g], s1 = starts[g + 1];
  float m = -1e30f;
  for (int i = s0 + t; i < s1; i += 256) m = fmaxf(m, gate[i]);
  red[t] = m;
  __syncthreads();
  for (int off = 128; off; off >>= 1) {
    if (t < off) red[t] = fmaxf(red[t], red[t + off]);
    __syncthreads();
  }
  m = red[0];
  __syncthreads();
  float sm = 0.f;
  for (int i = s0 + t; i < s1; i += 256) {
    float ge = __expf(gate[i] - m);
    gate[i] = ge;
    sm += ge;
  }
  red[t] = sm;
  __syncthreads();
  for (int off = 128; off; off >>= 1) {
    if (t < off) red[t] += red[t + off];
    __syncthreads();
  }
  float inv = 1.f / (red[0] + 1e-16f);
  __syncthreads();
  int c = t & 127, half = t >> 7;
  float acc = 0.f;
  for (int i = s0 + half; i < s1; i += 2) acc = fmaf(gate[i], bf2f(h4[(size_t)i * H + c]), acc);
  red[t] = acc;
  __syncthreads();
  if (t < 128) pl[t] = (red[t] + red[t + 128]) * inv;
  __syncthreads();
  if (t < OUTD) {
    float o = fcB[t];
    for (int k = 0; k < 128; ++k) o = fmaf(pl[k], fcW[k * OUTD + t], o);
    red[t] = o;
  }
  __syncthreads();
  if (t == 0) {
    float mm = -1e30f;
    for (int j = 0; j < OUTD; ++j) mm = fmaxf(mm, red[j]);
    float s = 0.f;
    for (int j = 0; j < OUTD; ++j) s += __expf(red[j] - mm);
    float l = logf(s);
    for (int j = 0; j < OUTD; ++j) out[g * OUTD + j] = red[j] - mm - l;
  }
}

extern "C" void kernel_launch(void* const* d_in, const int* in_sizes, int n_in, void* d_out,
                              int out_size, void* d_ws, size_t ws_size, hipStream_t stream) {
  const float* x = (const float*)d_in[0];
  const int* ei = (const int*)d_in[1];
  const int* batch = (const int*)d_in[2];
  const float* gcnW = (const float*)d_in[3];
  const float* gcnB = (const float*)d_in[4];
  const float* gatW = (const float*)d_in[5];
  const float* attS = (const float*)d_in[6];
  const float* attD = (const float*)d_in[7];
  const float* gatB = (const float*)d_in[8];
  const float* ecW1 = (const float*)d_in[9];
  const float* ecB1 = (const float*)d_in[10];
  const float* ecW2 = (const float*)d_in[11];
  const float* ecB2 = (const float*)d_in[12];
  const float* ginW1 = (const float*)d_in[13];
  const float* ginB1 = (const float*)d_in[14];
  const float* ginW2 = (const float*)d_in[15];
  const float* ginB2 = (const float*)d_in[16];
  const float* gtW1 = (const float*)d_in[17];
  const float* gtB1 = (const float*)d_in[18];
  const float* gtW2 = (const float*)d_in[19];
  const float* gtB2 = (const float*)d_in[20];
  const float* fcW = (const float*)d_in[21];
  const float* fcB = (const float*)d_in[22];

  const int N = in_sizes[0] / H;
  const int E = in_sizes[1] / 2;
  const int G = out_size / OUTD;
  const size_t NH = (size_t)N * H;

  auto align16 = [](char* p) { return (char*)(((uintptr_t)p + 15) & ~(uintptr_t)15); };
  char* p = (char*)d_ws;
  unsigned* hec = (unsigned*)p;      p += NH * 4;
  float* dinv = (float*)p;           p += (size_t)N * 4;
  float* asrc = (float*)p;           p += (size_t)4 * N * 4;
  float* adst = (float*)p;           p += (size_t)4 * N * 4;
  float* gate = (float*)p;           p += (size_t)N * 4;
  int* starts = (int*)p;             p += (size_t)(G + 1) * 4;
  int* cnt = (int*)p;                p += (size_t)N * 4;
  int* row_ptr = (int*)p;            p += (size_t)(N + 1) * 4;
  int* cursor = (int*)p;             p += (size_t)N * 4;
  int* csr_src = (int*)p;            p += (size_t)E * 4;
  int* csr_dst = (int*)p;            p += (size_t)E * 4;
  p = align16(p);
  unsigned short* WT = (unsigned short*)p;  p += (size_t)8 * 16384 * 2;
  p = align16(p);
  unsigned short* T0 = (unsigned short*)p;  p += NH * 2;
  p = align16(p);
  unsigned short* T1 = (unsigned short*)p;  p += NH * 2;
  p = align16(p);
  unsigned short* T2 = (unsigned short*)p;  p += NH * 2;

  const unsigned short* gcnT = WT;
  const unsigned short* gatT = WT + 16384;
  const unsigned short* WaT = WT + 2 * 16384;
  const unsigned short* WbT = WT + 3 * 16384;
  const unsigned short* W2T = WT + 4 * 16384;
  const unsigned short* gin1T = WT + 5 * 16384;
  const unsigned short* gin2T = WT + 6 * 16384;
  const unsigned short* gt1T = WT + 7 * 16384;

  const int gN = (N + 255) / 256;
  const int gNH = (int)((NH + 255) / 256);
  const int gE = (E + 255) / 256;
  const int gDense = (N + 63) / 64;
  const int gW4 = (N + 3) / 4;

  // ---- prep + CSR ----
  prep_w<<<(8 * 16384 + 255) / 256, 256, 0, stream>>>(gcnW, gatW, ecW1, ecW2, ginW1, ginW2,
                                                      gtW1, WT);
  zero_int<<<gN, 256, 0, stream>>>(cnt, N);
  csr_count<<<gE, 256, 0, stream>>>(ei, cnt, E);
  scan50k<<<1, 1024, 0, stream>>>(cnt, row_ptr, N);
  copy_int<<<gN, 256, 0, stream>>>(row_ptr, cursor, N);
  csr_fill<<<gE, 256, 0, stream>>>(ei, cursor, csr_src, csr_dst, E);
  dinv_kernel<<<gN, 256, 0, stream>>>(row_ptr, dinv, N);

  // ---- GCN ----
  dense_mfma<0, 0, 0><<<gDense, 256, 0, stream>>>(x, gcnT, nullptr, T0, N);
  gcn_gather<<<gW4, 256, 0, stream>>>(T0, dinv, row_ptr, csr_src, gcnB, T1, N);

  // ---- GAT ----
  dense_mfma<1, 0, 0><<<gDense, 256, 0, stream>>>(T1, gatT, nullptr, T2, N);
  att_pre<<<(N * 4 + 255) / 256, 256, 0, stream>>>(T2, attS, attD, asrc, adst, N);
  gat_gather<<<N, 128, 0, stream>>>(T2, asrc, adst, row_ptr, csr_src, gatB, T0, N);

  // ---- EdgeConv ----
  dense_dual<<<gDense, 256, 0, stream>>>(T0, WaT, WbT, ecB1, T1, T2, N);
  fill_u32<<<gNH, 256, 0, stream>>>(hec, 0x80000000u, NH);
  edgeconv_mfma<<<2048, 256, 0, stream>>>(T1, T2, csr_src, csr_dst, W2T, ecB2, hec, E);

  // ---- GIN ----
  gin_gather<<<gW4, 256, 0, stream>>>(hec, row_ptr, csr_src, T0, N);
  dense_mfma<1, 1, 1><<<gDense, 256, 0, stream>>>(T0, gin1T, ginB1, T1, N);
  dense_mfma<1, 1, 1><<<gDense, 256, 0, stream>>>(T1, gin2T, ginB2, T2, N);  // h4 = T2

  // ---- gating + pooling ----
  dense_mfma<1, 1, 1><<<gDense, 256, 0, stream>>>(T2, gt1T, gtB1, T0, N);
  gate_dot<<<(N * 64 + 255) / 256, 256, 0, stream>>>(T0, gtW2, gtB2, gate, N);
  starts_kernel<<<gN, 256, 0, stream>>>(batch, starts, N, G);
  pool_fused<<<G, 256, 0, stream>>>(gate, T2, starts, fcW, fcB, (float*)d_out);
}

// Round 5
// 976.045 us; speedup vs baseline: 10.7384x; 1.0061x over previous
//
#include <hip/hip_runtime.h>

#define H 128
#define OUTD 10

typedef short bf16x8 __attribute__((ext_vector_type(8)));
typedef float f32x4 __attribute__((ext_vector_type(4)));

// ---------- bf16 helpers ----------
__device__ __forceinline__ unsigned short f2bf(float x) {
  unsigned u = __float_as_uint(x);
  u += 0x7fffu + ((u >> 16) & 1u);  // RNE
  return (unsigned short)(u >> 16);
}
__device__ __forceinline__ unsigned pack2bf(float a, float b) {
  return (unsigned)f2bf(a) | ((unsigned)f2bf(b) << 16);
}
__device__ __forceinline__ float bf2f(unsigned short u) {
  return __uint_as_float(((unsigned)u) << 16);
}
__device__ __forceinline__ float bflo(unsigned u) { return __uint_as_float(u << 16); }
__device__ __forceinline__ float bfhi(unsigned u) { return __uint_as_float(u & 0xffff0000u); }

// ---------- weight prep: 8 matrices -> bf16 transposed [j][k] ----------
__global__ void prep_w(const float* __restrict__ gcnW, const float* __restrict__ gatW,
                       const float* __restrict__ ecW1, const float* __restrict__ ecW2,
                       const float* __restrict__ ginW1, const float* __restrict__ ginW2,
                       const float* __restrict__ gtW1, unsigned short* __restrict__ WT) {
  int f = blockIdx.x * 256 + threadIdx.x;
  if (f >= 8 * 16384) return;
  int m = f >> 14, idx = f & 16383;
  int j = idx >> 7, k = idx & 127;
  int src = k * 128 + j;
  float v;
  switch (m) {
    case 0: v = gcnW[src]; break;
    case 1: v = gatW[src]; break;
    case 2: v = ecW1[src] - ecW1[16384 + src]; break;  // Wa = top - bot
    case 3: v = ecW1[16384 + src]; break;              // Wb
    case 4: v = ecW2[src]; break;
    case 5: v = ginW1[src]; break;
    case 6: v = ginW2[src]; break;
    default: v = gtW1[src]; break;
  }
  WT[f] = f2bf(v);
}

// ---------- MFMA dense [n,128]@[128,128], W^T bf16 in global (L1), bf16 out ----------
template <int IN_BF, int RELU, int BIAS>
__global__ __launch_bounds__(256) void dense_mfma(const void* __restrict__ Xv,
                                                  const unsigned short* __restrict__ WT,
                                                  const float* __restrict__ bias,
                                                  unsigned short* __restrict__ Y, int n) {
  __shared__ unsigned short tile[64][136];
  const int tid = threadIdx.x, lane = tid & 63, wave = tid >> 6;
  const int jl = lane & 15, kg = lane >> 4;
  const int base = blockIdx.x * 64;
  if (base >= n) return;
  const int nr = min(64, n - base);
  if (IN_BF) {
    const uint4* X4 = (const uint4*)Xv;
#pragma unroll
    for (int it = 0; it < 4; ++it) {
      int f = it * 256 + tid, r = f >> 4, q = f & 15;
      if (r < nr) *(uint4*)&tile[r][q * 8] = X4[(size_t)(base + r) * 16 + q];
    }
  } else {
    const float* X = (const float*)Xv;
#pragma unroll
    for (int it = 0; it < 16; ++it) {
      int f = it * 256 + tid, r = f >> 6, kp = f & 63;
      if (r < nr) {
        float2 v = *(const float2*)&X[(size_t)(base + r) * H + 2 * kp];
        *(unsigned*)&tile[r][2 * kp] = pack2bf(v.x, v.y);
      }
    }
  }
  __syncthreads();
  bf16x8 afrag[4];
#pragma unroll
  for (int kk = 0; kk < 4; ++kk)
    afrag[kk] = *(const bf16x8*)&tile[wave * 16 + jl][kk * 32 + kg * 8];
  f32x4 acc[8];
#pragma unroll
  for (int jt = 0; jt < 8; ++jt) {
    f32x4 c = {0.f, 0.f, 0.f, 0.f};
#pragma unroll
    for (int kk = 0; kk < 4; ++kk) {
      bf16x8 bf = *(const bf16x8*)&WT[(size_t)(jt * 16 + jl) * H + kk * 32 + kg * 8];
      c = __builtin_amdgcn_mfma_f32_16x16x32_bf16(afrag[kk], bf, c, 0, 0, 0);
    }
    if (BIAS) {
      float bb = bias[jt * 16 + jl];
#pragma unroll
      for (int r = 0; r < 4; ++r) c[r] += bb;
    }
    if (RELU) {
#pragma unroll
      for (int r = 0; r < 4; ++r) c[r] = fmaxf(c[r], 0.f);
    }
    acc[jt] = c;
  }
  __syncthreads();
#pragma unroll
  for (int jt = 0; jt < 8; ++jt)
#pragma unroll
    for (int r = 0; r < 4; ++r) tile[wave * 16 + kg * 4 + r][jt * 16 + jl] = f2bf(acc[jt][r]);
  __syncthreads();
#pragma unroll
  for (int it = 0; it < 4; ++it) {
    int f = it * 256 + tid, r = f >> 4, q = f & 15;
    if (r < nr) *(uint4*)&Y[(size_t)(base + r) * H + q * 8] = *(const uint4*)&tile[r][q * 8];
  }
}

// ---------- dual dense: Y1 = X@W1, Y2 = X@W2 + b2 (shared X staging) ----------
__global__ __launch_bounds__(256) void dense_dual(const unsigned short* __restrict__ X,
                                                  const unsigned short* __restrict__ WT1,
                                                  const unsigned short* __restrict__ WT2,
                                                  const float* __restrict__ bias2,
                                                  unsigned short* __restrict__ Y1,
                                                  unsigned short* __restrict__ Y2, int n) {
  __shared__ unsigned short tile[64][136];
  const int tid = threadIdx.x, lane = tid & 63, wave = tid >> 6;
  const int jl = lane & 15, kg = lane >> 4;
  const int base = blockIdx.x * 64;
  if (base >= n) return;
  const int nr = min(64, n - base);
  const uint4* X4 = (const uint4*)X;
#pragma unroll
  for (int it = 0; it < 4; ++it) {
    int f = it * 256 + tid, r = f >> 4, q = f & 15;
    if (r < nr) *(uint4*)&tile[r][q * 8] = X4[(size_t)(base + r) * 16 + q];
  }
  __syncthreads();
  bf16x8 afrag[4];
#pragma unroll
  for (int kk = 0; kk < 4; ++kk)
    afrag[kk] = *(const bf16x8*)&tile[wave * 16 + jl][kk * 32 + kg * 8];
  f32x4 acc[8];
#pragma unroll
  for (int jt = 0; jt < 8; ++jt) {
    f32x4 c = {0.f, 0.f, 0.f, 0.f};
#pragma unroll
    for (int kk = 0; kk < 4; ++kk) {
      bf16x8 bf = *(const bf16x8*)&WT1[(size_t)(jt * 16 + jl) * H + kk * 32 + kg * 8];
      c = __builtin_amdgcn_mfma_f32_16x16x32_bf16(afrag[kk], bf, c, 0, 0, 0);
    }
    acc[jt] = c;
  }
  __syncthreads();
#pragma unroll
  for (int jt = 0; jt < 8; ++jt)
#pragma unroll
    for (int r = 0; r < 4; ++r) tile[wave * 16 + kg * 4 + r][jt * 16 + jl] = f2bf(acc[jt][r]);
  __syncthreads();
#pragma unroll
  for (int it = 0; it < 4; ++it) {
    int f = it * 256 + tid, r = f >> 4, q = f & 15;
    if (r < nr) *(uint4*)&Y1[(size_t)(base + r) * H + q * 8] = *(const uint4*)&tile[r][q * 8];
  }
  __syncthreads();
#pragma unroll
  for (int jt = 0; jt < 8; ++jt) {
    f32x4 c = {0.f, 0.f, 0.f, 0.f};
#pragma unroll
    for (int kk = 0; kk < 4; ++kk) {
      bf16x8 bf = *(const bf16x8*)&WT2[(size_t)(jt * 16 + jl) * H + kk * 32 + kg * 8];
      c = __builtin_amdgcn_mfma_f32_16x16x32_bf16(afrag[kk], bf, c, 0, 0, 0);
    }
    float bb = bias2[jt * 16 + jl];
#pragma unroll
    for (int r = 0; r < 4; ++r) c[r] += bb;
    acc[jt] = c;
  }
  __syncthreads();
#pragma unroll
  for (int jt = 0; jt < 8; ++jt)
#pragma unroll
    for (int r = 0; r < 4; ++r) tile[wave * 16 + kg * 4 + r][jt * 16 + jl] = f2bf(acc[jt][r]);
  __syncthreads();
#pragma unroll
  for (int it = 0; it < 4; ++it) {
    int f = it * 256 + tid, r = f >> 4, q = f & 15;
    if (r < nr) *(uint4*)&Y2[(size_t)(base + r) * H + q * 8] = *(const uint4*)&tile[r][q * 8];
  }
}

// ---------- CSR build ----------
__global__ void zero_int(int* p, int n) {
  int i = blockIdx.x * 256 + threadIdx.x;
  if (i < n) p[i] = 0;
}
__global__ void csr_count(const int* __restrict__ ei, int* __restrict__ cnt, int E) {
  int e = blockIdx.x * 256 + threadIdx.x;
  if (e < E) atomicAdd(&cnt[ei[(size_t)E + e]], 1);
}
__global__ __launch_bounds__(1024) void scan50k(const int* __restrict__ cnt,
                                                int* __restrict__ row_ptr, int n) {
  __shared__ int ls[1024];
  int t = threadIdx.x;
  int chunk = (n + 1023) >> 10;
  int a = t * chunk;
  if (a > n) a = n;
  int b = a + chunk;
  if (b > n) b = n;
  int s = 0;
  for (int i = a; i < b; ++i) s += cnt[i];
  ls[t] = s;
  __syncthreads();
  for (int off = 1; off < 1024; off <<= 1) {
    int v = (t >= off) ? ls[t - off] : 0;
    __syncthreads();
    ls[t] += v;
    __syncthreads();
  }
  int run = (t > 0) ? ls[t - 1] : 0;
  for (int i = a; i < b; ++i) {
    row_ptr[i] = run;
    run += cnt[i];
  }
  if (t == 1023) row_ptr[n] = ls[1023];
}
__global__ void copy_int(const int* __restrict__ a, int* __restrict__ b, int n) {
  int i = blockIdx.x * 256 + threadIdx.x;
  if (i < n) b[i] = a[i];
}
__global__ void csr_fill(const int* __restrict__ ei, int* __restrict__ cursor,
                         int* __restrict__ csr_src, int E) {
  int e = blockIdx.x * 256 + threadIdx.x;
  if (e >= E) return;
  int s = ei[e], d = ei[(size_t)E + e];
  int p = atomicAdd(&cursor[d], 1);
  csr_src[p] = s;
}
__global__ void dinv_kernel(const int* __restrict__ row_ptr, float* __restrict__ dinv, int n) {
  int i = blockIdx.x * 256 + threadIdx.x;
  if (i < n) dinv[i] = rsqrtf((float)(1 + row_ptr[i + 1] - row_ptr[i]));
}

// ---------- GCN gather: wave per node, 2 bf16 channels/lane, 4x unrolled ----------
__global__ __launch_bounds__(256) void gcn_gather(const unsigned short* __restrict__ h,
                                                  const float* __restrict__ dinv,
                                                  const int* __restrict__ row_ptr,
                                                  const int* __restrict__ csr_src,
                                                  const float* __restrict__ bias,
                                                  unsigned short* __restrict__ out, int n) {
  int node = blockIdx.x * 4 + (threadIdx.x >> 6);
  int lane = threadIdx.x & 63;
  if (node >= n) return;
  const unsigned* hu = (const unsigned*)h;
  float di = dinv[node];
  unsigned v = hu[(size_t)node * 64 + lane];
  float t0 = bflo(v) * di, t1 = bfhi(v) * di;
  int a = row_ptr[node], b = row_ptr[node + 1];
  int e = a;
  for (; e + 4 <= b; e += 4) {
    int s0 = csr_src[e], s1 = csr_src[e + 1], s2 = csr_src[e + 2], s3 = csr_src[e + 3];
    unsigned w0 = hu[(size_t)s0 * 64 + lane], w1 = hu[(size_t)s1 * 64 + lane];
    unsigned w2 = hu[(size_t)s2 * 64 + lane], w3 = hu[(size_t)s3 * 64 + lane];
    float d0 = dinv[s0], d1 = dinv[s1], d2 = dinv[s2], d3 = dinv[s3];
    t0 = fmaf(bflo(w0), d0, t0);
    t1 = fmaf(bfhi(w0), d0, t1);
    t0 = fmaf(bflo(w1), d1, t0);
    t1 = fmaf(bfhi(w1), d1, t1);
    t0 = fmaf(bflo(w2), d2, t0);
    t1 = fmaf(bfhi(w2), d2, t1);
    t0 = fmaf(bflo(w3), d3, t0);
    t1 = fmaf(bfhi(w3), d3, t1);
  }
  for (; e < b; ++e) {
    int s = csr_src[e];
    float ds = dinv[s];
    unsigned w = hu[(size_t)s * 64 + lane];
    t0 = fmaf(bflo(w), ds, t0);
    t1 = fmaf(bfhi(w), ds, t1);
  }
  float y0 = fmaxf(fmaf(t0, di, bias[lane * 2]), 0.f);
  float y1 = fmaxf(fmaf(t1, di, bias[lane * 2 + 1]), 0.f);
  ((unsigned*)out)[(size_t)node * 64 + lane] = pack2bf(y0, y1);
}

__global__ void att_pre(const unsigned short* __restrict__ g, const float* __restrict__ attS,
                        const float* __restrict__ attD, float* __restrict__ asrc,
                        float* __restrict__ adst, int n) {
  int t = blockIdx.x * 256 + threadIdx.x;
  if (t >= n * 4) return;
  int i = t >> 2, hd = t & 3;
  const unsigned* gr = (const unsigned*)(g + (size_t)i * H + hd * 32);
  float s1 = 0.f, s2 = 0.f;
#pragma unroll
  for (int p = 0; p < 16; ++p) {
    unsigned u = gr[p];
    float a = bflo(u), b = bfhi(u);
    s1 = fmaf(a, attS[hd * 32 + 2 * p], fmaf(b, attS[hd * 32 + 2 * p + 1], s1));
    s2 = fmaf(a, attD[hd * 32 + 2 * p], fmaf(b, attD[hd * 32 + 2 * p + 1], s2));
  }
  asrc[t] = s1;
  adst[t] = s2;
}

__device__ __forceinline__ float lrelu_exp(float v) {
  v = v > 0.f ? v : 0.2f * v;
  return __expf(v);
}

// ---------- GAT gather: wave per node, no LDS/barriers, 4x unrolled ----------
__global__ __launch_bounds__(256) void gat_gather(const unsigned short* __restrict__ g,
                                                  const float* __restrict__ asrc,
                                                  const float* __restrict__ adst,
                                                  const int* __restrict__ row_ptr,
                                                  const int* __restrict__ csr_src,
                                                  const float* __restrict__ bias,
                                                  unsigned short* __restrict__ out, int n) {
  int node = blockIdx.x * 4 + (threadIdx.x >> 6);
  int lane = threadIdx.x & 63;
  if (node >= n) return;
  const int hd = lane >> 4;  // head of channels 2*lane, 2*lane+1
  const unsigned* gu = (const unsigned*)g;
  float adc = adst[node * 4 + hd];
  float w = lrelu_exp(asrc[node * 4 + hd] + adc);
  unsigned u = gu[(size_t)node * 64 + lane];
  float acc0 = w * bflo(u), acc1 = w * bfhi(u), wsum = w;
  int a = row_ptr[node], b = row_ptr[node + 1];
  int e = a;
  for (; e + 4 <= b; e += 4) {
    int s0 = csr_src[e], s1 = csr_src[e + 1], s2 = csr_src[e + 2], s3 = csr_src[e + 3];
    unsigned u0 = gu[(size_t)s0 * 64 + lane], u1 = gu[(size_t)s1 * 64 + lane];
    unsigned u2 = gu[(size_t)s2 * 64 + lane], u3 = gu[(size_t)s3 * 64 + lane];
    float w0 = lrelu_exp(asrc[s0 * 4 + hd] + adc), w1 = lrelu_exp(asrc[s1 * 4 + hd] + adc);
    float w2 = lrelu_exp(asrc[s2 * 4 + hd] + adc), w3 = lrelu_exp(asrc[s3 * 4 + hd] + adc);
    acc0 = fmaf(w0, bflo(u0), acc0);
    acc1 = fmaf(w0, bfhi(u0), acc1);
    acc0 = fmaf(w1, bflo(u1), acc0);
    acc1 = fmaf(w1, bfhi(u1), acc1);
    acc0 = fmaf(w2, bflo(u2), acc0);
    acc1 = fmaf(w2, bfhi(u2), acc1);
    acc0 = fmaf(w3, bflo(u3), acc0);
    acc1 = fmaf(w3, bfhi(u3), acc1);
    wsum += w0 + w1 + w2 + w3;
  }
  for (; e < b; ++e) {
    int s = csr_src[e];
    unsigned us = gu[(size_t)s * 64 + lane];
    float we = lrelu_exp(asrc[s * 4 + hd] + adc);
    acc0 = fmaf(we, bflo(us), acc0);
    acc1 = fmaf(we, bfhi(us), acc1);
    wsum += we;
  }
  float inv = 1.f / (wsum + 1e-16f);
  float r0 = acc0 * inv + bias[2 * lane];
  float r1 = acc1 * inv + bias[2 * lane + 1];
  r0 = r0 > 0.f ? r0 : expm1f(r0);
  r1 = r1 > 0.f ? r1 : expm1f(r1);
  ((unsigned*)out)[(size_t)node * 64 + lane] = pack2bf(r0, r1);
}

// ---------- EdgeConv: wave per dst node, MFMA over 16-edge chunks ----------
__global__ __launch_bounds__(256) void edgeconv_node(const unsigned short* __restrict__ A,
                                                     const unsigned short* __restrict__ Bm,
                                                     const int* __restrict__ row_ptr,
                                                     const int* __restrict__ csr_src,
                                                     const unsigned short* __restrict__ W2T,
                                                     const float* __restrict__ b2,
                                                     unsigned short* __restrict__ out, int n) {
  int node = blockIdx.x * 4 + (threadIdx.x >> 6);
  if (node >= n) return;
  const int lane = threadIdx.x & 63;
  const int jl = lane & 15, kg = lane >> 4;
  int a = row_ptr[node], b = row_ptr[node + 1];
  unsigned* orow = (unsigned*)(out + (size_t)node * H);
  if (a == b) {  // isolated node -> zeros
    if (kg == 0 && !(jl & 1)) {
#pragma unroll
      for (int jt = 0; jt < 8; ++jt) orow[jt * 8 + (jl >> 1)] = 0u;
    }
    return;
  }
  bf16x8 ad[4];
  const unsigned short* Arow = A + (size_t)node * H;
#pragma unroll
  for (int kk = 0; kk < 4; ++kk) ad[kk] = *(const bf16x8*)&Arow[kk * 32 + kg * 8];
  f32x4 best[8];
#pragma unroll
  for (int jt = 0; jt < 8; ++jt) best[jt] = {-1e30f, -1e30f, -1e30f, -1e30f};
  for (int base = a; base < b; base += 16) {
    const int m = min(16, b - base);
    bf16x8 af[4];
    if (jl < m) {
      int s = csr_src[base + jl];
      const unsigned short* Brow = Bm + (size_t)s * H;
#pragma unroll
      for (int kk = 0; kk < 4; ++kk) {
        bf16x8 bv = *(const bf16x8*)&Brow[kk * 32 + kg * 8];
        bf16x8 o;
#pragma unroll
        for (int q = 0; q < 8; ++q) {
          float xv = bf2f((unsigned short)ad[kk][q]) + bf2f((unsigned short)bv[q]);
          o[q] = (short)f2bf(fmaxf(xv, 0.f));
        }
        af[kk] = o;
      }
    } else {
#pragma unroll
      for (int kk = 0; kk < 4; ++kk) {
#pragma unroll
        for (int q = 0; q < 8; ++q) af[kk][q] = 0;
      }
    }
#pragma unroll
    for (int jt = 0; jt < 8; ++jt) {
      f32x4 c = {0.f, 0.f, 0.f, 0.f};
#pragma unroll
      for (int kk = 0; kk < 4; ++kk) {
        bf16x8 wf = *(const bf16x8*)&W2T[(size_t)(jt * 16 + jl) * H + kk * 32 + kg * 8];
        c = __builtin_amdgcn_mfma_f32_16x16x32_bf16(af[kk], wf, c, 0, 0, 0);
      }
#pragma unroll
      for (int r = 0; r < 4; ++r) {
        int row = kg * 4 + r;
        best[jt][r] = fmaxf(best[jt][r], (row < m) ? c[r] : -1e30f);
      }
    }
  }
#pragma unroll
  for (int jt = 0; jt < 8; ++jt) {
    float mv = fmaxf(fmaxf(best[jt][0], best[jt][1]), fmaxf(best[jt][2], best[jt][3]));
    mv = fmaxf(mv, __shfl_xor(mv, 16));
    mv = fmaxf(mv, __shfl_xor(mv, 32));
    float val = fmaxf(mv + b2[jt * 16 + jl], 0.f);
    float other = __shfl_xor(val, 1);
    if (kg == 0 && !(jl & 1)) orow[jt * 8 + (jl >> 1)] = pack2bf(val, other);
  }
}

// ---------- GIN gather: wave per node, bf16, 4x unrolled ----------
__global__ __launch_bounds__(256) void gin_gather(const unsigned short* __restrict__ h,
                                                  const int* __restrict__ row_ptr,
                                                  const int* __restrict__ csr_src,
                                                  unsigned short* __restrict__ out, int n) {
  int node = blockIdx.x * 4 + (threadIdx.x >> 6);
  int lane = threadIdx.x & 63;
  if (node >= n) return;
  const unsigned* hu = (const unsigned*)h;
  unsigned v = hu[(size_t)node * 64 + lane];
  float t0 = bflo(v), t1 = bfhi(v);
  int a = row_ptr[node], b = row_ptr[node + 1];
  int e = a;
  for (; e + 4 <= b; e += 4) {
    int s0 = csr_src[e], s1 = csr_src[e + 1], s2 = csr_src[e + 2], s3 = csr_src[e + 3];
    unsigned w0 = hu[(size_t)s0 * 64 + lane], w1 = hu[(size_t)s1 * 64 + lane];
    unsigned w2 = hu[(size_t)s2 * 64 + lane], w3 = hu[(size_t)s3 * 64 + lane];
    t0 += bflo(w0) + bflo(w1) + bflo(w2) + bflo(w3);
    t1 += bfhi(w0) + bfhi(w1) + bfhi(w2) + bfhi(w3);
  }
  for (; e < b; ++e) {
    int s = csr_src[e];
    unsigned w = hu[(size_t)s * 64 + lane];
    t0 += bflo(w);
    t1 += bfhi(w);
  }
  ((unsigned*)out)[(size_t)node * 64 + lane] = pack2bf(t0, t1);
}

// ---------- gating + fused pooling ----------
__global__ __launch_bounds__(256) void gate_dot(const unsigned short* __restrict__ X,
                                                const float* __restrict__ w2,
                                                const float* __restrict__ b2,
                                                float* __restrict__ gate, int n) {
  int wid = (blockIdx.x * 256 + threadIdx.x) >> 6;
  int lane = threadIdx.x & 63;
  if (wid >= n) return;
  unsigned u = ((const unsigned*)X)[(size_t)wid * 64 + lane];
  float a = fmaf(bflo(u), w2[lane * 2], bfhi(u) * w2[lane * 2 + 1]);
#pragma unroll
  for (int off = 32; off; off >>= 1) a += __shfl_xor(a, off);
  if (lane == 0) gate[wid] = a + b2[0];
}
__global__ void starts_kernel(const int* __restrict__ batch, int* __restrict__ starts, int n,
                              int G) {
  int i = blockIdx.x * 256 + threadIdx.x;
  if (i >= n) return;
  int b = batch[i];
  int bp = (i == 0) ? -1 : batch[i - 1];
  for (int g = bp + 1; g <= b; ++g) starts[g] = i;
  if (i == n - 1)
    for (int g = b + 1; g <= G; ++g) starts[g] = n;
}
__global__ __launch_bounds__(256) void pool_fused(float* __restrict__ gate,
                                                  const unsigned short* __restrict__ h4,
                                                  const int* __restrict__ starts,
                                                  const float* __restrict__ fcW,
                                                  const float* __restrict__ fcB,
                                                  float* __restrict__ out) {
  __shared__ float red[256];
  __shared__ float pl[128];
  int g = blockIdx.x, t = threadIdx.x;
  int s0 = starts[g], s1 = starts[g + 1];
  float m = -1e30f;
  for (int i = s0 + t; i < s1; i += 256) m = fmaxf(m, gate[i]);
  red[t] = m;
  __syncthreads();
  for (int off = 128; off; off >>= 1) {
    if (t < off) red[t] = fmaxf(red[t], red[t + off]);
    __syncthreads();
  }
  m = red[0];
  __syncthreads();
  float sm = 0.f;
  for (int i = s0 + t; i < s1; i += 256) {
    float ge = __expf(gate[i] - m);
    gate[i] = ge;
    sm += ge;
  }
  red[t] = sm;
  __syncthreads();
  for (int off = 128; off; off >>= 1) {
    if (t < off) red[t] += red[t + off];
    __syncthreads();
  }
  float inv = 1.f / (red[0] + 1e-16f);
  __syncthreads();
  int c = t & 127, half = t >> 7;
  float acc = 0.f;
  for (int i = s0 + half; i < s1; i += 2) acc = fmaf(gate[i], bf2f(h4[(size_t)i * H + c]), acc);
  red[t] = acc;
  __syncthreads();
  if (t < 128) pl[t] = (red[t] + red[t + 128]) * inv;
  __syncthreads();
  if (t < OUTD) {
    float o = fcB[t];
    for (int k = 0; k < 128; ++k) o = fmaf(pl[k], fcW[k * OUTD + t], o);
    red[t] = o;
  }
  __syncthreads();
  if (t == 0) {
    float mm = -1e30f;
    for (int j = 0; j < OUTD; ++j) mm = fmaxf(mm, red[j]);
    float s = 0.f;
    for (int j = 0; j < OUTD; ++j) s += __expf(red[j] - mm);
    float l = logf(s);
    for (int j = 0; j < OUTD; ++j) out[g * OUTD + j] = red[j] - mm - l;
  }
}

extern "C" void kernel_launch(void* const* d_in, const int* in_sizes, int n_in, void* d_out,
                              int out_size, void* d_ws, size_t ws_size, hipStream_t stream) {
  const float* x = (const float*)d_in[0];
  const int* ei = (const int*)d_in[1];
  const int* batch = (const int*)d_in[2];
  const float* gcnW = (const float*)d_in[3];
  const float* gcnB = (const float*)d_in[4];
  const float* gatW = (const float*)d_in[5];
  const float* attS = (const float*)d_in[6];
  const float* attD = (const float*)d_in[7];
  const float* gatB = (const float*)d_in[8];
  const float* ecW1 = (const float*)d_in[9];
  const float* ecB1 = (const float*)d_in[10];
  const float* ecW2 = (const float*)d_in[11];
  const float* ecB2 = (const float*)d_in[12];
  const float* ginW1 = (const float*)d_in[13];
  const float* ginB1 = (const float*)d_in[14];
  const float* ginW2 = (const float*)d_in[15];
  const float* ginB2 = (const float*)d_in[16];
  const float* gtW1 = (const float*)d_in[17];
  const float* gtB1 = (const float*)d_in[18];
  const float* gtW2 = (const float*)d_in[19];
  const float* gtB2 = (const float*)d_in[20];
  const float* fcW = (const float*)d_in[21];
  const float* fcB = (const float*)d_in[22];

  const int N = in_sizes[0] / H;
  const int E = in_sizes[1] / 2;
  const int G = out_size / OUTD;
  const size_t NH = (size_t)N * H;

  auto align16 = [](char* p) { return (char*)(((uintptr_t)p + 15) & ~(uintptr_t)15); };
  char* p = (char*)d_ws;
  float* dinv = (float*)p;           p += (size_t)N * 4;
  float* asrc = (float*)p;           p += (size_t)4 * N * 4;
  float* adst = (float*)p;           p += (size_t)4 * N * 4;
  float* gate = (float*)p;           p += (size_t)N * 4;
  int* starts = (int*)p;             p += (size_t)(G + 1) * 4;
  int* cnt = (int*)p;                p += (size_t)N * 4;
  int* row_ptr = (int*)p;            p += (size_t)(N + 1) * 4;
  int* cursor = (int*)p;             p += (size_t)N * 4;
  int* csr_src = (int*)p;            p += (size_t)E * 4;
  p = align16(p);
  unsigned short* WT = (unsigned short*)p;  p += (size_t)8 * 16384 * 2;
  p = align16(p);
  unsigned short* T0 = (unsigned short*)p;  p += NH * 2;
  p = align16(p);
  unsigned short* T1 = (unsigned short*)p;  p += NH * 2;
  p = align16(p);
  unsigned short* T2 = (unsigned short*)p;  p += NH * 2;
  p = align16(p);
  unsigned short* T3 = (unsigned short*)p;  p += NH * 2;

  const unsigned short* gcnT = WT;
  const unsigned short* gatT = WT + 16384;
  const unsigned short* WaT = WT + 2 * 16384;
  const unsigned short* WbT = WT + 3 * 16384;
  const unsigned short* W2T = WT + 4 * 16384;
  const unsigned short* gin1T = WT + 5 * 16384;
  const unsigned short* gin2T = WT + 6 * 16384;
  const unsigned short* gt1T = WT + 7 * 16384;

  const int gN = (N + 255) / 256;
  const int gE = (E + 255) / 256;
  const int gDense = (N + 63) / 64;
  const int gW4 = (N + 3) / 4;

  // ---- prep + CSR ----
  prep_w<<<(8 * 16384 + 255) / 256, 256, 0, stream>>>(gcnW, gatW, ecW1, ecW2, ginW1, ginW2,
                                                      gtW1, WT);
  zero_int<<<gN, 256, 0, stream>>>(cnt, N);
  csr_count<<<gE, 256, 0, stream>>>(ei, cnt, E);
  scan50k<<<1, 1024, 0, stream>>>(cnt, row_ptr, N);
  copy_int<<<gN, 256, 0, stream>>>(row_ptr, cursor, N);
  csr_fill<<<gE, 256, 0, stream>>>(ei, cursor, csr_src, E);
  dinv_kernel<<<gN, 256, 0, stream>>>(row_ptr, dinv, N);

  // ---- GCN ----
  dense_mfma<0, 0, 0><<<gDense, 256, 0, stream>>>(x, gcnT, nullptr, T0, N);
  gcn_gather<<<gW4, 256, 0, stream>>>(T0, dinv, row_ptr, csr_src, gcnB, T1, N);

  // ---- GAT ----
  dense_mfma<1, 0, 0><<<gDense, 256, 0, stream>>>(T1, gatT, nullptr, T2, N);
  att_pre<<<(N * 4 + 255) / 256, 256, 0, stream>>>(T2, attS, attD, asrc, adst, N);
  gat_gather<<<gW4, 256, 0, stream>>>(T2, asrc, adst, row_ptr, csr_src, gatB, T0, N);

  // ---- EdgeConv ----
  dense_dual<<<gDense, 256, 0, stream>>>(T0, WaT, WbT, ecB1, T1, T2, N);
  edgeconv_node<<<gW4, 256, 0, stream>>>(T1, T2, row_ptr, csr_src, W2T, ecB2, T3, N);

  // ---- GIN ----
  gin_gather<<<gW4, 256, 0, stream>>>(T3, row_ptr, csr_src, T0, N);
  dense_mfma<1, 1, 1><<<gDense, 256, 0, stream>>>(T0, gin1T, ginB1, T1, N);
  dense_mfma<1, 1, 1><<<gDense, 256, 0, stream>>>(T1, gin2T, ginB2, T2, N);  // h4 = T2

  // ---- gating + pooling ----
  dense_mfma<1, 1, 1><<<gDense, 256, 0, stream>>>(T2, gt1T, gtB1, T0, N);
  gate_dot<<<(N * 64 + 255) / 256, 256, 0, stream>>>(T0, gtW2, gtB2, gate, N);
  starts_kernel<<<gN, 256, 0, stream>>>(batch, starts, N, G);
  pool_fused<<<G, 256, 0, stream>>>(gate, T2, starts, fcW, fcB, (float*)d_out);
}

// Round 6
// 816.954 us; speedup vs baseline: 12.8295x; 1.1947x over previous
//
#include <hip/hip_runtime.h>

#define H 128
#define OUTD 10

typedef short bf16x8 __attribute__((ext_vector_type(8)));
typedef float f32x4 __attribute__((ext_vector_type(4)));

// ---------- bf16 helpers ----------
__device__ __forceinline__ unsigned short f2bf(float x) {
  unsigned u = __float_as_uint(x);
  u += 0x7fffu + ((u >> 16) & 1u);  // RNE
  return (unsigned short)(u >> 16);
}
__device__ __forceinline__ unsigned pack2bf(float a, float b) {
  return (unsigned)f2bf(a) | ((unsigned)f2bf(b) << 16);
}
__device__ __forceinline__ float bf2f(unsigned short u) {
  return __uint_as_float(((unsigned)u) << 16);
}
__device__ __forceinline__ float bflo(unsigned u) { return __uint_as_float(u << 16); }
__device__ __forceinline__ float bfhi(unsigned u) { return __uint_as_float(u & 0xffff0000u); }

// ---------- ordered-float encoding for atomic max ----------
__device__ __forceinline__ unsigned fenc(float x) {
  unsigned u = __float_as_uint(x);
  return (u & 0x80000000u) ? ~u : (u | 0x80000000u);
}
__device__ __forceinline__ float fdec(unsigned u) {
  u = (u & 0x80000000u) ? (u & 0x7fffffffu) : ~u;
  return __uint_as_float(u);
}

// ---------- weight prep: 8 matrices -> bf16 transposed [j][k] ----------
__global__ void prep_w(const float* __restrict__ gcnW, const float* __restrict__ gatW,
                       const float* __restrict__ ecW1, const float* __restrict__ ecW2,
                       const float* __restrict__ ginW1, const float* __restrict__ ginW2,
                       const float* __restrict__ gtW1, unsigned short* __restrict__ WT) {
  int f = blockIdx.x * 256 + threadIdx.x;
  if (f >= 8 * 16384) return;
  int m = f >> 14, idx = f & 16383;
  int j = idx >> 7, k = idx & 127;
  int src = k * 128 + j;
  float v;
  switch (m) {
    case 0: v = gcnW[src]; break;
    case 1: v = gatW[src]; break;
    case 2: v = ecW1[src] - ecW1[16384 + src]; break;  // Wa = top - bot
    case 3: v = ecW1[16384 + src]; break;              // Wb
    case 4: v = ecW2[src]; break;
    case 5: v = ginW1[src]; break;
    case 6: v = ginW2[src]; break;
    default: v = gtW1[src]; break;
  }
  WT[f] = f2bf(v);
}

// ---------- MFMA dense [n,128]@[128,128], W^T bf16 in global (L1), bf16 out ----------
template <int IN_BF, int RELU, int BIAS>
__global__ __launch_bounds__(256) void dense_mfma(const void* __restrict__ Xv,
                                                  const unsigned short* __restrict__ WT,
                                                  const float* __restrict__ bias,
                                                  unsigned short* __restrict__ Y, int n) {
  __shared__ unsigned short tile[64][136];
  const int tid = threadIdx.x, lane = tid & 63, wave = tid >> 6;
  const int jl = lane & 15, kg = lane >> 4;
  const int base = blockIdx.x * 64;
  if (base >= n) return;
  const int nr = min(64, n - base);
  if (IN_BF) {
    const uint4* X4 = (const uint4*)Xv;
#pragma unroll
    for (int it = 0; it < 4; ++it) {
      int f = it * 256 + tid, r = f >> 4, q = f & 15;
      if (r < nr) *(uint4*)&tile[r][q * 8] = X4[(size_t)(base + r) * 16 + q];
    }
  } else {
    const float* X = (const float*)Xv;
#pragma unroll
    for (int it = 0; it < 16; ++it) {
      int f = it * 256 + tid, r = f >> 6, kp = f & 63;
      if (r < nr) {
        float2 v = *(const float2*)&X[(size_t)(base + r) * H + 2 * kp];
        *(unsigned*)&tile[r][2 * kp] = pack2bf(v.x, v.y);
      }
    }
  }
  __syncthreads();
  bf16x8 afrag[4];
#pragma unroll
  for (int kk = 0; kk < 4; ++kk)
    afrag[kk] = *(const bf16x8*)&tile[wave * 16 + jl][kk * 32 + kg * 8];
  f32x4 acc[8];
#pragma unroll
  for (int jt = 0; jt < 8; ++jt) {
    f32x4 c = {0.f, 0.f, 0.f, 0.f};
#pragma unroll
    for (int kk = 0; kk < 4; ++kk) {
      bf16x8 bf = *(const bf16x8*)&WT[(size_t)(jt * 16 + jl) * H + kk * 32 + kg * 8];
      c = __builtin_amdgcn_mfma_f32_16x16x32_bf16(afrag[kk], bf, c, 0, 0, 0);
    }
    if (BIAS) {
      float bb = bias[jt * 16 + jl];
#pragma unroll
      for (int r = 0; r < 4; ++r) c[r] += bb;
    }
    if (RELU) {
#pragma unroll
      for (int r = 0; r < 4; ++r) c[r] = fmaxf(c[r], 0.f);
    }
    acc[jt] = c;
  }
  __syncthreads();
#pragma unroll
  for (int jt = 0; jt < 8; ++jt)
#pragma unroll
    for (int r = 0; r < 4; ++r) tile[wave * 16 + kg * 4 + r][jt * 16 + jl] = f2bf(acc[jt][r]);
  __syncthreads();
#pragma unroll
  for (int it = 0; it < 4; ++it) {
    int f = it * 256 + tid, r = f >> 4, q = f & 15;
    if (r < nr) *(uint4*)&Y[(size_t)(base + r) * H + q * 8] = *(const uint4*)&tile[r][q * 8];
  }
}

// ---------- dual dense: Y1 = X@W1, Y2 = X@W2 + b2 (shared X staging) ----------
__global__ __launch_bounds__(256) void dense_dual(const unsigned short* __restrict__ X,
                                                  const unsigned short* __restrict__ WT1,
                                                  const unsigned short* __restrict__ WT2,
                                                  const float* __restrict__ bias2,
                                                  unsigned short* __restrict__ Y1,
                                                  unsigned short* __restrict__ Y2, int n) {
  __shared__ unsigned short tile[64][136];
  const int tid = threadIdx.x, lane = tid & 63, wave = tid >> 6;
  const int jl = lane & 15, kg = lane >> 4;
  const int base = blockIdx.x * 64;
  if (base >= n) return;
  const int nr = min(64, n - base);
  const uint4* X4 = (const uint4*)X;
#pragma unroll
  for (int it = 0; it < 4; ++it) {
    int f = it * 256 + tid, r = f >> 4, q = f & 15;
    if (r < nr) *(uint4*)&tile[r][q * 8] = X4[(size_t)(base + r) * 16 + q];
  }
  __syncthreads();
  bf16x8 afrag[4];
#pragma unroll
  for (int kk = 0; kk < 4; ++kk)
    afrag[kk] = *(const bf16x8*)&tile[wave * 16 + jl][kk * 32 + kg * 8];
  f32x4 acc[8];
#pragma unroll
  for (int jt = 0; jt < 8; ++jt) {
    f32x4 c = {0.f, 0.f, 0.f, 0.f};
#pragma unroll
    for (int kk = 0; kk < 4; ++kk) {
      bf16x8 bf = *(const bf16x8*)&WT1[(size_t)(jt * 16 + jl) * H + kk * 32 + kg * 8];
      c = __builtin_amdgcn_mfma_f32_16x16x32_bf16(afrag[kk], bf, c, 0, 0, 0);
    }
    acc[jt] = c;
  }
  __syncthreads();
#pragma unroll
  for (int jt = 0; jt < 8; ++jt)
#pragma unroll
    for (int r = 0; r < 4; ++r) tile[wave * 16 + kg * 4 + r][jt * 16 + jl] = f2bf(acc[jt][r]);
  __syncthreads();
#pragma unroll
  for (int it = 0; it < 4; ++it) {
    int f = it * 256 + tid, r = f >> 4, q = f & 15;
    if (r < nr) *(uint4*)&Y1[(size_t)(base + r) * H + q * 8] = *(const uint4*)&tile[r][q * 8];
  }
  __syncthreads();
#pragma unroll
  for (int jt = 0; jt < 8; ++jt) {
    f32x4 c = {0.f, 0.f, 0.f, 0.f};
#pragma unroll
    for (int kk = 0; kk < 4; ++kk) {
      bf16x8 bf = *(const bf16x8*)&WT2[(size_t)(jt * 16 + jl) * H + kk * 32 + kg * 8];
      c = __builtin_amdgcn_mfma_f32_16x16x32_bf16(afrag[kk], bf, c, 0, 0, 0);
    }
    float bb = bias2[jt * 16 + jl];
#pragma unroll
    for (int r = 0; r < 4; ++r) c[r] += bb;
    acc[jt] = c;
  }
  __syncthreads();
#pragma unroll
  for (int jt = 0; jt < 8; ++jt)
#pragma unroll
    for (int r = 0; r < 4; ++r) tile[wave * 16 + kg * 4 + r][jt * 16 + jl] = f2bf(acc[jt][r]);
  __syncthreads();
#pragma unroll
  for (int it = 0; it < 4; ++it) {
    int f = it * 256 + tid, r = f >> 4, q = f & 15;
    if (r < nr) *(uint4*)&Y2[(size_t)(base + r) * H + q * 8] = *(const uint4*)&tile[r][q * 8];
  }
}

// ---------- chained dense (GIN): Y = relu(relu(X@W1+b1)@W2+b2) ----------
__global__ __launch_bounds__(256) void dense_chain(const unsigned short* __restrict__ X,
                                                   const unsigned short* __restrict__ WT1,
                                                   const float* __restrict__ b1,
                                                   const unsigned short* __restrict__ WT2,
                                                   const float* __restrict__ b2,
                                                   unsigned short* __restrict__ Y, int n) {
  __shared__ unsigned short tile[64][136];
  const int tid = threadIdx.x, lane = tid & 63, wave = tid >> 6;
  const int jl = lane & 15, kg = lane >> 4;
  const int base = blockIdx.x * 64;
  if (base >= n) return;
  const int nr = min(64, n - base);
  const uint4* X4 = (const uint4*)X;
#pragma unroll
  for (int it = 0; it < 4; ++it) {
    int f = it * 256 + tid, r = f >> 4, q = f & 15;
    if (r < nr) *(uint4*)&tile[r][q * 8] = X4[(size_t)(base + r) * 16 + q];
  }
  __syncthreads();
  bf16x8 af[4];
#pragma unroll
  for (int kk = 0; kk < 4; ++kk) af[kk] = *(const bf16x8*)&tile[wave * 16 + jl][kk * 32 + kg * 8];
  f32x4 acc[8];
#pragma unroll
  for (int jt = 0; jt < 8; ++jt) {
    f32x4 c = {0.f, 0.f, 0.f, 0.f};
#pragma unroll
    for (int kk = 0; kk < 4; ++kk) {
      bf16x8 bf = *(const bf16x8*)&WT1[(size_t)(jt * 16 + jl) * H + kk * 32 + kg * 8];
      c = __builtin_amdgcn_mfma_f32_16x16x32_bf16(af[kk], bf, c, 0, 0, 0);
    }
    float bb = b1[jt * 16 + jl];
#pragma unroll
    for (int r = 0; r < 4; ++r) c[r] = fmaxf(c[r] + bb, 0.f);
    acc[jt] = c;
  }
  __syncthreads();
#pragma unroll
  for (int jt = 0; jt < 8; ++jt)
#pragma unroll
    for (int r = 0; r < 4; ++r) tile[wave * 16 + kg * 4 + r][jt * 16 + jl] = f2bf(acc[jt][r]);
  __syncthreads();
#pragma unroll
  for (int kk = 0; kk < 4; ++kk) af[kk] = *(const bf16x8*)&tile[wave * 16 + jl][kk * 32 + kg * 8];
#pragma unroll
  for (int jt = 0; jt < 8; ++jt) {
    f32x4 c = {0.f, 0.f, 0.f, 0.f};
#pragma unroll
    for (int kk = 0; kk < 4; ++kk) {
      bf16x8 bf = *(const bf16x8*)&WT2[(size_t)(jt * 16 + jl) * H + kk * 32 + kg * 8];
      c = __builtin_amdgcn_mfma_f32_16x16x32_bf16(af[kk], bf, c, 0, 0, 0);
    }
    float bb = b2[jt * 16 + jl];
#pragma unroll
    for (int r = 0; r < 4; ++r) c[r] = fmaxf(c[r] + bb, 0.f);
    acc[jt] = c;
  }
  __syncthreads();
#pragma unroll
  for (int jt = 0; jt < 8; ++jt)
#pragma unroll
    for (int r = 0; r < 4; ++r) tile[wave * 16 + kg * 4 + r][jt * 16 + jl] = f2bf(acc[jt][r]);
  __syncthreads();
#pragma unroll
  for (int it = 0; it < 4; ++it) {
    int f = it * 256 + tid, r = f >> 4, q = f & 15;
    if (r < nr) *(uint4*)&Y[(size_t)(base + r) * H + q * 8] = *(const uint4*)&tile[r][q * 8];
  }
}

// ---------- gate dense: gate = relu(X@W1+b1) . w2 + b2 (no intermediate write) ----------
__global__ __launch_bounds__(256) void dense_gate(const unsigned short* __restrict__ X,
                                                  const unsigned short* __restrict__ WT,
                                                  const float* __restrict__ b1,
                                                  const float* __restrict__ w2,
                                                  const float* __restrict__ b2,
                                                  float* __restrict__ gate, int n) {
  __shared__ unsigned short tile[64][136];
  const int tid = threadIdx.x, lane = tid & 63, wave = tid >> 6;
  const int jl = lane & 15, kg = lane >> 4;
  const int base = blockIdx.x * 64;
  if (base >= n) return;
  const int nr = min(64, n - base);
  const uint4* X4 = (const uint4*)X;
#pragma unroll
  for (int it = 0; it < 4; ++it) {
    int f = it * 256 + tid, r = f >> 4, q = f & 15;
    if (r < nr) *(uint4*)&tile[r][q * 8] = X4[(size_t)(base + r) * 16 + q];
  }
  __syncthreads();
  bf16x8 af[4];
#pragma unroll
  for (int kk = 0; kk < 4; ++kk) af[kk] = *(const bf16x8*)&tile[wave * 16 + jl][kk * 32 + kg * 8];
  float p0 = 0.f, p1 = 0.f, p2 = 0.f, p3 = 0.f;
#pragma unroll
  for (int jt = 0; jt < 8; ++jt) {
    f32x4 c = {0.f, 0.f, 0.f, 0.f};
#pragma unroll
    for (int kk = 0; kk < 4; ++kk) {
      bf16x8 bf = *(const bf16x8*)&WT[(size_t)(jt * 16 + jl) * H + kk * 32 + kg * 8];
      c = __builtin_amdgcn_mfma_f32_16x16x32_bf16(af[kk], bf, c, 0, 0, 0);
    }
    float bb = b1[jt * 16 + jl];
    float wv = w2[jt * 16 + jl];
    p0 = fmaf(fmaxf(c[0] + bb, 0.f), wv, p0);
    p1 = fmaf(fmaxf(c[1] + bb, 0.f), wv, p1);
    p2 = fmaf(fmaxf(c[2] + bb, 0.f), wv, p2);
    p3 = fmaf(fmaxf(c[3] + bb, 0.f), wv, p3);
  }
#pragma unroll
  for (int off = 1; off <= 8; off <<= 1) {
    p0 += __shfl_xor(p0, off);
    p1 += __shfl_xor(p1, off);
    p2 += __shfl_xor(p2, off);
    p3 += __shfl_xor(p3, off);
  }
  if (jl == 0) {
    float bb2 = b2[0];
    int row = wave * 16 + kg * 4;
    if (row + 0 < nr) gate[base + row + 0] = p0 + bb2;
    if (row + 1 < nr) gate[base + row + 1] = p1 + bb2;
    if (row + 2 < nr) gate[base + row + 2] = p2 + bb2;
    if (row + 3 < nr) gate[base + row + 3] = p3 + bb2;
  }
}

// ---------- CSR build ----------
__global__ void zero_int(int* p, int n) {
  int i = blockIdx.x * 256 + threadIdx.x;
  if (i < n) p[i] = 0;
}
__global__ void csr_count(const int* __restrict__ ei, int* __restrict__ cnt, int E) {
  int e = blockIdx.x * 256 + threadIdx.x;
  if (e < E) atomicAdd(&cnt[ei[(size_t)E + e]], 1);
}
__global__ __launch_bounds__(1024) void scan50k(const int* __restrict__ cnt,
                                                int* __restrict__ row_ptr, int n) {
  __shared__ int ls[1024];
  int t = threadIdx.x;
  int chunk = (n + 1023) >> 10;
  int a = t * chunk;
  if (a > n) a = n;
  int b = a + chunk;
  if (b > n) b = n;
  int s = 0;
  for (int i = a; i < b; ++i) s += cnt[i];
  ls[t] = s;
  __syncthreads();
  for (int off = 1; off < 1024; off <<= 1) {
    int v = (t >= off) ? ls[t - off] : 0;
    __syncthreads();
    ls[t] += v;
    __syncthreads();
  }
  int run = (t > 0) ? ls[t - 1] : 0;
  for (int i = a; i < b; ++i) {
    row_ptr[i] = run;
    run += cnt[i];
  }
  if (t == 1023) row_ptr[n] = ls[1023];
}
__global__ void copy_int(const int* __restrict__ a, int* __restrict__ b, int n) {
  int i = blockIdx.x * 256 + threadIdx.x;
  if (i < n) b[i] = a[i];
}
__global__ void csr_fill(const int* __restrict__ ei, int* __restrict__ cursor,
                         int* __restrict__ csr_src, int* __restrict__ csr_dst, int E) {
  int e = blockIdx.x * 256 + threadIdx.x;
  if (e >= E) return;
  int s = ei[e], d = ei[(size_t)E + e];
  int p = atomicAdd(&cursor[d], 1);
  csr_src[p] = s;
  csr_dst[p] = d;
}
__global__ void dinv_kernel(const int* __restrict__ row_ptr, float* __restrict__ dinv, int n) {
  int i = blockIdx.x * 256 + threadIdx.x;
  if (i < n) dinv[i] = rsqrtf((float)(1 + row_ptr[i + 1] - row_ptr[i]));
}
__global__ void fill_u32(unsigned* p, unsigned v, size_t n) {
  size_t i = (size_t)blockIdx.x * 256 + threadIdx.x;
  if (i < n) p[i] = v;
}

// ---------- GCN gather: wave per node, 8x unrolled ----------
__global__ __launch_bounds__(256) void gcn_gather(const unsigned short* __restrict__ h,
                                                  const float* __restrict__ dinv,
                                                  const int* __restrict__ row_ptr,
                                                  const int* __restrict__ csr_src,
                                                  const float* __restrict__ bias,
                                                  unsigned short* __restrict__ out, int n) {
  int node = blockIdx.x * 4 + (threadIdx.x >> 6);
  int lane = threadIdx.x & 63;
  if (node >= n) return;
  const unsigned* hu = (const unsigned*)h;
  float di = dinv[node];
  unsigned v = hu[(size_t)node * 64 + lane];
  float t0 = bflo(v) * di, t1 = bfhi(v) * di;
  int a = row_ptr[node], b = row_ptr[node + 1];
  int e = a;
  for (; e + 8 <= b; e += 8) {
    int sx[8];
#pragma unroll
    for (int i = 0; i < 8; ++i) sx[i] = csr_src[e + i];
    unsigned w[8];
    float dd[8];
#pragma unroll
    for (int i = 0; i < 8; ++i) w[i] = hu[(size_t)sx[i] * 64 + lane];
#pragma unroll
    for (int i = 0; i < 8; ++i) dd[i] = dinv[sx[i]];
#pragma unroll
    for (int i = 0; i < 8; ++i) {
      t0 = fmaf(bflo(w[i]), dd[i], t0);
      t1 = fmaf(bfhi(w[i]), dd[i], t1);
    }
  }
  for (; e < b; ++e) {
    int s = csr_src[e];
    float ds = dinv[s];
    unsigned w = hu[(size_t)s * 64 + lane];
    t0 = fmaf(bflo(w), ds, t0);
    t1 = fmaf(bfhi(w), ds, t1);
  }
  float y0 = fmaxf(fmaf(t0, di, bias[lane * 2]), 0.f);
  float y1 = fmaxf(fmaf(t1, di, bias[lane * 2 + 1]), 0.f);
  ((unsigned*)out)[(size_t)node * 64 + lane] = pack2bf(y0, y1);
}

__global__ void att_pre(const unsigned short* __restrict__ g, const float* __restrict__ attS,
                        const float* __restrict__ attD, float* __restrict__ asrc,
                        float* __restrict__ adst, int n) {
  int t = blockIdx.x * 256 + threadIdx.x;
  if (t >= n * 4) return;
  int i = t >> 2, hd = t & 3;
  const unsigned* gr = (const unsigned*)(g + (size_t)i * H + hd * 32);
  float s1 = 0.f, s2 = 0.f;
#pragma unroll
  for (int p = 0; p < 16; ++p) {
    unsigned u = gr[p];
    float a = bflo(u), b = bfhi(u);
    s1 = fmaf(a, attS[hd * 32 + 2 * p], fmaf(b, attS[hd * 32 + 2 * p + 1], s1));
    s2 = fmaf(a, attD[hd * 32 + 2 * p], fmaf(b, attD[hd * 32 + 2 * p + 1], s2));
  }
  asrc[t] = s1;
  adst[t] = s2;
}

__device__ __forceinline__ float lrelu_exp(float v) {
  v = v > 0.f ? v : 0.2f * v;
  return __expf(v);
}

// ---------- GAT gather: wave per node, 4x unrolled ----------
__global__ __launch_bounds__(256) void gat_gather(const unsigned short* __restrict__ g,
                                                  const float* __restrict__ asrc,
                                                  const float* __restrict__ adst,
                                                  const int* __restrict__ row_ptr,
                                                  const int* __restrict__ csr_src,
                                                  const float* __restrict__ bias,
                                                  unsigned short* __restrict__ out, int n) {
  int node = blockIdx.x * 4 + (threadIdx.x >> 6);
  int lane = threadIdx.x & 63;
  if (node >= n) return;
  const int hd = lane >> 4;
  const unsigned* gu = (const unsigned*)g;
  float adc = adst[node * 4 + hd];
  float w = lrelu_exp(asrc[node * 4 + hd] + adc);
  unsigned u = gu[(size_t)node * 64 + lane];
  float acc0 = w * bflo(u), acc1 = w * bfhi(u), wsum = w;
  int a = row_ptr[node], b = row_ptr[node + 1];
  int e = a;
  for (; e + 4 <= b; e += 4) {
    int s0 = csr_src[e], s1 = csr_src[e + 1], s2 = csr_src[e + 2], s3 = csr_src[e + 3];
    unsigned u0 = gu[(size_t)s0 * 64 + lane], u1 = gu[(size_t)s1 * 64 + lane];
    unsigned u2 = gu[(size_t)s2 * 64 + lane], u3 = gu[(size_t)s3 * 64 + lane];
    float w0 = lrelu_exp(asrc[s0 * 4 + hd] + adc), w1 = lrelu_exp(asrc[s1 * 4 + hd] + adc);
    float w2 = lrelu_exp(asrc[s2 * 4 + hd] + adc), w3 = lrelu_exp(asrc[s3 * 4 + hd] + adc);
    acc0 = fmaf(w0, bflo(u0), acc0);
    acc1 = fmaf(w0, bfhi(u0), acc1);
    acc0 = fmaf(w1, bflo(u1), acc0);
    acc1 = fmaf(w1, bfhi(u1), acc1);
    acc0 = fmaf(w2, bflo(u2), acc0);
    acc1 = fmaf(w2, bfhi(u2), acc1);
    acc0 = fmaf(w3, bflo(u3), acc0);
    acc1 = fmaf(w3, bfhi(u3), acc1);
    wsum += w0 + w1 + w2 + w3;
  }
  for (; e < b; ++e) {
    int s = csr_src[e];
    unsigned us = gu[(size_t)s * 64 + lane];
    float we = lrelu_exp(asrc[s * 4 + hd] + adc);
    acc0 = fmaf(we, bflo(us), acc0);
    acc1 = fmaf(we, bfhi(us), acc1);
    wsum += we;
  }
  float inv = 1.f / (wsum + 1e-16f);
  float r0 = acc0 * inv + bias[2 * lane];
  float r1 = acc1 * inv + bias[2 * lane + 1];
  r0 = r0 > 0.f ? r0 : expm1f(r0);
  r1 = r1 > 0.f ? r1 : expm1f(r1);
  ((unsigned*)out)[(size_t)node * 64 + lane] = pack2bf(r0, r1);
}

// ---------- EdgeConv: pipelined 64-edge tile MFMA, register segmented-max ----------
__global__ __launch_bounds__(256) void edgeconv_tile(const unsigned short* __restrict__ A,
                                                     const unsigned short* __restrict__ Bm,
                                                     const int* __restrict__ csr_src,
                                                     const int* __restrict__ csr_dst,
                                                     const unsigned short* __restrict__ W2T,
                                                     const float* __restrict__ b2,
                                                     unsigned* __restrict__ hec, int E) {
  __shared__ unsigned short buf[2][64][136];
  __shared__ int dbuf[2][64];
  const int tid = threadIdx.x, lane = tid & 63, wave = tid >> 6;
  const int jl = lane & 15, kg = lane >> 4;
  const int srow = tid >> 2, sq = tid & 3;  // staging: 4 threads/row, 32 cols each
  float b2v[8];
#pragma unroll
  for (int jt = 0; jt < 8; ++jt) b2v[jt] = b2[jt * 16 + jl];

  const int tiles = (E + 63) >> 6;
  int t = blockIdx.x;
  if (t >= tiles) return;
  int cur = 0;
  {  // prologue: stage tile t into buf[0]
    int base = t << 6;
    int ne = min(64, E - base);
    uint2 pk[8];
    if (srow < ne) {
      int d = csr_dst[base + srow], s = csr_src[base + srow];
      const uint2* Ar = (const uint2*)(A + (size_t)d * H + sq * 32);
      const uint2* Br = (const uint2*)(Bm + (size_t)s * H + sq * 32);
#pragma unroll
      for (int i = 0; i < 8; ++i) {
        uint2 va = Ar[i], vb = Br[i];
        pk[i].x = pack2bf(fmaxf(bflo(va.x) + bflo(vb.x), 0.f), fmaxf(bfhi(va.x) + bfhi(vb.x), 0.f));
        pk[i].y = pack2bf(fmaxf(bflo(va.y) + bflo(vb.y), 0.f), fmaxf(bfhi(va.y) + bfhi(vb.y), 0.f));
      }
    } else {
#pragma unroll
      for (int i = 0; i < 8; ++i) pk[i] = {0u, 0u};
    }
#pragma unroll
    for (int i = 0; i < 8; ++i) *(uint2*)&buf[0][srow][sq * 32 + i * 4] = pk[i];
    if (sq == 0) dbuf[0][srow] = (srow < ne) ? csr_dst[base + srow] : -1;
  }
  __syncthreads();

  for (; t < tiles; t += gridDim.x) {
    const int nt = t + gridDim.x;
    const bool havenext = nt < tiles;
    // prefetch next tile into registers (overlaps with MFMAs below)
    uint2 pk[8];
    if (havenext) {
      int base = nt << 6;
      int ne = min(64, E - base);
      if (srow < ne) {
        int d = csr_dst[base + srow], s = csr_src[base + srow];
        const uint2* Ar = (const uint2*)(A + (size_t)d * H + sq * 32);
        const uint2* Br = (const uint2*)(Bm + (size_t)s * H + sq * 32);
#pragma unroll
        for (int i = 0; i < 8; ++i) {
          uint2 va = Ar[i], vb = Br[i];
          pk[i].x =
              pack2bf(fmaxf(bflo(va.x) + bflo(vb.x), 0.f), fmaxf(bfhi(va.x) + bfhi(vb.x), 0.f));
          pk[i].y =
              pack2bf(fmaxf(bflo(va.y) + bflo(vb.y), 0.f), fmaxf(bfhi(va.y) + bfhi(vb.y), 0.f));
        }
      } else {
#pragma unroll
        for (int i = 0; i < 8; ++i) pk[i] = {0u, 0u};
      }
    }
    // MFMA on current buffer + register segmented-max epilogue
    bf16x8 af[4];
#pragma unroll
    for (int kk = 0; kk < 4; ++kk)
      af[kk] = *(const bf16x8*)&buf[cur][wave * 16 + jl][kk * 32 + kg * 8];
    const int r0 = wave * 16 + kg * 4;
    const int d0 = dbuf[cur][r0 + 0], d1 = dbuf[cur][r0 + 1];
    const int d2 = dbuf[cur][r0 + 2], d3 = dbuf[cur][r0 + 3];
#pragma unroll
    for (int jt = 0; jt < 8; ++jt) {
      f32x4 c = {0.f, 0.f, 0.f, 0.f};
#pragma unroll
      for (int kk = 0; kk < 4; ++kk) {
        bf16x8 wf = *(const bf16x8*)&W2T[(size_t)(jt * 16 + jl) * H + kk * 32 + kg * 8];
        c = __builtin_amdgcn_mfma_f32_16x16x32_bf16(af[kk], wf, c, 0, 0, 0);
      }
      const int col = jt * 16 + jl;
      int cd = d0;
      float m = c[0];
      if (d1 != cd) {
        if (cd >= 0) atomicMax(&hec[(size_t)cd * H + col], fenc(m + b2v[jt]));
        cd = d1;
        m = c[1];
      } else
        m = fmaxf(m, c[1]);
      if (d2 != cd) {
        if (cd >= 0) atomicMax(&hec[(size_t)cd * H + col], fenc(m + b2v[jt]));
        cd = d2;
        m = c[2];
      } else
        m = fmaxf(m, c[2]);
      if (d3 != cd) {
        if (cd >= 0) atomicMax(&hec[(size_t)cd * H + col], fenc(m + b2v[jt]));
        cd = d3;
        m = c[3];
      } else
        m = fmaxf(m, c[3]);
      if (cd >= 0) atomicMax(&hec[(size_t)cd * H + col], fenc(m + b2v[jt]));
    }
    // write staged next tile into alternate buffer
    if (havenext) {
      int base = nt << 6;
      int ne = min(64, E - base);
#pragma unroll
      for (int i = 0; i < 8; ++i) *(uint2*)&buf[cur ^ 1][srow][sq * 32 + i * 4] = pk[i];
      if (sq == 0) dbuf[cur ^ 1][srow] = (srow < ne) ? csr_dst[base + srow] : -1;
    }
    __syncthreads();
    cur ^= 1;
  }
}

// ---------- GIN gather: decode hec, wave per node, 4x unrolled ----------
__global__ __launch_bounds__(256) void gin_gather(const unsigned* __restrict__ hec,
                                                  const int* __restrict__ row_ptr,
                                                  const int* __restrict__ csr_src,
                                                  unsigned short* __restrict__ out, int n) {
  int node = blockIdx.x * 4 + (threadIdx.x >> 6);
  int lane = threadIdx.x & 63;
  if (node >= n) return;
  uint2 v = *(const uint2*)&hec[(size_t)node * H + lane * 2];
  float t0 = fdec(v.x), t1 = fdec(v.y);
  int a = row_ptr[node], b = row_ptr[node + 1];
  int e = a;
  for (; e + 4 <= b; e += 4) {
    int s0 = csr_src[e], s1 = csr_src[e + 1], s2 = csr_src[e + 2], s3 = csr_src[e + 3];
    uint2 w0 = *(const uint2*)&hec[(size_t)s0 * H + lane * 2];
    uint2 w1 = *(const uint2*)&hec[(size_t)s1 * H + lane * 2];
    uint2 w2 = *(const uint2*)&hec[(size_t)s2 * H + lane * 2];
    uint2 w3 = *(const uint2*)&hec[(size_t)s3 * H + lane * 2];
    t0 += fdec(w0.x) + fdec(w1.x) + fdec(w2.x) + fdec(w3.x);
    t1 += fdec(w0.y) + fdec(w1.y) + fdec(w2.y) + fdec(w3.y);
  }
  for (; e < b; ++e) {
    int s = csr_src[e];
    uint2 w = *(const uint2*)&hec[(size_t)s * H + lane * 2];
    t0 += fdec(w.x);
    t1 += fdec(w.y);
  }
  ((unsigned*)out)[(size_t)node * 64 + lane] = pack2bf(t0, t1);
}

// ---------- pooling ----------
__global__ void starts_kernel(const int* __restrict__ batch, int* __restrict__ starts, int n,
                              int G) {
  int i = blockIdx.x * 256 + threadIdx.x;
  if (i >= n) return;
  int b = batch[i];
  int bp = (i == 0) ? -1 : batch[i - 1];
  for (int g = bp + 1; g <= b; ++g) starts[g] = i;
  if (i == n - 1)
    for (int g = b + 1; g <= G; ++g) starts[g] = n;
}
__global__ __launch_bounds__(256) void pool_fused(float* __restrict__ gate,
                                                  const unsigned short* __restrict__ h4,
                                                  const int* __restrict__ starts,
                                                  const float* __restrict__ fcW,
                                                  const float* __restrict__ fcB,
                                                  float* __restrict__ out) {
  __shared__ float red[256];
  __shared__ float pl[128];
  int g = blockIdx.x, t = threadIdx.x;
  int s0 = starts[g], s1 = starts[g + 1];
  float m = -1e30f;
  for (int i = s0 + t; i < s1; i += 256) m = fmaxf(m, gate[i]);
  red[t] = m;
  __syncthreads();
  for (int off = 128; off; off >>= 1) {
    if (t < off) red[t] = fmaxf(red[t], red[t + off]);
    __syncthreads();
  }
  m = red[0];
  __syncthreads();
  float sm = 0.f;
  for (int i = s0 + t; i < s1; i += 256) {
    float ge = __expf(gate[i] - m);
    gate[i] = ge;
    sm += ge;
  }
  red[t] = sm;
  __syncthreads();
  for (int off = 128; off; off >>= 1) {
    if (t < off) red[t] += red[t + off];
    __syncthreads();
  }
  float inv = 1.f / (red[0] + 1e-16f);
  __syncthreads();
  int c = t & 127, half = t >> 7;
  float acc = 0.f;
  for (int i = s0 + half; i < s1; i += 2) acc = fmaf(gate[i], bf2f(h4[(size_t)i * H + c]), acc);
  red[t] = acc;
  __syncthreads();
  if (t < 128) pl[t] = (red[t] + red[t + 128]) * inv;
  __syncthreads();
  if (t < OUTD) {
    float o = fcB[t];
    for (int k = 0; k < 128; ++k) o = fmaf(pl[k], fcW[k * OUTD + t], o);
    red[t] = o;
  }
  __syncthreads();
  if (t == 0) {
    float mm = -1e30f;
    for (int j = 0; j < OUTD; ++j) mm = fmaxf(mm, red[j]);
    float s = 0.f;
    for (int j = 0; j < OUTD; ++j) s += __expf(red[j] - mm);
    float l = logf(s);
    for (int j = 0; j < OUTD; ++j) out[g * OUTD + j] = red[j] - mm - l;
  }
}

extern "C" void kernel_launch(void* const* d_in, const int* in_sizes, int n_in, void* d_out,
                              int out_size, void* d_ws, size_t ws_size, hipStream_t stream) {
  const float* x = (const float*)d_in[0];
  const int* ei = (const int*)d_in[1];
  const int* batch = (const int*)d_in[2];
  const float* gcnW = (const float*)d_in[3];
  const float* gcnB = (const float*)d_in[4];
  const float* gatW = (const float*)d_in[5];
  const float* attS = (const float*)d_in[6];
  const float* attD = (const float*)d_in[7];
  const float* gatB = (const float*)d_in[8];
  const float* ecW1 = (const float*)d_in[9];
  const float* ecB1 = (const float*)d_in[10];
  const float* ecW2 = (const float*)d_in[11];
  const float* ecB2 = (const float*)d_in[12];
  const float* ginW1 = (const float*)d_in[13];
  const float* ginB1 = (const float*)d_in[14];
  const float* ginW2 = (const float*)d_in[15];
  const float* ginB2 = (const float*)d_in[16];
  const float* gtW1 = (const float*)d_in[17];
  const float* gtB1 = (const float*)d_in[18];
  const float* gtW2 = (const float*)d_in[19];
  const float* gtB2 = (const float*)d_in[20];
  const float* fcW = (const float*)d_in[21];
  const float* fcB = (const float*)d_in[22];

  const int N = in_sizes[0] / H;
  const int E = in_sizes[1] / 2;
  const int G = out_size / OUTD;
  const size_t NH = (size_t)N * H;

  auto align16 = [](char* p) { return (char*)(((uintptr_t)p + 15) & ~(uintptr_t)15); };
  char* p = (char*)d_ws;
  unsigned* hec = (unsigned*)p;      p += NH * 4;
  float* dinv = (float*)p;           p += (size_t)N * 4;
  float* asrc = (float*)p;           p += (size_t)4 * N * 4;
  float* adst = (float*)p;           p += (size_t)4 * N * 4;
  float* gate = (float*)p;           p += (size_t)N * 4;
  int* starts = (int*)p;             p += (size_t)(G + 1) * 4;
  int* cnt = (int*)p;                p += (size_t)N * 4;
  int* row_ptr = (int*)p;            p += (size_t)(N + 1) * 4;
  int* cursor = (int*)p;             p += (size_t)N * 4;
  int* csr_src = (int*)p;            p += (size_t)E * 4;
  int* csr_dst = (int*)p;            p += (size_t)E * 4;
  p = align16(p);
  unsigned short* WT = (unsigned short*)p;  p += (size_t)8 * 16384 * 2;
  p = align16(p);
  unsigned short* T0 = (unsigned short*)p;  p += NH * 2;
  p = align16(p);
  unsigned short* T1 = (unsigned short*)p;  p += NH * 2;
  p = align16(p);
  unsigned short* T2 = (unsigned short*)p;  p += NH * 2;

  const unsigned short* gcnT = WT;
  const unsigned short* gatT = WT + 16384;
  const unsigned short* WaT = WT + 2 * 16384;
  const unsigned short* WbT = WT + 3 * 16384;
  const unsigned short* W2T = WT + 4 * 16384;
  const unsigned short* gin1T = WT + 5 * 16384;
  const unsigned short* gin2T = WT + 6 * 16384;
  const unsigned short* gt1T = WT + 7 * 16384;

  const int gN = (N + 255) / 256;
  const int gNH = (int)((NH + 255) / 256);
  const int gE = (E + 255) / 256;
  const int gDense = (N + 63) / 64;
  const int gW4 = (N + 3) / 4;

  // ---- prep + CSR ----
  prep_w<<<(8 * 16384 + 255) / 256, 256, 0, stream>>>(gcnW, gatW, ecW1, ecW2, ginW1, ginW2,
                                                      gtW1, WT);
  zero_int<<<gN, 256, 0, stream>>>(cnt, N);
  csr_count<<<gE, 256, 0, stream>>>(ei, cnt, E);
  scan50k<<<1, 1024, 0, stream>>>(cnt, row_ptr, N);
  copy_int<<<gN, 256, 0, stream>>>(row_ptr, cursor, N);
  csr_fill<<<gE, 256, 0, stream>>>(ei, cursor, csr_src, csr_dst, E);
  dinv_kernel<<<gN, 256, 0, stream>>>(row_ptr, dinv, N);

  // ---- GCN ----
  dense_mfma<0, 0, 0><<<gDense, 256, 0, stream>>>(x, gcnT, nullptr, T0, N);
  gcn_gather<<<gW4, 256, 0, stream>>>(T0, dinv, row_ptr, csr_src, gcnB, T1, N);

  // ---- GAT ----
  dense_mfma<1, 0, 0><<<gDense, 256, 0, stream>>>(T1, gatT, nullptr, T2, N);
  att_pre<<<(N * 4 + 255) / 256, 256, 0, stream>>>(T2, attS, attD, asrc, adst, N);
  gat_gather<<<gW4, 256, 0, stream>>>(T2, asrc, adst, row_ptr, csr_src, gatB, T0, N);

  // ---- EdgeConv ----
  dense_dual<<<gDense, 256, 0, stream>>>(T0, WaT, WbT, ecB1, T1, T2, N);
  fill_u32<<<gNH, 256, 0, stream>>>(hec, 0x80000000u, NH);  // enc(0.0): folds relu + isolated
  edgeconv_tile<<<2048, 256, 0, stream>>>(T1, T2, csr_src, csr_dst, W2T, ecB2, hec, E);

  // ---- GIN ----
  gin_gather<<<gW4, 256, 0, stream>>>(hec, row_ptr, csr_src, T0, N);
  dense_chain<<<gDense, 256, 0, stream>>>(T0, gin1T, ginB1, gin2T, ginB2, T2, N);  // h4 = T2

  // ---- gating + pooling ----
  dense_gate<<<gDense, 256, 0, stream>>>(T2, gt1T, gtB1, gtW2, gtB2, gate, N);
  starts_kernel<<<gN, 256, 0, stream>>>(batch, starts, N, G);
  pool_fused<<<G, 256, 0, stream>>>(gate, T2, starts, fcW, fcB, (float*)d_out);
}

// Round 7
// 813.644 us; speedup vs baseline: 12.8817x; 1.0041x over previous
//
#include <hip/hip_runtime.h>

#define H 128
#define OUTD 10

typedef short bf16x8 __attribute__((ext_vector_type(8)));
typedef float f32x4 __attribute__((ext_vector_type(4)));

// ---------- bf16 helpers ----------
__device__ __forceinline__ unsigned short f2bf(float x) {
  unsigned u = __float_as_uint(x);
  u += 0x7fffu + ((u >> 16) & 1u);  // RNE
  return (unsigned short)(u >> 16);
}
__device__ __forceinline__ unsigned pack2bf(float a, float b) {
  return (unsigned)f2bf(a) | ((unsigned)f2bf(b) << 16);
}
__device__ __forceinline__ float bf2f(unsigned short u) {
  return __uint_as_float(((unsigned)u) << 16);
}
__device__ __forceinline__ float bflo(unsigned u) { return __uint_as_float(u << 16); }
__device__ __forceinline__ float bfhi(unsigned u) { return __uint_as_float(u & 0xffff0000u); }

// ---------- ordered-float encoding for atomic max ----------
__device__ __forceinline__ unsigned fenc(float x) {
  unsigned u = __float_as_uint(x);
  return (u & 0x80000000u) ? ~u : (u | 0x80000000u);
}
__device__ __forceinline__ float fdec(unsigned u) {
  u = (u & 0x80000000u) ? (u & 0x7fffffffu) : ~u;
  return __uint_as_float(u);
}

// ---------- weight prep: 8 matrices -> bf16 transposed [j][k] ----------
__global__ void prep_w(const float* __restrict__ gcnW, const float* __restrict__ gatW,
                       const float* __restrict__ ecW1, const float* __restrict__ ecW2,
                       const float* __restrict__ ginW1, const float* __restrict__ ginW2,
                       const float* __restrict__ gtW1, unsigned short* __restrict__ WT) {
  int f = blockIdx.x * 256 + threadIdx.x;
  if (f >= 8 * 16384) return;
  int m = f >> 14, idx = f & 16383;
  int j = idx >> 7, k = idx & 127;
  int src = k * 128 + j;
  float v;
  switch (m) {
    case 0: v = gcnW[src]; break;
    case 1: v = gatW[src]; break;
    case 2: v = ecW1[src] - ecW1[16384 + src]; break;  // Wa = top - bot
    case 3: v = ecW1[16384 + src]; break;              // Wb
    case 4: v = ecW2[src]; break;
    case 5: v = ginW1[src]; break;
    case 6: v = ginW2[src]; break;
    default: v = gtW1[src]; break;
  }
  WT[f] = f2bf(v);
}

// ---------- MFMA dense [n,128]@[128,128], W^T bf16 in global (L1), bf16 out ----------
template <int IN_BF, int RELU, int BIAS>
__global__ __launch_bounds__(256) void dense_mfma(const void* __restrict__ Xv,
                                                  const unsigned short* __restrict__ WT,
                                                  const float* __restrict__ bias,
                                                  unsigned short* __restrict__ Y, int n) {
  __shared__ unsigned short tile[64][136];
  const int tid = threadIdx.x, lane = tid & 63, wave = tid >> 6;
  const int jl = lane & 15, kg = lane >> 4;
  const int base = blockIdx.x * 64;
  if (base >= n) return;
  const int nr = min(64, n - base);
  if (IN_BF) {
    const uint4* X4 = (const uint4*)Xv;
#pragma unroll
    for (int it = 0; it < 4; ++it) {
      int f = it * 256 + tid, r = f >> 4, q = f & 15;
      if (r < nr) *(uint4*)&tile[r][q * 8] = X4[(size_t)(base + r) * 16 + q];
    }
  } else {
    const float* X = (const float*)Xv;
#pragma unroll
    for (int it = 0; it < 16; ++it) {
      int f = it * 256 + tid, r = f >> 6, kp = f & 63;
      if (r < nr) {
        float2 v = *(const float2*)&X[(size_t)(base + r) * H + 2 * kp];
        *(unsigned*)&tile[r][2 * kp] = pack2bf(v.x, v.y);
      }
    }
  }
  __syncthreads();
  bf16x8 afrag[4];
#pragma unroll
  for (int kk = 0; kk < 4; ++kk)
    afrag[kk] = *(const bf16x8*)&tile[wave * 16 + jl][kk * 32 + kg * 8];
  f32x4 acc[8];
#pragma unroll
  for (int jt = 0; jt < 8; ++jt) {
    f32x4 c = {0.f, 0.f, 0.f, 0.f};
#pragma unroll
    for (int kk = 0; kk < 4; ++kk) {
      bf16x8 bf = *(const bf16x8*)&WT[(size_t)(jt * 16 + jl) * H + kk * 32 + kg * 8];
      c = __builtin_amdgcn_mfma_f32_16x16x32_bf16(afrag[kk], bf, c, 0, 0, 0);
    }
    if (BIAS) {
      float bb = bias[jt * 16 + jl];
#pragma unroll
      for (int r = 0; r < 4; ++r) c[r] += bb;
    }
    if (RELU) {
#pragma unroll
      for (int r = 0; r < 4; ++r) c[r] = fmaxf(c[r], 0.f);
    }
    acc[jt] = c;
  }
  __syncthreads();
#pragma unroll
  for (int jt = 0; jt < 8; ++jt)
#pragma unroll
    for (int r = 0; r < 4; ++r) tile[wave * 16 + kg * 4 + r][jt * 16 + jl] = f2bf(acc[jt][r]);
  __syncthreads();
#pragma unroll
  for (int it = 0; it < 4; ++it) {
    int f = it * 256 + tid, r = f >> 4, q = f & 15;
    if (r < nr) *(uint4*)&Y[(size_t)(base + r) * H + q * 8] = *(const uint4*)&tile[r][q * 8];
  }
}

// ---------- dual dense: Y1 = X@W1, Y2 = X@W2 + b2 (shared X staging) ----------
__global__ __launch_bounds__(256) void dense_dual(const unsigned short* __restrict__ X,
                                                  const unsigned short* __restrict__ WT1,
                                                  const unsigned short* __restrict__ WT2,
                                                  const float* __restrict__ bias2,
                                                  unsigned short* __restrict__ Y1,
                                                  unsigned short* __restrict__ Y2, int n) {
  __shared__ unsigned short tile[64][136];
  const int tid = threadIdx.x, lane = tid & 63, wave = tid >> 6;
  const int jl = lane & 15, kg = lane >> 4;
  const int base = blockIdx.x * 64;
  if (base >= n) return;
  const int nr = min(64, n - base);
  const uint4* X4 = (const uint4*)X;
#pragma unroll
  for (int it = 0; it < 4; ++it) {
    int f = it * 256 + tid, r = f >> 4, q = f & 15;
    if (r < nr) *(uint4*)&tile[r][q * 8] = X4[(size_t)(base + r) * 16 + q];
  }
  __syncthreads();
  bf16x8 afrag[4];
#pragma unroll
  for (int kk = 0; kk < 4; ++kk)
    afrag[kk] = *(const bf16x8*)&tile[wave * 16 + jl][kk * 32 + kg * 8];
  f32x4 acc[8];
#pragma unroll
  for (int jt = 0; jt < 8; ++jt) {
    f32x4 c = {0.f, 0.f, 0.f, 0.f};
#pragma unroll
    for (int kk = 0; kk < 4; ++kk) {
      bf16x8 bf = *(const bf16x8*)&WT1[(size_t)(jt * 16 + jl) * H + kk * 32 + kg * 8];
      c = __builtin_amdgcn_mfma_f32_16x16x32_bf16(afrag[kk], bf, c, 0, 0, 0);
    }
    acc[jt] = c;
  }
  __syncthreads();
#pragma unroll
  for (int jt = 0; jt < 8; ++jt)
#pragma unroll
    for (int r = 0; r < 4; ++r) tile[wave * 16 + kg * 4 + r][jt * 16 + jl] = f2bf(acc[jt][r]);
  __syncthreads();
#pragma unroll
  for (int it = 0; it < 4; ++it) {
    int f = it * 256 + tid, r = f >> 4, q = f & 15;
    if (r < nr) *(uint4*)&Y1[(size_t)(base + r) * H + q * 8] = *(const uint4*)&tile[r][q * 8];
  }
  __syncthreads();
#pragma unroll
  for (int jt = 0; jt < 8; ++jt) {
    f32x4 c = {0.f, 0.f, 0.f, 0.f};
#pragma unroll
    for (int kk = 0; kk < 4; ++kk) {
      bf16x8 bf = *(const bf16x8*)&WT2[(size_t)(jt * 16 + jl) * H + kk * 32 + kg * 8];
      c = __builtin_amdgcn_mfma_f32_16x16x32_bf16(afrag[kk], bf, c, 0, 0, 0);
    }
    float bb = bias2[jt * 16 + jl];
#pragma unroll
    for (int r = 0; r < 4; ++r) c[r] += bb;
    acc[jt] = c;
  }
  __syncthreads();
#pragma unroll
  for (int jt = 0; jt < 8; ++jt)
#pragma unroll
    for (int r = 0; r < 4; ++r) tile[wave * 16 + kg * 4 + r][jt * 16 + jl] = f2bf(acc[jt][r]);
  __syncthreads();
#pragma unroll
  for (int it = 0; it < 4; ++it) {
    int f = it * 256 + tid, r = f >> 4, q = f & 15;
    if (r < nr) *(uint4*)&Y2[(size_t)(base + r) * H + q * 8] = *(const uint4*)&tile[r][q * 8];
  }
}

// ---------- chained dense (GIN): Y = relu(relu(X@W1+b1)@W2+b2) ----------
__global__ __launch_bounds__(256) void dense_chain(const unsigned short* __restrict__ X,
                                                   const unsigned short* __restrict__ WT1,
                                                   const float* __restrict__ b1,
                                                   const unsigned short* __restrict__ WT2,
                                                   const float* __restrict__ b2,
                                                   unsigned short* __restrict__ Y, int n) {
  __shared__ unsigned short tile[64][136];
  const int tid = threadIdx.x, lane = tid & 63, wave = tid >> 6;
  const int jl = lane & 15, kg = lane >> 4;
  const int base = blockIdx.x * 64;
  if (base >= n) return;
  const int nr = min(64, n - base);
  const uint4* X4 = (const uint4*)X;
#pragma unroll
  for (int it = 0; it < 4; ++it) {
    int f = it * 256 + tid, r = f >> 4, q = f & 15;
    if (r < nr) *(uint4*)&tile[r][q * 8] = X4[(size_t)(base + r) * 16 + q];
  }
  __syncthreads();
  bf16x8 af[4];
#pragma unroll
  for (int kk = 0; kk < 4; ++kk) af[kk] = *(const bf16x8*)&tile[wave * 16 + jl][kk * 32 + kg * 8];
  f32x4 acc[8];
#pragma unroll
  for (int jt = 0; jt < 8; ++jt) {
    f32x4 c = {0.f, 0.f, 0.f, 0.f};
#pragma unroll
    for (int kk = 0; kk < 4; ++kk) {
      bf16x8 bf = *(const bf16x8*)&WT1[(size_t)(jt * 16 + jl) * H + kk * 32 + kg * 8];
      c = __builtin_amdgcn_mfma_f32_16x16x32_bf16(af[kk], bf, c, 0, 0, 0);
    }
    float bb = b1[jt * 16 + jl];
#pragma unroll
    for (int r = 0; r < 4; ++r) c[r] = fmaxf(c[r] + bb, 0.f);
    acc[jt] = c;
  }
  __syncthreads();
#pragma unroll
  for (int jt = 0; jt < 8; ++jt)
#pragma unroll
    for (int r = 0; r < 4; ++r) tile[wave * 16 + kg * 4 + r][jt * 16 + jl] = f2bf(acc[jt][r]);
  __syncthreads();
#pragma unroll
  for (int kk = 0; kk < 4; ++kk) af[kk] = *(const bf16x8*)&tile[wave * 16 + jl][kk * 32 + kg * 8];
#pragma unroll
  for (int jt = 0; jt < 8; ++jt) {
    f32x4 c = {0.f, 0.f, 0.f, 0.f};
#pragma unroll
    for (int kk = 0; kk < 4; ++kk) {
      bf16x8 bf = *(const bf16x8*)&WT2[(size_t)(jt * 16 + jl) * H + kk * 32 + kg * 8];
      c = __builtin_amdgcn_mfma_f32_16x16x32_bf16(af[kk], bf, c, 0, 0, 0);
    }
    float bb = b2[jt * 16 + jl];
#pragma unroll
    for (int r = 0; r < 4; ++r) c[r] = fmaxf(c[r] + bb, 0.f);
    acc[jt] = c;
  }
  __syncthreads();
#pragma unroll
  for (int jt = 0; jt < 8; ++jt)
#pragma unroll
    for (int r = 0; r < 4; ++r) tile[wave * 16 + kg * 4 + r][jt * 16 + jl] = f2bf(acc[jt][r]);
  __syncthreads();
#pragma unroll
  for (int it = 0; it < 4; ++it) {
    int f = it * 256 + tid, r = f >> 4, q = f & 15;
    if (r < nr) *(uint4*)&Y[(size_t)(base + r) * H + q * 8] = *(const uint4*)&tile[r][q * 8];
  }
}

// ---------- gate dense: gate = relu(X@W1+b1) . w2 + b2 ----------
__global__ __launch_bounds__(256) void dense_gate(const unsigned short* __restrict__ X,
                                                  const unsigned short* __restrict__ WT,
                                                  const float* __restrict__ b1,
                                                  const float* __restrict__ w2,
                                                  const float* __restrict__ b2,
                                                  float* __restrict__ gate, int n) {
  __shared__ unsigned short tile[64][136];
  const int tid = threadIdx.x, lane = tid & 63, wave = tid >> 6;
  const int jl = lane & 15, kg = lane >> 4;
  const int base = blockIdx.x * 64;
  if (base >= n) return;
  const int nr = min(64, n - base);
  const uint4* X4 = (const uint4*)X;
#pragma unroll
  for (int it = 0; it < 4; ++it) {
    int f = it * 256 + tid, r = f >> 4, q = f & 15;
    if (r < nr) *(uint4*)&tile[r][q * 8] = X4[(size_t)(base + r) * 16 + q];
  }
  __syncthreads();
  bf16x8 af[4];
#pragma unroll
  for (int kk = 0; kk < 4; ++kk) af[kk] = *(const bf16x8*)&tile[wave * 16 + jl][kk * 32 + kg * 8];
  float p0 = 0.f, p1 = 0.f, p2 = 0.f, p3 = 0.f;
#pragma unroll
  for (int jt = 0; jt < 8; ++jt) {
    f32x4 c = {0.f, 0.f, 0.f, 0.f};
#pragma unroll
    for (int kk = 0; kk < 4; ++kk) {
      bf16x8 bf = *(const bf16x8*)&WT[(size_t)(jt * 16 + jl) * H + kk * 32 + kg * 8];
      c = __builtin_amdgcn_mfma_f32_16x16x32_bf16(af[kk], bf, c, 0, 0, 0);
    }
    float bb = b1[jt * 16 + jl];
    float wv = w2[jt * 16 + jl];
    p0 = fmaf(fmaxf(c[0] + bb, 0.f), wv, p0);
    p1 = fmaf(fmaxf(c[1] + bb, 0.f), wv, p1);
    p2 = fmaf(fmaxf(c[2] + bb, 0.f), wv, p2);
    p3 = fmaf(fmaxf(c[3] + bb, 0.f), wv, p3);
  }
#pragma unroll
  for (int off = 1; off <= 8; off <<= 1) {
    p0 += __shfl_xor(p0, off);
    p1 += __shfl_xor(p1, off);
    p2 += __shfl_xor(p2, off);
    p3 += __shfl_xor(p3, off);
  }
  if (jl == 0) {
    float bb2 = b2[0];
    int row = wave * 16 + kg * 4;
    if (row + 0 < nr) gate[base + row + 0] = p0 + bb2;
    if (row + 1 < nr) gate[base + row + 1] = p1 + bb2;
    if (row + 2 < nr) gate[base + row + 2] = p2 + bb2;
    if (row + 3 < nr) gate[base + row + 3] = p3 + bb2;
  }
}

// ---------- CSR build ----------
__global__ void zero_int(int* p, int n) {
  int i = blockIdx.x * 256 + threadIdx.x;
  if (i < n) p[i] = 0;
}
__global__ void csr_count(const int* __restrict__ ei, int* __restrict__ cnt, int E) {
  int e = blockIdx.x * 256 + threadIdx.x;
  if (e < E) atomicAdd(&cnt[ei[(size_t)E + e]], 1);
}
__global__ __launch_bounds__(1024) void scan50k(const int* __restrict__ cnt,
                                                int* __restrict__ row_ptr, int n) {
  __shared__ int ls[1024];
  int t = threadIdx.x;
  int chunk = (n + 1023) >> 10;
  int a = t * chunk;
  if (a > n) a = n;
  int b = a + chunk;
  if (b > n) b = n;
  int s = 0;
  for (int i = a; i < b; ++i) s += cnt[i];
  ls[t] = s;
  __syncthreads();
  for (int off = 1; off < 1024; off <<= 1) {
    int v = (t >= off) ? ls[t - off] : 0;
    __syncthreads();
    ls[t] += v;
    __syncthreads();
  }
  int run = (t > 0) ? ls[t - 1] : 0;
  for (int i = a; i < b; ++i) {
    row_ptr[i] = run;
    run += cnt[i];
  }
  if (t == 1023) row_ptr[n] = ls[1023];
}
__global__ void copy_int(const int* __restrict__ a, int* __restrict__ b, int n) {
  int i = blockIdx.x * 256 + threadIdx.x;
  if (i < n) b[i] = a[i];
}
__global__ void csr_fill(const int* __restrict__ ei, int* __restrict__ cursor,
                         int* __restrict__ csr_src, int* __restrict__ csr_dst, int E) {
  int e = blockIdx.x * 256 + threadIdx.x;
  if (e >= E) return;
  int s = ei[e], d = ei[(size_t)E + e];
  int p = atomicAdd(&cursor[d], 1);
  csr_src[p] = s;
  csr_dst[p] = d;
}
__global__ void dinv_kernel(const int* __restrict__ row_ptr, float* __restrict__ dinv, int n) {
  int i = blockIdx.x * 256 + threadIdx.x;
  if (i < n) dinv[i] = rsqrtf((float)(1 + row_ptr[i + 1] - row_ptr[i]));
}
__global__ void fill_u32(unsigned* p, unsigned v, size_t n) {
  size_t i = (size_t)blockIdx.x * 256 + threadIdx.x;
  if (i < n) p[i] = v;
}

// ---------- GCN gather: wave per node, 8x unrolled ----------
__global__ __launch_bounds__(256) void gcn_gather(const unsigned short* __restrict__ h,
                                                  const float* __restrict__ dinv,
                                                  const int* __restrict__ row_ptr,
                                                  const int* __restrict__ csr_src,
                                                  const float* __restrict__ bias,
                                                  unsigned short* __restrict__ out, int n) {
  int node = blockIdx.x * 4 + (threadIdx.x >> 6);
  int lane = threadIdx.x & 63;
  if (node >= n) return;
  const unsigned* hu = (const unsigned*)h;
  float di = dinv[node];
  unsigned v = hu[(size_t)node * 64 + lane];
  float t0 = bflo(v) * di, t1 = bfhi(v) * di;
  int a = row_ptr[node], b = row_ptr[node + 1];
  int e = a;
  for (; e + 8 <= b; e += 8) {
    int sx[8];
#pragma unroll
    for (int i = 0; i < 8; ++i) sx[i] = csr_src[e + i];
    unsigned w[8];
    float dd[8];
#pragma unroll
    for (int i = 0; i < 8; ++i) w[i] = hu[(size_t)sx[i] * 64 + lane];
#pragma unroll
    for (int i = 0; i < 8; ++i) dd[i] = dinv[sx[i]];
#pragma unroll
    for (int i = 0; i < 8; ++i) {
      t0 = fmaf(bflo(w[i]), dd[i], t0);
      t1 = fmaf(bfhi(w[i]), dd[i], t1);
    }
  }
  for (; e < b; ++e) {
    int s = csr_src[e];
    float ds = dinv[s];
    unsigned w = hu[(size_t)s * 64 + lane];
    t0 = fmaf(bflo(w), ds, t0);
    t1 = fmaf(bfhi(w), ds, t1);
  }
  float y0 = fmaxf(fmaf(t0, di, bias[lane * 2]), 0.f);
  float y1 = fmaxf(fmaf(t1, di, bias[lane * 2 + 1]), 0.f);
  ((unsigned*)out)[(size_t)node * 64 + lane] = pack2bf(y0, y1);
}

__global__ void att_pre(const unsigned short* __restrict__ g, const float* __restrict__ attS,
                        const float* __restrict__ attD, float* __restrict__ asrc,
                        float* __restrict__ adst, int n) {
  int t = blockIdx.x * 256 + threadIdx.x;
  if (t >= n * 4) return;
  int i = t >> 2, hd = t & 3;
  const unsigned* gr = (const unsigned*)(g + (size_t)i * H + hd * 32);
  float s1 = 0.f, s2 = 0.f;
#pragma unroll
  for (int p = 0; p < 16; ++p) {
    unsigned u = gr[p];
    float a = bflo(u), b = bfhi(u);
    s1 = fmaf(a, attS[hd * 32 + 2 * p], fmaf(b, attS[hd * 32 + 2 * p + 1], s1));
    s2 = fmaf(a, attD[hd * 32 + 2 * p], fmaf(b, attD[hd * 32 + 2 * p + 1], s2));
  }
  asrc[t] = s1;
  adst[t] = s2;
}

__device__ __forceinline__ float lrelu_exp(float v) {
  v = v > 0.f ? v : 0.2f * v;
  return __expf(v);
}

// ---------- GAT gather: wave per node, 8x unrolled ----------
__global__ __launch_bounds__(256) void gat_gather(const unsigned short* __restrict__ g,
                                                  const float* __restrict__ asrc,
                                                  const float* __restrict__ adst,
                                                  const int* __restrict__ row_ptr,
                                                  const int* __restrict__ csr_src,
                                                  const float* __restrict__ bias,
                                                  unsigned short* __restrict__ out, int n) {
  int node = blockIdx.x * 4 + (threadIdx.x >> 6);
  int lane = threadIdx.x & 63;
  if (node >= n) return;
  const int hd = lane >> 4;
  const unsigned* gu = (const unsigned*)g;
  float adc = adst[node * 4 + hd];
  float w = lrelu_exp(asrc[node * 4 + hd] + adc);
  unsigned u = gu[(size_t)node * 64 + lane];
  float acc0 = w * bflo(u), acc1 = w * bfhi(u), wsum = w;
  int a = row_ptr[node], b = row_ptr[node + 1];
  int e = a;
  for (; e + 8 <= b; e += 8) {
    int sx[8];
#pragma unroll
    for (int i = 0; i < 8; ++i) sx[i] = csr_src[e + i];
    unsigned uu[8];
#pragma unroll
    for (int i = 0; i < 8; ++i) uu[i] = gu[(size_t)sx[i] * 64 + lane];
    float ww[8];
#pragma unroll
    for (int i = 0; i < 8; ++i) ww[i] = lrelu_exp(asrc[sx[i] * 4 + hd] + adc);
#pragma unroll
    for (int i = 0; i < 8; ++i) {
      acc0 = fmaf(ww[i], bflo(uu[i]), acc0);
      acc1 = fmaf(ww[i], bfhi(uu[i]), acc1);
      wsum += ww[i];
    }
  }
  for (; e < b; ++e) {
    int s = csr_src[e];
    unsigned us = gu[(size_t)s * 64 + lane];
    float we = lrelu_exp(asrc[s * 4 + hd] + adc);
    acc0 = fmaf(we, bflo(us), acc0);
    acc1 = fmaf(we, bfhi(us), acc1);
    wsum += we;
  }
  float inv = 1.f / (wsum + 1e-16f);
  float r0 = acc0 * inv + bias[2 * lane];
  float r1 = acc1 * inv + bias[2 * lane + 1];
  r0 = r0 > 0.f ? r0 : expm1f(r0);
  r1 = r1 > 0.f ? r1 : expm1f(r1);
  ((unsigned*)out)[(size_t)node * 64 + lane] = pack2bf(r0, r1);
}

// ---------- EdgeConv: pipelined tile MFMA; atomics issued AFTER prefetch-write+barrier ----------
__global__ __launch_bounds__(256) void edgeconv_tile(const unsigned short* __restrict__ A,
                                                     const unsigned short* __restrict__ Bm,
                                                     const int* __restrict__ csr_src,
                                                     const int* __restrict__ csr_dst,
                                                     const unsigned short* __restrict__ W2T,
                                                     const float* __restrict__ b2,
                                                     unsigned* __restrict__ hec, int E) {
  __shared__ unsigned short buf[2][64][140];  // row stride 280B: conflict-free staging/frag reads
  __shared__ int dbuf[2][64];
  const int tid = threadIdx.x, lane = tid & 63, wave = tid >> 6;
  const int jl = lane & 15, kg = lane >> 4;
  const int srow = tid >> 2, sq = tid & 3;
  float b2v[8];
#pragma unroll
  for (int jt = 0; jt < 8; ++jt) b2v[jt] = b2[jt * 16 + jl];

  const int tiles = (E + 63) >> 6;
  int t = blockIdx.x;
  if (t >= tiles) return;
  int cur = 0;
  {  // prologue: stage tile t into buf[0]
    int base = t << 6;
    int ne = min(64, E - base);
    uint2 pk[8];
    if (srow < ne) {
      int d = csr_dst[base + srow], s = csr_src[base + srow];
      const uint2* Ar = (const uint2*)(A + (size_t)d * H + sq * 32);
      const uint2* Br = (const uint2*)(Bm + (size_t)s * H + sq * 32);
#pragma unroll
      for (int i = 0; i < 8; ++i) {
        uint2 va = Ar[i], vb = Br[i];
        pk[i].x = pack2bf(fmaxf(bflo(va.x) + bflo(vb.x), 0.f), fmaxf(bfhi(va.x) + bfhi(vb.x), 0.f));
        pk[i].y = pack2bf(fmaxf(bflo(va.y) + bflo(vb.y), 0.f), fmaxf(bfhi(va.y) + bfhi(vb.y), 0.f));
      }
    } else {
#pragma unroll
      for (int i = 0; i < 8; ++i) pk[i] = {0u, 0u};
    }
#pragma unroll
    for (int i = 0; i < 8; ++i) *(uint2*)&buf[0][srow][sq * 32 + i * 4] = pk[i];
    if (sq == 0) dbuf[0][srow] = (srow < ne) ? csr_dst[base + srow] : -1;
  }
  __syncthreads();

  for (; t < tiles; t += gridDim.x) {
    const int nt = t + gridDim.x;
    const bool havenext = nt < tiles;
    // prefetch next tile into registers
    uint2 pk[8];
    if (havenext) {
      int base = nt << 6;
      int ne = min(64, E - base);
      if (srow < ne) {
        int d = csr_dst[base + srow], s = csr_src[base + srow];
        const uint2* Ar = (const uint2*)(A + (size_t)d * H + sq * 32);
        const uint2* Br = (const uint2*)(Bm + (size_t)s * H + sq * 32);
#pragma unroll
        for (int i = 0; i < 8; ++i) {
          uint2 va = Ar[i], vb = Br[i];
          pk[i].x =
              pack2bf(fmaxf(bflo(va.x) + bflo(vb.x), 0.f), fmaxf(bfhi(va.x) + bfhi(vb.x), 0.f));
          pk[i].y =
              pack2bf(fmaxf(bflo(va.y) + bflo(vb.y), 0.f), fmaxf(bfhi(va.y) + bfhi(vb.y), 0.f));
        }
      } else {
#pragma unroll
        for (int i = 0; i < 8; ++i) pk[i] = {0u, 0u};
      }
    }
    // MFMA on current buffer
    bf16x8 af[4];
#pragma unroll
    for (int kk = 0; kk < 4; ++kk)
      af[kk] = *(const bf16x8*)&buf[cur][wave * 16 + jl][kk * 32 + kg * 8];
    const int r0 = wave * 16 + kg * 4;
    const int d0 = dbuf[cur][r0 + 0], d1 = dbuf[cur][r0 + 1];
    const int d2 = dbuf[cur][r0 + 2], d3 = dbuf[cur][r0 + 3];
    f32x4 acc[8];
#pragma unroll
    for (int jt = 0; jt < 8; ++jt) {
      f32x4 c = {0.f, 0.f, 0.f, 0.f};
#pragma unroll
      for (int kk = 0; kk < 4; ++kk) {
        bf16x8 wf = *(const bf16x8*)&W2T[(size_t)(jt * 16 + jl) * H + kk * 32 + kg * 8];
        c = __builtin_amdgcn_mfma_f32_16x16x32_bf16(af[kk], wf, c, 0, 0, 0);
      }
      acc[jt] = c;
    }
    // write staged next tile into alternate buffer (waits only on the 16 gather loads)
    if (havenext) {
      int base = nt << 6;
      int ne = min(64, E - base);
#pragma unroll
      for (int i = 0; i < 8; ++i) *(uint2*)&buf[cur ^ 1][srow][sq * 32 + i * 4] = pk[i];
      if (sq == 0) dbuf[cur ^ 1][srow] = (srow < ne) ? csr_dst[base + srow] : -1;
    }
    __syncthreads();
    // atomic epilogue for tile t: drains under next tile's MFMA phase
#pragma unroll
    for (int jt = 0; jt < 8; ++jt) {
      const int col = jt * 16 + jl;
      f32x4 c = acc[jt];
      int cd = d0;
      float m = c[0];
      if (d1 != cd) {
        if (cd >= 0) atomicMax(&hec[(size_t)cd * H + col], fenc(m + b2v[jt]));
        cd = d1;
        m = c[1];
      } else
        m = fmaxf(m, c[1]);
      if (d2 != cd) {
        if (cd >= 0) atomicMax(&hec[(size_t)cd * H + col], fenc(m + b2v[jt]));
        cd = d2;
        m = c[2];
      } else
        m = fmaxf(m, c[2]);
      if (d3 != cd) {
        if (cd >= 0) atomicMax(&hec[(size_t)cd * H + col], fenc(m + b2v[jt]));
        cd = d3;
        m = c[3];
      } else
        m = fmaxf(m, c[3]);
      if (cd >= 0) atomicMax(&hec[(size_t)cd * H + col], fenc(m + b2v[jt]));
    }
    cur ^= 1;
  }
}

// ---------- decode hec (ordered u32) -> bf16 rows ----------
__global__ void ec_decode(const unsigned* __restrict__ hec, unsigned short* __restrict__ out,
                          size_t half) {
  size_t i = (size_t)blockIdx.x * 256 + threadIdx.x;
  if (i < half) {
    uint2 v = *(const uint2*)&hec[i * 2];
    ((unsigned*)out)[i] = pack2bf(fdec(v.x), fdec(v.y));
  }
}

// ---------- GIN gather: bf16 input, wave per node, 8x unrolled ----------
__global__ __launch_bounds__(256) void gin_gather(const unsigned short* __restrict__ h,
                                                  const int* __restrict__ row_ptr,
                                                  const int* __restrict__ csr_src,
                                                  unsigned short* __restrict__ out, int n) {
  int node = blockIdx.x * 4 + (threadIdx.x >> 6);
  int lane = threadIdx.x & 63;
  if (node >= n) return;
  const unsigned* hu = (const unsigned*)h;
  unsigned v = hu[(size_t)node * 64 + lane];
  float t0 = bflo(v), t1 = bfhi(v);
  int a = row_ptr[node], b = row_ptr[node + 1];
  int e = a;
  for (; e + 8 <= b; e += 8) {
    int sx[8];
#pragma unroll
    for (int i = 0; i < 8; ++i) sx[i] = csr_src[e + i];
    unsigned w[8];
#pragma unroll
    for (int i = 0; i < 8; ++i) w[i] = hu[(size_t)sx[i] * 64 + lane];
#pragma unroll
    for (int i = 0; i < 8; ++i) {
      t0 += bflo(w[i]);
      t1 += bfhi(w[i]);
    }
  }
  for (; e < b; ++e) {
    int s = csr_src[e];
    unsigned w = hu[(size_t)s * 64 + lane];
    t0 += bflo(w);
    t1 += bfhi(w);
  }
  ((unsigned*)out)[(size_t)node * 64 + lane] = pack2bf(t0, t1);
}

// ---------- pooling ----------
__global__ void starts_kernel(const int* __restrict__ batch, int* __restrict__ starts, int n,
                              int G) {
  int i = blockIdx.x * 256 + threadIdx.x;
  if (i >= n) return;
  int b = batch[i];
  int bp = (i == 0) ? -1 : batch[i - 1];
  for (int g = bp + 1; g <= b; ++g) starts[g] = i;
  if (i == n - 1)
    for (int g = b + 1; g <= G; ++g) starts[g] = n;
}
__global__ __launch_bounds__(256) void pool_fused(float* __restrict__ gate,
                                                  const unsigned short* __restrict__ h4,
                                                  const int* __restrict__ starts,
                                                  const float* __restrict__ fcW,
                                                  const float* __restrict__ fcB,
                                                  float* __restrict__ out) {
  __shared__ float red[256];
  __shared__ float pl[128];
  int g = blockIdx.x, t = threadIdx.x;
  int s0 = starts[g], s1 = starts[g + 1];
  float m = -1e30f;
  for (int i = s0 + t; i < s1; i += 256) m = fmaxf(m, gate[i]);
  red[t] = m;
  __syncthreads();
  for (int off = 128; off; off >>= 1) {
    if (t < off) red[t] = fmaxf(red[t], red[t + off]);
    __syncthreads();
  }
  m = red[0];
  __syncthreads();
  float sm = 0.f;
  for (int i = s0 + t; i < s1; i += 256) {
    float ge = __expf(gate[i] - m);
    gate[i] = ge;
    sm += ge;
  }
  red[t] = sm;
  __syncthreads();
  for (int off = 128; off; off >>= 1) {
    if (t < off) red[t] += red[t + off];
    __syncthreads();
  }
  float inv = 1.f / (red[0] + 1e-16f);
  __syncthreads();
  int c = t & 127, half = t >> 7;
  float acc = 0.f;
  for (int i = s0 + half; i < s1; i += 2) acc = fmaf(gate[i], bf2f(h4[(size_t)i * H + c]), acc);
  red[t] = acc;
  __syncthreads();
  if (t < 128) pl[t] = (red[t] + red[t + 128]) * inv;
  __syncthreads();
  if (t < OUTD) {
    float o = fcB[t];
    for (int k = 0; k < 128; ++k) o = fmaf(pl[k], fcW[k * OUTD + t], o);
    red[t] = o;
  }
  __syncthreads();
  if (t == 0) {
    float mm = -1e30f;
    for (int j = 0; j < OUTD; ++j) mm = fmaxf(mm, red[j]);
    float s = 0.f;
    for (int j = 0; j < OUTD; ++j) s += __expf(red[j] - mm);
    float l = logf(s);
    for (int j = 0; j < OUTD; ++j) out[g * OUTD + j] = red[j] - mm - l;
  }
}

extern "C" void kernel_launch(void* const* d_in, const int* in_sizes, int n_in, void* d_out,
                              int out_size, void* d_ws, size_t ws_size, hipStream_t stream) {
  const float* x = (const float*)d_in[0];
  const int* ei = (const int*)d_in[1];
  const int* batch = (const int*)d_in[2];
  const float* gcnW = (const float*)d_in[3];
  const float* gcnB = (const float*)d_in[4];
  const float* gatW = (const float*)d_in[5];
  const float* attS = (const float*)d_in[6];
  const float* attD = (const float*)d_in[7];
  const float* gatB = (const float*)d_in[8];
  const float* ecW1 = (const float*)d_in[9];
  const float* ecB1 = (const float*)d_in[10];
  const float* ecW2 = (const float*)d_in[11];
  const float* ecB2 = (const float*)d_in[12];
  const float* ginW1 = (const float*)d_in[13];
  const float* ginB1 = (const float*)d_in[14];
  const float* ginW2 = (const float*)d_in[15];
  const float* ginB2 = (const float*)d_in[16];
  const float* gtW1 = (const float*)d_in[17];
  const float* gtB1 = (const float*)d_in[18];
  const float* gtW2 = (const float*)d_in[19];
  const float* gtB2 = (const float*)d_in[20];
  const float* fcW = (const float*)d_in[21];
  const float* fcB = (const float*)d_in[22];

  const int N = in_sizes[0] / H;
  const int E = in_sizes[1] / 2;
  const int G = out_size / OUTD;
  const size_t NH = (size_t)N * H;

  auto align16 = [](char* p) { return (char*)(((uintptr_t)p + 15) & ~(uintptr_t)15); };
  char* p = (char*)d_ws;
  unsigned* hec = (unsigned*)p;      p += NH * 4;
  float* dinv = (float*)p;           p += (size_t)N * 4;
  float* asrc = (float*)p;           p += (size_t)4 * N * 4;
  float* adst = (float*)p;           p += (size_t)4 * N * 4;
  float* gate = (float*)p;           p += (size_t)N * 4;
  int* starts = (int*)p;             p += (size_t)(G + 1) * 4;
  int* cnt = (int*)p;                p += (size_t)N * 4;
  int* row_ptr = (int*)p;            p += (size_t)(N + 1) * 4;
  int* cursor = (int*)p;             p += (size_t)N * 4;
  int* csr_src = (int*)p;            p += (size_t)E * 4;
  int* csr_dst = (int*)p;            p += (size_t)E * 4;
  p = align16(p);
  unsigned short* WT = (unsigned short*)p;  p += (size_t)8 * 16384 * 2;
  p = align16(p);
  unsigned short* T0 = (unsigned short*)p;  p += NH * 2;
  p = align16(p);
  unsigned short* T1 = (unsigned short*)p;  p += NH * 2;
  p = align16(p);
  unsigned short* T2 = (unsigned short*)p;  p += NH * 2;

  const unsigned short* gcnT = WT;
  const unsigned short* gatT = WT + 16384;
  const unsigned short* WaT = WT + 2 * 16384;
  const unsigned short* WbT = WT + 3 * 16384;
  const unsigned short* W2T = WT + 4 * 16384;
  const unsigned short* gin1T = WT + 5 * 16384;
  const unsigned short* gin2T = WT + 6 * 16384;
  const unsigned short* gt1T = WT + 7 * 16384;

  const int gN = (N + 255) / 256;
  const int gNH = (int)((NH + 255) / 256);
  const int gE = (E + 255) / 256;
  const int gDense = (N + 63) / 64;
  const int gW4 = (N + 3) / 4;

  // ---- prep + CSR ----
  prep_w<<<(8 * 16384 + 255) / 256, 256, 0, stream>>>(gcnW, gatW, ecW1, ecW2, ginW1, ginW2,
                                                      gtW1, WT);
  zero_int<<<gN, 256, 0, stream>>>(cnt, N);
  csr_count<<<gE, 256, 0, stream>>>(ei, cnt, E);
  scan50k<<<1, 1024, 0, stream>>>(cnt, row_ptr, N);
  copy_int<<<gN, 256, 0, stream>>>(row_ptr, cursor, N);
  csr_fill<<<gE, 256, 0, stream>>>(ei, cursor, csr_src, csr_dst, E);
  dinv_kernel<<<gN, 256, 0, stream>>>(row_ptr, dinv, N);

  // ---- GCN ----
  dense_mfma<0, 0, 0><<<gDense, 256, 0, stream>>>(x, gcnT, nullptr, T0, N);
  gcn_gather<<<gW4, 256, 0, stream>>>(T0, dinv, row_ptr, csr_src, gcnB, T1, N);

  // ---- GAT ----
  dense_mfma<1, 0, 0><<<gDense, 256, 0, stream>>>(T1, gatT, nullptr, T2, N);
  att_pre<<<(N * 4 + 255) / 256, 256, 0, stream>>>(T2, attS, attD, asrc, adst, N);
  gat_gather<<<gW4, 256, 0, stream>>>(T2, asrc, adst, row_ptr, csr_src, gatB, T0, N);

  // ---- EdgeConv ----
  dense_dual<<<gDense, 256, 0, stream>>>(T0, WaT, WbT, ecB1, T1, T2, N);
  fill_u32<<<gNH, 256, 0, stream>>>(hec, 0x80000000u, NH);  // enc(0.0): folds relu + isolated
  edgeconv_tile<<<2048, 256, 0, stream>>>(T1, T2, csr_src, csr_dst, W2T, ecB2, hec, E);
  ec_decode<<<(int)((NH / 2 + 255) / 256), 256, 0, stream>>>(hec, T0, NH / 2);

  // ---- GIN ----
  gin_gather<<<gW4, 256, 0, stream>>>(T0, row_ptr, csr_src, T1, N);
  dense_chain<<<gDense, 256, 0, stream>>>(T1, gin1T, ginB1, gin2T, ginB2, T2, N);  // h4 = T2

  // ---- gating + pooling ----
  dense_gate<<<gDense, 256, 0, stream>>>(T2, gt1T, gtB1, gtW2, gtB2, gate, N);
  starts_kernel<<<gN, 256, 0, stream>>>(batch, starts, N, G);
  pool_fused<<<G, 256, 0, stream>>>(gate, T2, starts, fcW, fcB, (float*)d_out);
}